// Round 3
// baseline (192.618 us; speedup 1.0000x reference)
//
#include <hip/hip_runtime.h>
#include <hip/hip_fp16.h>

#define BATCH_N   2048
#define EMB_D_    768
#define PROJ_D_   128
#define QUEUE_N   32768
#define HARD_K_   512
static constexpr float INV_T  = 1.0f / 0.07f;
static constexpr float WLO    = 0.12f;              // code-0 boundary (512th opp val ~0.164)
static constexpr float S8ENC  = 255.0f / 0.88f;     // encode scale
static constexpr float BINW   = 0.88f / 255.0f;     // code bin width

typedef __attribute__((ext_vector_type(8))) short short8;
typedef __attribute__((ext_vector_type(4))) short short4v;
typedef __attribute__((ext_vector_type(4))) float f32x4;

__device__ __forceinline__ unsigned short f2bf(float f) {
    unsigned u = __float_as_uint(f);
    unsigned r = u + 0x7fffu + ((u >> 16) & 1u);   // RNE
    return (unsigned short)(r >> 16);
}
__device__ __forceinline__ float bf2f(short s) {
    return __uint_as_float(((unsigned)(unsigned short)s) << 16);
}
__device__ __forceinline__ int opp_of(int mylab, const int* __restrict__ qcnt) {
    const int same = (mylab == 0) ? qcnt[0] : ((mylab == 1) ? qcnt[1] : 0);
    return qcnt[2] - same;
}

// ---------------------------------------------------------------------------
// Merged prep: emb cast + queue cast + qlab census (PLAIN partial stores, no
// atomics -> no pre-zero needed) + W1/W2 transpose + row census + pc zero.
// Eliminates the hipMemsetAsync dispatch.
// ---------------------------------------------------------------------------
__global__ void __launch_bounds__(256) prep(const float* __restrict__ emb, short* __restrict__ embb,
                                            const float* __restrict__ queue, short* __restrict__ qb,
                                            const int* __restrict__ qlab, int* __restrict__ qpart,
                                            const float* __restrict__ W1, short* __restrict__ w1t,
                                            const float* __restrict__ W2, short* __restrict__ w2t,
                                            const int* __restrict__ labels, int* __restrict__ rcnt,
                                            int* __restrict__ pc) {
    __shared__ float tile[64][65];
    const int b = blockIdx.x, t = threadIdx.x;
    if (b < 1536) {
        const int i = b * 256 + t;
        const float4 f = ((const float4*)emb)[i];
        short4v o = {(short)f2bf(f.x), (short)f2bf(f.y), (short)f2bf(f.z), (short)f2bf(f.w)};
        ((short4v*)embb)[i] = o;
    } else if (b < 5632) {
        const int i = (b - 1536) * 256 + t;
        const float4 f = ((const float4*)queue)[i];
        short4v o = {(short)f2bf(f.x), (short)f2bf(f.y), (short)f2bf(f.z), (short)f2bf(f.w)};
        ((short4v*)qb)[i] = o;
    } else if (b < 5664) {
        const int i = (b - 5632) * 256 + t;
        int c0 = 0, c1 = 0, cv = 0;
        for (int j = i; j < QUEUE_N; j += 8192) {
            const int q = qlab[j];
            c0 += (q == 0); c1 += (q == 1); cv += (q >= 0);
        }
        #pragma unroll
        for (int o = 32; o > 0; o >>= 1) {
            c0 += __shfl_xor(c0, o); c1 += __shfl_xor(c1, o); cv += __shfl_xor(cv, o);
        }
        int* red = (int*)tile;
        const int wv = t >> 6;
        if ((t & 63) == 0) { red[wv * 4 + 0] = c0; red[wv * 4 + 1] = c1; red[wv * 4 + 2] = cv; }
        __syncthreads();
        if (t == 0) {
            const int bb = (b - 5632) * 4;
            qpart[bb + 0] = red[0] + red[4] + red[8]  + red[12];
            qpart[bb + 1] = red[1] + red[5] + red[9]  + red[13];
            qpart[bb + 2] = red[2] + red[6] + red[10] + red[14];
        }
    } else if (b < 5832) {
        const int bid = b - 5664;
        const float* A; short* At; int R, C, bx, by;
        if (bid < 144) { A = W1; At = w1t; R = EMB_D_; C = EMB_D_;  bx = (bid % 12) * 64; by = (bid / 12) * 64; }
        else { const int b2 = bid - 144; A = W2; At = w2t; R = EMB_D_; C = PROJ_D_; bx = (b2 & 1) * 64; by = (b2 >> 1) * 64; }
        const int tc = t & 63, tg = t >> 6;
        #pragma unroll
        for (int i = 0; i < 16; i++) {
            const int r = tg * 16 + i;
            tile[r][tc] = A[(size_t)(by + r) * C + bx + tc];
        }
        __syncthreads();
        #pragma unroll
        for (int i = 0; i < 16; i++) {
            const int r = tg * 16 + i;
            At[(size_t)(bx + r) * R + by + tc] = (short)f2bf(tile[tc][r]);
        }
    } else {
        // row-label census (plain store) + pc zero for build_perm atomics
        int c = 0;
        for (int j = t; j < BATCH_N; j += 256) c += (labels[j] == 0);
        #pragma unroll
        for (int o = 32; o > 0; o >>= 1) c += __shfl_xor(c, o);
        int* red = (int*)tile;
        if ((t & 63) == 0) red[t >> 6] = c;
        __syncthreads();
        if (t == 0) rcnt[0] = red[0] + red[1] + red[2] + red[3];
        if (t < 8) pc[t] = 0;
    }
}

// ---------------------------------------------------------------------------
// GEMM1: bf16 MFMA NT, 64x128 (MxN) tile, K-loop, fused bias+ReLU, bf16 out.
// ---------------------------------------------------------------------------
__global__ void __launch_bounds__(256) mfma_h64(const short* __restrict__ Ab,
                                                const short* __restrict__ Bb,
                                                const float* __restrict__ bias,
                                                short* __restrict__ C,
                                                int N, int K) {
    __shared__ __align__(16) short As[64 * 128];    // 16 KB
    __shared__ __align__(16) short Bs[128 * 128];   // 32 KB
    const int t = threadIdx.x;
    const int lane = t & 63, wv = t >> 6;
    const int l16 = lane & 15, l4 = lane >> 4;
    const int m0 = blockIdx.y * 64, n0 = blockIdx.x * 128;
    const int wn = wv * 32;

    f32x4 acc[4][2];
    #pragma unroll
    for (int i = 0; i < 4; ++i)
        #pragma unroll
        for (int j = 0; j < 2; ++j) acc[i][j] = f32x4{0.f, 0.f, 0.f, 0.f};

    for (int kb = 0; kb < K; kb += 128) {
        __syncthreads();
        #pragma unroll
        for (int it = 0; it < 4; ++it) {            // A: 16 units of 512 shorts
            const int r = it * 4 + wv, row = r * 4 + l4, cg = l16 ^ (row & 15);
            __builtin_amdgcn_global_load_lds(
                (const __attribute__((address_space(1))) void*)(Ab + (size_t)(m0 + row) * K + kb + cg * 8),
                (__attribute__((address_space(3))) void*)(As + r * 512), 16, 0, 0);
        }
        #pragma unroll
        for (int it = 0; it < 8; ++it) {            // B: 32 units
            const int r = it * 4 + wv, row = r * 4 + l4, cg = l16 ^ (row & 15);
            __builtin_amdgcn_global_load_lds(
                (const __attribute__((address_space(1))) void*)(Bb + (size_t)(n0 + row) * K + kb + cg * 8),
                (__attribute__((address_space(3))) void*)(Bs + r * 512), 16, 0, 0);
        }
        __syncthreads();
        #pragma unroll
        for (int ks = 0; ks < 4; ++ks) {
            short8 af[4], bfr[2];
            const int ch = (ks * 4 + l4) ^ l16;
            #pragma unroll
            for (int i = 0; i < 4; ++i)
                af[i] = *(const short8*)(As + (i * 16 + l16) * 128 + ch * 8);
            #pragma unroll
            for (int j = 0; j < 2; ++j)
                bfr[j] = *(const short8*)(Bs + (wn + j * 16 + l16) * 128 + ch * 8);
            #pragma unroll
            for (int i = 0; i < 4; ++i)
                #pragma unroll
                for (int j = 0; j < 2; ++j)
                    acc[i][j] = __builtin_amdgcn_mfma_f32_16x16x32_bf16(af[i], bfr[j], acc[i][j], 0, 0, 0);
        }
    }

    float bsv[2];
    #pragma unroll
    for (int j = 0; j < 2; ++j) bsv[j] = bias[n0 + wn + j * 16 + l16];
    #pragma unroll
    for (int i = 0; i < 4; ++i)
        #pragma unroll
        for (int r = 0; r < 4; ++r) {
            const int m = m0 + i * 16 + l4 * 4 + r;
            #pragma unroll
            for (int j = 0; j < 2; ++j) {
                const int n = n0 + wn + j * 16 + l16;
                const float v = fmaxf(acc[i][j][r] + bsv[j], 0.0f);
                C[(size_t)m * N + n] = (short)f2bf(v);
            }
        }
}

// ---------------------------------------------------------------------------
// Fused dispatch: z-GEMM (M-tile 32, grid 64 -> 2x parallelism) + the
// permutation builder (independent of h64 output; rides the same launch).
// blocks 0..63: z-norm; 64..191: queue-col perm; 192..199: row perm.
// ---------------------------------------------------------------------------
__global__ void __launch_bounds__(256) znorm_perm(const short* __restrict__ Ab,
                                                  const short* __restrict__ Bb,
                                                  const float* __restrict__ bias,
                                                  short* __restrict__ zb,
                                                  const int* __restrict__ qlab,
                                                  const int* __restrict__ labels,
                                                  const int* __restrict__ qpart,
                                                  const int* __restrict__ rcnt,
                                                  int* __restrict__ qcnt,
                                                  int* __restrict__ colidx,
                                                  int* __restrict__ qlabp,
                                                  int* __restrict__ rowmap,
                                                  int* __restrict__ rlabp,
                                                  int* __restrict__ pc) {
    __shared__ __align__(16) short As[32 * 128];    // 8 KB
    __shared__ __align__(16) short Bs[128 * 128];   // 32 KB
    __shared__ float ssq[32];
    __shared__ int wcnt[4][3];
    __shared__ int gbase[3];
    const int blk = blockIdx.x;
    const int t = threadIdx.x;
    const int lane = t & 63, wv = t >> 6;

    if (blk >= 64) {
        // ---- permutation builder (ballot-rank, one atomic/class/block) ----
        const unsigned long long below = (1ull << lane) - 1ull;
        int q0 = 0, q1 = 0, qv = 0;
        for (int i = 0; i < 32; ++i) {
            q0 += qpart[i * 4]; q1 += qpart[i * 4 + 1]; qv += qpart[i * 4 + 2];
        }
        if (blk < 192) {
            const int cb = blk - 64;
            if (cb == 0 && t == 0) { qcnt[0] = q0; qcnt[1] = q1; qcnt[2] = qv; }
            const int j = cb * 256 + t;
            const int q = qlab[j];
            const int cls = (q == 0) ? 0 : ((q == 1) ? 1 : 2);
            const unsigned long long b0 = __ballot(cls == 0);
            const unsigned long long b1 = __ballot(cls == 1);
            const unsigned long long b2 = __ballot(cls == 2);
            const int rank = (cls == 0) ? __popcll(b0 & below)
                           : ((cls == 1) ? __popcll(b1 & below) : __popcll(b2 & below));
            if (lane == 0) {
                wcnt[wv][0] = __popcll(b0); wcnt[wv][1] = __popcll(b1); wcnt[wv][2] = __popcll(b2);
            }
            __syncthreads();
            if (t < 3) {
                const int tot = wcnt[0][t] + wcnt[1][t] + wcnt[2][t] + wcnt[3][t];
                gbase[t] = atomicAdd(&pc[t], tot);
            }
            __syncthreads();
            int wb = 0;
            #pragma unroll
            for (int w = 0; w < 4; ++w) if (w < wv) wb += wcnt[w][cls];
            const int cbase = (cls == 0) ? 0 : ((cls == 1) ? q0 : q0 + q1);
            const int pos = cbase + gbase[cls] + wb + rank;
            colidx[pos] = j; qlabp[pos] = q;
        } else {
            const int r = (blk - 192) * 256 + t;
            const int l = labels[r];
            const int cls = (l == 0) ? 0 : 1;
            const unsigned long long b0 = __ballot(cls == 0);
            const unsigned long long b1 = __ballot(cls == 1);
            const int rank = (cls == 0) ? __popcll(b0 & below) : __popcll(b1 & below);
            if (lane == 0) { wcnt[wv][0] = __popcll(b0); wcnt[wv][1] = __popcll(b1); }
            __syncthreads();
            if (t < 2) {
                const int tot = wcnt[0][t] + wcnt[1][t] + wcnt[2][t] + wcnt[3][t];
                gbase[t] = atomicAdd(&pc[3 + t], tot);
            }
            __syncthreads();
            int wb = 0;
            #pragma unroll
            for (int w = 0; w < 4; ++w) if (w < wv) wb += wcnt[w][cls];
            const int cbase = (cls == 0) ? 0 : rcnt[0];
            const int pos = cbase + gbase[cls] + wb + rank;
            rowmap[pos] = r; rlabp[pos] = l;
        }
        return;
    }

    // ---- z GEMM path: 32-row M-tile, fused bias + L2-normalize ----
    const int l16 = lane & 15, l4 = lane >> 4;
    const int m0 = blk * 32;
    const int wn = wv * 32;
    const int K = EMB_D_;

    if (t < 32) ssq[t] = 0.0f;    // ordered before epilogue by K-loop barriers

    f32x4 acc[2][2];
    #pragma unroll
    for (int i = 0; i < 2; ++i)
        #pragma unroll
        for (int j = 0; j < 2; ++j) acc[i][j] = f32x4{0.f, 0.f, 0.f, 0.f};

    for (int kb = 0; kb < K; kb += 128) {
        __syncthreads();
        #pragma unroll
        for (int it = 0; it < 2; ++it) {            // A: 8 units of 512 shorts
            const int r = it * 4 + wv, row = r * 4 + l4, cg = l16 ^ (row & 15);
            __builtin_amdgcn_global_load_lds(
                (const __attribute__((address_space(1))) void*)(Ab + (size_t)(m0 + row) * K + kb + cg * 8),
                (__attribute__((address_space(3))) void*)(As + r * 512), 16, 0, 0);
        }
        #pragma unroll
        for (int it = 0; it < 8; ++it) {            // B: 32 units
            const int r = it * 4 + wv, row = r * 4 + l4, cg = l16 ^ (row & 15);
            __builtin_amdgcn_global_load_lds(
                (const __attribute__((address_space(1))) void*)(Bb + (size_t)(row) * K + kb + cg * 8),
                (__attribute__((address_space(3))) void*)(Bs + r * 512), 16, 0, 0);
        }
        __syncthreads();
        #pragma unroll
        for (int ks = 0; ks < 4; ++ks) {
            short8 af[2], bfr[2];
            const int ch = (ks * 4 + l4) ^ l16;
            #pragma unroll
            for (int i = 0; i < 2; ++i)
                af[i] = *(const short8*)(As + (i * 16 + l16) * 128 + ch * 8);
            #pragma unroll
            for (int j = 0; j < 2; ++j)
                bfr[j] = *(const short8*)(Bs + (wn + j * 16 + l16) * 128 + ch * 8);
            #pragma unroll
            for (int i = 0; i < 2; ++i)
                #pragma unroll
                for (int j = 0; j < 2; ++j)
                    acc[i][j] = __builtin_amdgcn_mfma_f32_16x16x32_bf16(af[i], bfr[j], acc[i][j], 0, 0, 0);
        }
    }

    float bsv[2];
    #pragma unroll
    for (int j = 0; j < 2; ++j) bsv[j] = bias[wn + j * 16 + l16];
    #pragma unroll
    for (int i = 0; i < 2; ++i)
        #pragma unroll
        for (int r = 0; r < 4; ++r) {
            float p = 0.0f;
            #pragma unroll
            for (int j = 0; j < 2; ++j) {
                acc[i][j][r] += bsv[j];
                p += acc[i][j][r] * acc[i][j][r];
            }
            #pragma unroll
            for (int o = 8; o > 0; o >>= 1) p += __shfl_xor(p, o);
            if (l16 == 0) atomicAdd(&ssq[i * 16 + l4 * 4 + r], p);
        }
    __syncthreads();
    #pragma unroll
    for (int i = 0; i < 2; ++i)
        #pragma unroll
        for (int r = 0; r < 4; ++r) {
            const int lrow = i * 16 + l4 * 4 + r;
            const float inv = rsqrtf(ssq[lrow]);
            #pragma unroll
            for (int j = 0; j < 2; ++j)
                zb[(size_t)(m0 + lrow) * PROJ_D_ + wn + j * 16 + l16] =
                    (short)f2bf(acc[i][j][r] * inv);
        }
}

// ---------------------------------------------------------------------------
// Masked queue GEMM -> u8 codes, label-partitioned (half the blocks exit).
// NEW r3: ALL gather indices (rowmap/colidx) and labels (rlabp/qlabp)
// prefetched into registers before the first staging -> single vmcnt drain
// at block start; the tile loop's staging pipeline is pure-ALU like r12.
// ---------------------------------------------------------------------------
__global__ void __launch_bounds__(256) mfma_mask8(const short* __restrict__ Ab,
                                                  const short* __restrict__ Bb,
                                                  unsigned char* __restrict__ codes,
                                                  const int* __restrict__ rlabp,
                                                  const int* __restrict__ qlabp,
                                                  const int* __restrict__ colidx,
                                                  const int* __restrict__ rowmap,
                                                  const int* __restrict__ qcnt,
                                                  const int* __restrict__ rcnt) {
    const int m0 = blockIdx.y * 128;
    const int c0 = qcnt[0], c1v = qcnt[1], r0 = rcnt[0];
    int lo, hi;
    if (m0 + 128 <= r0)      { lo = c0; hi = c0 + c1v; }   // label-0 rows -> label-1 cols
    else if (m0 >= r0)       { lo = 0;  hi = c0; }         // label-1 rows -> label-0 cols
    else                     { lo = 0;  hi = c0 + c1v; }   // mixed boundary tile
    const int bs = blockIdx.x * 512;
    if (bs + 512 <= lo || bs >= hi) return;                // uniform block exit

    __shared__ __align__(16) short As[128 * 128];
    __shared__ __align__(16) short Bs[128 * 128];
    const int t = threadIdx.x;
    const int lane = t & 63, wv = t >> 6;
    const int l16 = lane & 15, l4 = lane >> 4;
    const int wm = (wv & 1) * 64, wn = (wv >> 1) * 64;

    // prefetch all indirection into registers (one wait, then pure ALU)
    int ra[8], ca[32], la[16], qa[16];
    #pragma unroll
    for (int it = 0; it < 8; ++it)
        ra[it] = rowmap[m0 + (it * 4 + wv) * 4 + l4];
    #pragma unroll
    for (int tt = 0; tt < 4; ++tt)
        #pragma unroll
        for (int it = 0; it < 8; ++it)
            ca[tt * 8 + it] = colidx[bs + tt * 128 + (it * 4 + wv) * 4 + l4];
    #pragma unroll
    for (int i = 0; i < 4; ++i)
        #pragma unroll
        for (int r = 0; r < 4; ++r)
            la[i * 4 + r] = rlabp[m0 + wm + i * 16 + l4 * 4 + r];
    #pragma unroll
    for (int tt = 0; tt < 4; ++tt)
        #pragma unroll
        for (int j = 0; j < 4; ++j)
            qa[tt * 4 + j] = qlabp[bs + tt * 128 + wn + j * 16 + l16];

    #pragma unroll
    for (int it = 0; it < 8; ++it) {
        const int r = it * 4 + wv, row = r * 4 + l4, cg = l16 ^ (row & 15);
        __builtin_amdgcn_global_load_lds(
            (const __attribute__((address_space(1))) void*)(Ab + (size_t)ra[it] * 128 + cg * 8),
            (__attribute__((address_space(3))) void*)(As + r * 512), 16, 0, 0);
    }
    #pragma unroll
    for (int it = 0; it < 8; ++it) {
        const int r = it * 4 + wv, row = r * 4 + l4, cg = l16 ^ (row & 15);
        __builtin_amdgcn_global_load_lds(
            (const __attribute__((address_space(1))) void*)(Bb + (size_t)ca[it] * 128 + cg * 8),
            (__attribute__((address_space(3))) void*)(Bs + r * 512), 16, 0, 0);
    }
    const float C0 = 1.0f - WLO * S8ENC;
    __syncthreads();

    #pragma unroll
    for (int tt = 0; tt < 4; ++tt) {
        const int n0 = bs + tt * 128;

        f32x4 acc[4][4];
        #pragma unroll
        for (int i = 0; i < 4; ++i)
            #pragma unroll
            for (int j = 0; j < 4; ++j) acc[i][j] = f32x4{0.f, 0.f, 0.f, 0.f};

        #pragma unroll
        for (int ks = 0; ks < 4; ++ks) {
            short8 af[4], bfr[4];
            const int ch = (ks * 4 + l4) ^ l16;
            #pragma unroll
            for (int i = 0; i < 4; ++i) {
                af[i]  = *(const short8*)(As + (wm + i * 16 + l16) * 128 + ch * 8);
                bfr[i] = *(const short8*)(Bs + (wn + i * 16 + l16) * 128 + ch * 8);
            }
            #pragma unroll
            for (int i = 0; i < 4; ++i)
                #pragma unroll
                for (int j = 0; j < 4; ++j)
                    acc[i][j] = __builtin_amdgcn_mfma_f32_16x16x32_bf16(af[i], bfr[j], acc[i][j], 0, 0, 0);
        }

        if (tt < 3) {
            __syncthreads();          // all waves done reading Bs tile tt
            #pragma unroll
            for (int it = 0; it < 8; ++it) {
                const int r = it * 4 + wv, row = r * 4 + l4, cg = l16 ^ (row & 15);
                __builtin_amdgcn_global_load_lds(
                    (const __attribute__((address_space(1))) void*)(Bb + (size_t)ca[(tt + 1) * 8 + it] * 128 + cg * 8),
                    (__attribute__((address_space(3))) void*)(Bs + r * 512), 16, 0, 0);
            }
        }

        // epilogue for this tile (overlaps next tile's B staging)
        float a0[4], a1[4];
        #pragma unroll
        for (int j = 0; j < 4; ++j) {
            const int q = qa[tt * 4 + j];
            a0[j] = (q >= 0 && q != 0) ? C0 : -1e9f;
            a1[j] = (q >= 0 && q != 1) ? C0 : -1e9f;
        }
        #pragma unroll
        for (int i = 0; i < 4; ++i) {
            #pragma unroll
            for (int r = 0; r < 4; ++r) {
                const int m  = m0 + wm + i * 16 + l4 * 4 + r;
                const bool z = (la[i * 4 + r] == 0);
                unsigned pk = 0;
                #pragma unroll
                for (int j = 0; j < 4; ++j) {
                    const float add = z ? a0[j] : a1[j];
                    const float f = fmaf(acc[i][j][r], S8ENC, add);
#if __has_builtin(__builtin_amdgcn_cvt_pk_u8_f32)
                    pk = __builtin_amdgcn_cvt_pk_u8_f32(f, j, pk);
#else
                    const unsigned c = (unsigned)fminf(fmaxf(f, 0.0f), 255.0f);
                    pk |= c << (8 * j);
#endif
                }
                *(unsigned*)(codes + (size_t)m * QUEUE_N + n0 + wn + l16 * 4) = pk;
            }
        }
        if (tt < 3) __syncthreads();  // next tile's B staged (barrier drains vmcnt)
    }
}

// ---------------------------------------------------------------------------
// Histogram crossing search (used by inline fallback)
// ---------------------------------------------------------------------------
__device__ __forceinline__ void find_crossing(int* hist, int* grp, int target,
                                              int* s_bin, int* s_chi) {
    const int t = threadIdx.x;
    const int b0 = hist[4*t], b1 = hist[4*t+1], b2 = hist[4*t+2], b3 = hist[4*t+3];
    grp[t] = b0 + b1 + b2 + b3;
    __syncthreads();
    for (int off = 1; off < 256; off <<= 1) {
        int add = (t + off < 256) ? grp[t + off] : 0;
        __syncthreads();
        grp[t] += add;
        __syncthreads();
    }
    int cab = (t < 255) ? grp[t + 1] : 0;
    const int hb[4] = {b0, b1, b2, b3};
    #pragma unroll
    for (int i = 3; i >= 0; i--) {
        const int h = hb[i];
        if (cab < target && cab + h >= target) { *s_bin = 4*t + i; *s_chi = cab; }
        cab += h;
    }
    __syncthreads();
}

// iterate all 128 packed-half2 values
#define FOR_ALL_VALS(BODY)                                                   \
    _Pragma("unroll")                                                        \
    for (int _k = 0; _k < 64; _k++) {                                        \
        const float2 _f = __half22float2(*(const __half2*)&dv[_k]);          \
        { const float v = _f.x; BODY }                                       \
        { const float v = _f.y; BODY }                                       \
    }

// ---------------------------------------------------------------------------
// Fused tail dispatch: blocks 0..2047 = hist-topk lse (partitioned row p,
// opposite-label span only) with the exact fallback INLINE on failure;
// blocks 2048..2303 = S GEMM tile (independent, rides the same launch).
// ---------------------------------------------------------------------------
__global__ void __launch_bounds__(256) tail_fused(const unsigned char* __restrict__ codes,
                                                  const int* __restrict__ qcnt,
                                                  const int* __restrict__ rlabp,
                                                  const int* __restrict__ rowmap,
                                                  const short* __restrict__ zb,
                                                  const short* __restrict__ qb,
                                                  const int* __restrict__ qlab,
                                                  float* __restrict__ lseq,
                                                  short* __restrict__ Sbuf) {
    __shared__ __align__(16) short As[128 * 128];
    __shared__ __align__(16) short Bs[128 * 128];
    __shared__ int s_bin, s_chi, s_bin2, s_chi2;
    __shared__ float scf[4];
    __shared__ int sci[4];
    const int bid = blockIdx.x, t = threadIdx.x;

    if (bid >= BATCH_N) {
        // ---- S GEMM tile: bf16 MFMA NT, K=128, packed bf16 out ----
        const int q = bid - BATCH_N;
        const int lane = t & 63, wv = t >> 6;
        const int l16 = lane & 15, l4 = lane >> 4;
        const int m0 = (q >> 4) * 128, n0 = (q & 15) * 128;

        #pragma unroll
        for (int it = 0; it < 8; ++it) {
            const int r = it * 4 + wv, row = r * 4 + l4, cg = l16 ^ (row & 15);
            __builtin_amdgcn_global_load_lds(
                (const __attribute__((address_space(1))) void*)(zb + (size_t)(m0 + row) * 128 + cg * 8),
                (__attribute__((address_space(3))) void*)(As + r * 512), 16, 0, 0);
        }
        #pragma unroll
        for (int it = 0; it < 8; ++it) {
            const int r = it * 4 + wv, row = r * 4 + l4, cg = l16 ^ (row & 15);
            __builtin_amdgcn_global_load_lds(
                (const __attribute__((address_space(1))) void*)(zb + (size_t)(n0 + row) * 128 + cg * 8),
                (__attribute__((address_space(3))) void*)(Bs + r * 512), 16, 0, 0);
        }
        __syncthreads();

        const int wm = (wv & 1) * 64, wn = (wv >> 1) * 64;
        f32x4 acc[4][4];
        #pragma unroll
        for (int i = 0; i < 4; ++i)
            #pragma unroll
            for (int j = 0; j < 4; ++j) acc[i][j] = f32x4{0.f, 0.f, 0.f, 0.f};

        #pragma unroll
        for (int ks = 0; ks < 4; ++ks) {
            short8 af[4], bfr[4];
            const int ch = (ks * 4 + l4) ^ l16;
            #pragma unroll
            for (int i = 0; i < 4; ++i) {
                af[i]  = *(const short8*)(As + (wm + i * 16 + l16) * 128 + ch * 8);
                bfr[i] = *(const short8*)(Bs + (wn + i * 16 + l16) * 128 + ch * 8);
            }
            #pragma unroll
            for (int i = 0; i < 4; ++i)
                #pragma unroll
                for (int j = 0; j < 4; ++j)
                    acc[i][j] = __builtin_amdgcn_mfma_f32_16x16x32_bf16(af[i], bfr[j], acc[i][j], 0, 0, 0);
        }
        #pragma unroll
        for (int i = 0; i < 4; ++i)
            #pragma unroll
            for (int r = 0; r < 4; ++r) {
                const int m = m0 + wm + i * 16 + l4 * 4 + r;
                union { unsigned short u[4]; uint2 d; } pk;
                #pragma unroll
                for (int j = 0; j < 4; ++j) pk.u[j] = f2bf(acc[i][j][r]);
                *(uint2*)(Sbuf + (size_t)m * BATCH_N + n0 + wn + l16 * 4) = pk.d;
            }
        return;
    }

    // ---- topk path (partitioned row p) ----
    const int p = bid;
    const int orig  = rowmap[p];
    const int myLab = rlabp[p];
    const int opp   = opp_of(myLab, qcnt);
    bool fb = (opp < HARD_K_);
    if (!fb) {
        int* hist = (int*)Bs;
        int* suf  = (int*)(Bs + 512);
        hist[t] = 0;
        __syncthreads();

        const int c0 = qcnt[0];
        const int lo = (myLab == 0) ? c0 : 0;
        const int hi = (myLab == 0) ? c0 + qcnt[1] : c0;
        const int klo = (lo & ~511) >> 4;            // uint4 index (16 cols each)
        const int khi = ((hi + 511) & ~511) >> 4;

        const uint4* rowp = (const uint4*)(codes + (size_t)p * QUEUE_N);
        for (int k = klo + t; k < khi; k += 256) {
            const uint4 u = rowp[k];
            const unsigned w[4] = {u.x, u.y, u.z, u.w};
            #pragma unroll
            for (int q = 0; q < 4; q++)
                #pragma unroll
                for (int s = 0; s < 4; s++) {
                    const int c = (w[q] >> (8 * s)) & 0xFF;
                    if (c) atomicAdd(&hist[c], 1);
                }
        }
        __syncthreads();

        suf[t] = hist[t];
        __syncthreads();
        for (int off = 1; off < 256; off <<= 1) {
            int add = (t + off < 256) ? suf[t + off] : 0;
            __syncthreads();
            suf[t] += add;
            __syncthreads();
        }
        const int total = suf[1];
        if (total >= HARD_K_) {
            {
                const int above = (t < 255) ? suf[t + 1] : 0;
                if (suf[t] >= HARD_K_ && above < HARD_K_) s_bin = t;
            }
            __syncthreads();
            const int b = s_bin;

            float e = 0.0f;
            if (t > b && hist[t]) e = (float)hist[t] * __expf((WLO + ((float)t - 0.5f) * BINW - 1.0f) * INV_T);
            #pragma unroll
            for (int o = 32; o > 0; o >>= 1) e += __shfl_xor(e, o);
            if ((t & 63) == 0) scf[t >> 6] = e;
            __syncthreads();
            if (t == 0) {
                const float Eab  = scf[0] + scf[1] + scf[2] + scf[3];
                const int   cab  = (b < 255) ? suf[b + 1] : 0;
                const float ebin = __expf((WLO + ((float)b - 0.5f) * BINW - 1.0f) * INV_T);
                const float sadj = Eab + (float)(HARD_K_ - cab) * ebin;
                lseq[orig] = INV_T + __logf(sadj);
            }
            return;
        }
        __syncthreads();   // hist path failed; safe to reuse LDS below
    }

    // ---- exact fallback, inline (rare) ----
    float* zrow = (float*)As;            // 128 floats
    int*   fh   = (int*)(As + 512);      // 1024 ints
    int*   grp  = (int*)(As + 2560);     // 256 ints
    if (t < 128) zrow[t] = bf2f(zb[(size_t)orig * 128 + t]);
    __syncthreads();

    const int mylab = myLab;
    unsigned dv[64];
    float rm = -1e30f, rs = 0.0f;
    for (int k = 0; k < 128; k++) {
        const int j = t + 256 * k;
        float d = 0.0f;
        #pragma unroll
        for (int c = 0; c < 16; ++c) {
            const short8 qv = *(const short8*)(qb + (size_t)j * 128 + c * 8);
            #pragma unroll
            for (int e = 0; e < 8; ++e) d += zrow[c * 8 + e] * bf2f(qv[e]);
        }
        if (j < HARD_K_) {
            const float sv = d * INV_T;
            if (sv > rm) { rs = rs * __expf(rm - sv) + 1.0f; rm = sv; }
            else         { rs += __expf(sv - rm); }
        }
        const int q = qlab[j];
        const float mv = (q != mylab && q >= 0) ? d : -65504.0f;
        const __half h = __float2half(mv);
        unsigned short* pp = (unsigned short*)&dv[k >> 1];
        pp[k & 1] = *(const unsigned short*)&h;
    }

    if (opp == 0) {
        #pragma unroll
        for (int o = 32; o > 0; o >>= 1) {
            const float om = __shfl_xor(rm, o), os = __shfl_xor(rs, o);
            const float nm = fmaxf(rm, om);
            rs = rs * __expf(rm - nm) + os * __expf(om - nm);
            rm = nm;
        }
        if ((t & 63) == 0) { scf[t >> 6] = rm; ((float*)sci)[t >> 6] = rs; }
        __syncthreads();
        if (t == 0) {
            float M = -1e30f, Sx = 0.0f;
            for (int w = 0; w < 4; w++) {
                const float nm = fmaxf(M, scf[w]);
                Sx = Sx * __expf(M - nm) + ((float*)sci)[w] * __expf(scf[w] - nm);
                M = nm;
            }
            lseq[orig] = M + __logf(Sx);
        }
        return;
    }
    if (opp < HARD_K_) {
        float mm = -1e30f, ss = 0.0f;
        FOR_ALL_VALS(
            if (v > -60000.0f) {
                const float sv = v * INV_T;
                if (sv > mm) { ss = ss * __expf(mm - sv) + 1.0f; mm = sv; }
                else         { ss += __expf(sv - mm); }
            } )
        #pragma unroll
        for (int o = 32; o > 0; o >>= 1) {
            const float om = __shfl_xor(mm, o), os = __shfl_xor(ss, o);
            const float nm = fmaxf(mm, om);
            ss = ss * __expf(mm - nm) + os * __expf(om - nm);
            mm = nm;
        }
        if ((t & 63) == 0) { scf[t >> 6] = mm; ((float*)sci)[t >> 6] = ss; }
        __syncthreads();
        if (t == 0) {
            float M = -1e30f, Sx = 0.0f;
            for (int w = 0; w < 4; w++) {
                const float nm = fmaxf(M, scf[w]);
                Sx = Sx * __expf(M - nm) + ((float*)sci)[w] * __expf(scf[w] - nm);
                M = nm;
            }
            lseq[orig] = M + __logf(Sx);
        }
        return;
    }

    float mloc = -1e30f;
    FOR_ALL_VALS( mloc = fmaxf(mloc, v); )
    #pragma unroll
    for (int o = 32; o > 0; o >>= 1) mloc = fmaxf(mloc, __shfl_xor(mloc, o));
    if ((t & 63) == 0) scf[t >> 6] = mloc;
    __syncthreads();
    const float m = fmaxf(fmaxf(scf[0], scf[1]), fmaxf(scf[2], scf[3]));

    int c1 = 0, c2 = 0;
    const float w1 = m - 0.25f, w2 = m - 1.0f;
    FOR_ALL_VALS( c1 += (v >= w1); c2 += (v >= w2); )
    #pragma unroll
    for (int o = 32; o > 0; o >>= 1) { c1 += __shfl_xor(c1, o); c2 += __shfl_xor(c2, o); }
    if ((t & 63) == 0) { sci[t >> 6] = c1; }
    __syncthreads();
    const int C1 = sci[0] + sci[1] + sci[2] + sci[3];
    __syncthreads();
    if ((t & 63) == 0) { sci[t >> 6] = c2; }
    __syncthreads();
    const int C2 = sci[0] + sci[1] + sci[2] + sci[3];

    float lo;
    if      (C1 >= HARD_K_) lo = w1;
    else if (C2 >= HARD_K_) lo = w2;
    else                    lo = -1.01f;
    const float range = m - lo;
    const float scale = 1024.0f / range;

    for (int k = t; k < 1024; k += 256) fh[k] = 0;
    __syncthreads();
    FOR_ALL_VALS(
        if (v >= lo) {
            const float bf = fminf((v - lo) * scale, 1023.0f);
            atomicAdd(&fh[(int)bf], 1);
        } )
    __syncthreads();
    find_crossing(fh, grp, HARD_K_, &s_bin, &s_chi);
    const int   bin1 = s_bin, chi1 = s_chi;
    const float binw = range * (1.0f / 1024.0f);
    const float lo1  = lo + bin1 * binw;
    const float ssc  = 1024.0f / binw;

    for (int k = t; k < 1024; k += 256) fh[k] = 0;
    __syncthreads();
    FOR_ALL_VALS(
        if (v >= lo) {
            const float bf = fminf((v - lo) * scale, 1023.0f);
            if ((int)bf == bin1) {
                const float sf = fminf(fmaxf((v - lo1) * ssc, 0.0f), 1023.0f);
                atomicAdd(&fh[(int)sf], 1);
            }
        } )
    __syncthreads();
    find_crossing(fh, grp, HARD_K_ - chi1, &s_bin2, &s_chi2);
    const float thr = lo1 + s_bin2 * (binw * (1.0f / 1024.0f));

    float sl = 0.0f; int cg = 0;
    FOR_ALL_VALS( if (v > thr) { cg++; sl += __expf((v - m) * INV_T); } )
    #pragma unroll
    for (int o = 32; o > 0; o >>= 1) { sl += __shfl_xor(sl, o); cg += __shfl_xor(cg, o); }
    if ((t & 63) == 0) { scf[t >> 6] = sl; sci[t >> 6] = cg; }
    __syncthreads();
    if (t == 0) {
        const float slt = scf[0] + scf[1] + scf[2] + scf[3];
        const int   cgt = sci[0] + sci[1] + sci[2] + sci[3];
        const float sadj = slt + ((float)HARD_K_ - (float)cgt) * __expf((thr - m) * INV_T);
        lseq[orig] = m * INV_T + __logf(sadj);
    }
}

// ---------------------------------------------------------------------------
// Batch lse + positive-pair loss over packed bf16 S (verified r12).
// ---------------------------------------------------------------------------
__global__ void __launch_bounds__(256) batch_row_loss(const short* __restrict__ S,
                                                      const int* __restrict__ labels,
                                                      const float* __restrict__ lse_queue,
                                                      float* __restrict__ part_out,
                                                      int* __restrict__ cnt_out) {
    const int t = threadIdx.x;
    const int wv = t >> 6, lane = t & 63;
    const int row = blockIdx.x * 4 + wv;
    __shared__ int plab[BATCH_N];      // labels in packed order
    for (int idx = t; idx < BATCH_N; idx += 256) {
        const int col = (idx & ~63) + ((idx & 3) << 4) + ((idx >> 2) & 15);
        plab[idx] = labels[col];
    }
    __syncthreads();
    const int myLab = labels[row];
    const uint4* rp = (const uint4*)(S + (size_t)row * BATCH_N);  // 8 bf16 per uint4

    float v[32]; int lb[32];
    #pragma unroll
    for (int kk = 0; kk < 4; kk++) {
        const uint4 u = rp[lane + 64 * kk];
        const unsigned w[4] = {u.x, u.y, u.z, u.w};
        const int base = (lane + 64 * kk) * 8;
        #pragma unroll
        for (int q = 0; q < 4; q++) {
            v[kk * 8 + 2 * q]     = __uint_as_float(w[q] << 16);
            v[kk * 8 + 2 * q + 1] = __uint_as_float(w[q] & 0xFFFF0000u);
            lb[kk * 8 + 2 * q]     = plab[base + 2 * q];
            lb[kk * 8 + 2 * q + 1] = plab[base + 2 * q + 1];
        }
    }

    const float REF = INV_T;
    float sneg = 0.0f;
    #pragma unroll
    for (int k = 0; k < 32; k++) {
        const float ev = __expf(v[k] * INV_T - REF);
        sneg += (lb[k] != myLab) ? ev : 0.0f;
    }
    #pragma unroll
    for (int o = 32; o > 0; o >>= 1) sneg += __shfl_xor(sneg, o);
    const float lseb = (sneg > 0.0f) ? REF + __logf(sneg) : -1e30f;
    const float Lq = lse_queue[row];
    const float mx0 = fmaxf(lseb, Lq), mn0 = fminf(lseb, Lq);
    const float L = mx0 + __logf(1.0f + __expf(mn0 - mx0));

    float part = 0.0f; int cnt = 0;
    #pragma unroll
    for (int k = 0; k < 32; k++) {
        const int idx = ((lane + 64 * (k >> 3)) * 8) + (k & 7);
        const int col = (idx & ~63) + ((idx & 3) << 4) + ((idx >> 2) & 15);
        if (lb[k] == myLab && col != row) {
            const float sv = v[k] * INV_T;
            const float mx = fmaxf(sv, L), mn = fminf(sv, L);
            part += (mx - sv) + __logf(1.0f + __expf(mn - mx));
            cnt++;
        }
    }
    #pragma unroll
    for (int o = 32; o > 0; o >>= 1) { part += __shfl_xor(part, o); cnt += __shfl_xor(cnt, o); }
    if (lane == 0) { part_out[row] = part; cnt_out[row] = cnt; }
}

// reduce 2048 per-row partials -> scalar loss. One block.
__global__ void __launch_bounds__(256) finalize_loss(const float* __restrict__ part,
                                                     const int* __restrict__ cnt,
                                                     float* __restrict__ out) {
    const int t = threadIdx.x;
    float s = 0.0f; int c = 0;
    #pragma unroll
    for (int k = 0; k < 8; k++) { s += part[t + 256 * k]; c += cnt[t + 256 * k]; }
    #pragma unroll
    for (int o = 32; o > 0; o >>= 1) { s += __shfl_xor(s, o); c += __shfl_xor(c, o); }
    __shared__ float sf[4]; __shared__ int sc[4];
    if ((t & 63) == 0) { sf[t >> 6] = s; sc[t >> 6] = c; }
    __syncthreads();
    if (t == 0) {
        const float st = sf[0] + sf[1] + sf[2] + sf[3];
        const int   ct = sc[0] + sc[1] + sc[2] + sc[3];
        out[0] = (ct > 0) ? (st / (float)ct) : 0.0f;
    }
}

// ---------------------------------------------------------------------------
extern "C" void kernel_launch(void* const* d_in, const int* in_sizes, int n_in,
                              void* d_out, int out_size, void* d_ws, size_t ws_size,
                              hipStream_t stream) {
    const float* emb    = (const float*)d_in[0];
    const int*   labels = (const int*)  d_in[1];
    const float* W1     = (const float*)d_in[2];
    const float* b1     = (const float*)d_in[3];
    const float* W2     = (const float*)d_in[4];
    const float* b2     = (const float*)d_in[5];
    const float* queue  = (const float*)d_in[6];
    const int*   qlab   = (const int*)  d_in[7];

    char* ws = (char*)d_ws;
    short*         Sbuf  = (short*)        (ws);              // 8 MB used (16 MB region)
    unsigned char* codes = (unsigned char*)(ws + 16777216);   // 64 MB
    short*         embb  = (short*)        (ws + 83886080);   // 3145728
    short*         hbf   = (short*)        (ws + 87031808);   // 3145728
    short*         zb    = (short*)        (ws + 90177536);   // 524288
    short*         qb    = (short*)        (ws + 90701824);   // 8388608
    short*         w1t   = (short*)        (ws + 99090432);   // 1179648
    short*         w2t   = (short*)        (ws + 100270080);  // 196608
    float*         lseq  = (float*)        (ws + 100466688);  // 8192
    int*           qcnt  = (int*)          (ws + 100474880);  // 64
    int*           rcnt  = (int*)          (ws + 100474944);  // 64
    int*           pc    = (int*)          (ws + 100475008);  // 64
    int*           qpart = (int*)          (ws + 100475072);  // 512
    float*         partb = (float*)        (ws + 100475584);  // 8192
    int*           cntb  = (int*)          (ws + 100483776);  // 8192
    int*           colidx= (int*)          (ws + 100491968);  // 131072
    int*           qlabp = (int*)          (ws + 100623040);  // 131072
    int*           rowmap= (int*)          (ws + 100754112);  // 8192
    int*           rlabp = (int*)          (ws + 100762304);  // 8192

    dim3 blk(256);
    prep<<<dim3(5833), blk, 0, stream>>>(emb, embb, queue, qb, qlab, qpart, W1, w1t, W2, w2t, labels, rcnt, pc);
    mfma_h64<<<dim3(EMB_D_ / 128, BATCH_N / 64), blk, 0, stream>>>(embb, w1t, b1, hbf, EMB_D_, EMB_D_);
    znorm_perm<<<dim3(200), blk, 0, stream>>>(hbf, w2t, b2, zb, qlab, labels, qpart, rcnt,
                                              qcnt, colidx, qlabp, rowmap, rlabp, pc);
    mfma_mask8<<<dim3(QUEUE_N / 512, BATCH_N / 128), blk, 0, stream>>>(zb, qb, codes, rlabp, qlabp, colidx, rowmap, qcnt, rcnt);
    tail_fused<<<dim3(BATCH_N + 256), blk, 0, stream>>>(codes, qcnt, rlabp, rowmap, zb, qb, qlab, lseq, Sbuf);
    batch_row_loss<<<dim3(BATCH_N / 4), blk, 0, stream>>>(Sbuf, labels, lseq, partb, cntb);
    finalize_loss<<<1, blk, 0, stream>>>(partb, cntb, (float*)d_out);
}

// Round 4
// 185.764 us; speedup vs baseline: 1.0369x; 1.0369x over previous
//
#include <hip/hip_runtime.h>
#include <hip/hip_fp16.h>

#define BATCH_N   2048
#define EMB_D_    768
#define PROJ_D_   128
#define QUEUE_N   32768
#define HARD_K_   512
static constexpr float INV_T  = 1.0f / 0.07f;
static constexpr float WLO    = 0.12f;              // code-0 boundary (512th opp val ~0.164)
static constexpr float S8ENC  = 255.0f / 0.88f;     // encode scale
static constexpr float BINW   = 0.88f / 255.0f;     // code bin width

typedef __attribute__((ext_vector_type(8))) short short8;
typedef __attribute__((ext_vector_type(4))) short short4v;
typedef __attribute__((ext_vector_type(4))) float f32x4;

__device__ __forceinline__ unsigned short f2bf(float f) {
    unsigned u = __float_as_uint(f);
    unsigned r = u + 0x7fffu + ((u >> 16) & 1u);   // RNE
    return (unsigned short)(r >> 16);
}
__device__ __forceinline__ float bf2f(short s) {
    return __uint_as_float(((unsigned)(unsigned short)s) << 16);
}
__device__ __forceinline__ int opp_of(int mylab, const int* __restrict__ qcnt) {
    const int same = (mylab == 0) ? qcnt[0] : ((mylab == 1) ? qcnt[1] : 0);
    return qcnt[2] - same;
}

// ---------------------------------------------------------------------------
// Merged prep: emb cast + queue cast + qlab census (plain partial stores) +
// W1/W2 transpose + row census + pc/done zero. No memset dispatch needed.
// ---------------------------------------------------------------------------
__global__ void __launch_bounds__(256) prep(const float* __restrict__ emb, short* __restrict__ embb,
                                            const float* __restrict__ queue, short* __restrict__ qb,
                                            const int* __restrict__ qlab, int* __restrict__ qpart,
                                            const float* __restrict__ W1, short* __restrict__ w1t,
                                            const float* __restrict__ W2, short* __restrict__ w2t,
                                            const int* __restrict__ labels, int* __restrict__ rcnt,
                                            int* __restrict__ pc) {
    __shared__ float tile[64][65];
    const int b = blockIdx.x, t = threadIdx.x;
    if (b < 1536) {
        const int i = b * 256 + t;
        const float4 f = ((const float4*)emb)[i];
        short4v o = {(short)f2bf(f.x), (short)f2bf(f.y), (short)f2bf(f.z), (short)f2bf(f.w)};
        ((short4v*)embb)[i] = o;
    } else if (b < 5632) {
        const int i = (b - 1536) * 256 + t;
        const float4 f = ((const float4*)queue)[i];
        short4v o = {(short)f2bf(f.x), (short)f2bf(f.y), (short)f2bf(f.z), (short)f2bf(f.w)};
        ((short4v*)qb)[i] = o;
    } else if (b < 5664) {
        const int i = (b - 5632) * 256 + t;
        int c0 = 0, c1 = 0, cv = 0;
        for (int j = i; j < QUEUE_N; j += 8192) {
            const int q = qlab[j];
            c0 += (q == 0); c1 += (q == 1); cv += (q >= 0);
        }
        #pragma unroll
        for (int o = 32; o > 0; o >>= 1) {
            c0 += __shfl_xor(c0, o); c1 += __shfl_xor(c1, o); cv += __shfl_xor(cv, o);
        }
        int* red = (int*)tile;
        const int wv = t >> 6;
        if ((t & 63) == 0) { red[wv * 4 + 0] = c0; red[wv * 4 + 1] = c1; red[wv * 4 + 2] = cv; }
        __syncthreads();
        if (t == 0) {
            const int bb = (b - 5632) * 4;
            qpart[bb + 0] = red[0] + red[4] + red[8]  + red[12];
            qpart[bb + 1] = red[1] + red[5] + red[9]  + red[13];
            qpart[bb + 2] = red[2] + red[6] + red[10] + red[14];
        }
    } else if (b < 5832) {
        const int bid = b - 5664;
        const float* A; short* At; int R, C, bx, by;
        if (bid < 144) { A = W1; At = w1t; R = EMB_D_; C = EMB_D_;  bx = (bid % 12) * 64; by = (bid / 12) * 64; }
        else { const int b2 = bid - 144; A = W2; At = w2t; R = EMB_D_; C = PROJ_D_; bx = (b2 & 1) * 64; by = (b2 >> 1) * 64; }
        const int tc = t & 63, tg = t >> 6;
        #pragma unroll
        for (int i = 0; i < 16; i++) {
            const int r = tg * 16 + i;
            tile[r][tc] = A[(size_t)(by + r) * C + bx + tc];
        }
        __syncthreads();
        #pragma unroll
        for (int i = 0; i < 16; i++) {
            const int r = tg * 16 + i;
            At[(size_t)(bx + r) * R + by + tc] = (short)f2bf(tile[tc][r]);
        }
    } else {
        // row-label census (plain store) + pc/done zero
        int c = 0;
        for (int j = t; j < BATCH_N; j += 256) c += (labels[j] == 0);
        #pragma unroll
        for (int o = 32; o > 0; o >>= 1) c += __shfl_xor(c, o);
        int* red = (int*)tile;
        if ((t & 63) == 0) red[t >> 6] = c;
        __syncthreads();
        if (t == 0) rcnt[0] = red[0] + red[1] + red[2] + red[3];
        if (t < 8) pc[t] = 0;
    }
}

// ---------------------------------------------------------------------------
// GEMM1: bf16 MFMA NT, 64x128 (MxN) tile, K-loop, fused bias+ReLU, bf16 out.
// ---------------------------------------------------------------------------
__global__ void __launch_bounds__(256) mfma_h64(const short* __restrict__ Ab,
                                                const short* __restrict__ Bb,
                                                const float* __restrict__ bias,
                                                short* __restrict__ C,
                                                int N, int K) {
    __shared__ __align__(16) short As[64 * 128];    // 16 KB
    __shared__ __align__(16) short Bs[128 * 128];   // 32 KB
    const int t = threadIdx.x;
    const int lane = t & 63, wv = t >> 6;
    const int l16 = lane & 15, l4 = lane >> 4;
    const int m0 = blockIdx.y * 64, n0 = blockIdx.x * 128;
    const int wn = wv * 32;

    f32x4 acc[4][2];
    #pragma unroll
    for (int i = 0; i < 4; ++i)
        #pragma unroll
        for (int j = 0; j < 2; ++j) acc[i][j] = f32x4{0.f, 0.f, 0.f, 0.f};

    for (int kb = 0; kb < K; kb += 128) {
        __syncthreads();
        #pragma unroll
        for (int it = 0; it < 4; ++it) {            // A: 16 units of 512 shorts
            const int r = it * 4 + wv, row = r * 4 + l4, cg = l16 ^ (row & 15);
            __builtin_amdgcn_global_load_lds(
                (const __attribute__((address_space(1))) void*)(Ab + (size_t)(m0 + row) * K + kb + cg * 8),
                (__attribute__((address_space(3))) void*)(As + r * 512), 16, 0, 0);
        }
        #pragma unroll
        for (int it = 0; it < 8; ++it) {            // B: 32 units
            const int r = it * 4 + wv, row = r * 4 + l4, cg = l16 ^ (row & 15);
            __builtin_amdgcn_global_load_lds(
                (const __attribute__((address_space(1))) void*)(Bb + (size_t)(n0 + row) * K + kb + cg * 8),
                (__attribute__((address_space(3))) void*)(Bs + r * 512), 16, 0, 0);
        }
        __syncthreads();
        #pragma unroll
        for (int ks = 0; ks < 4; ++ks) {
            short8 af[4], bfr[2];
            const int ch = (ks * 4 + l4) ^ l16;
            #pragma unroll
            for (int i = 0; i < 4; ++i)
                af[i] = *(const short8*)(As + (i * 16 + l16) * 128 + ch * 8);
            #pragma unroll
            for (int j = 0; j < 2; ++j)
                bfr[j] = *(const short8*)(Bs + (wn + j * 16 + l16) * 128 + ch * 8);
            #pragma unroll
            for (int i = 0; i < 4; ++i)
                #pragma unroll
                for (int j = 0; j < 2; ++j)
                    acc[i][j] = __builtin_amdgcn_mfma_f32_16x16x32_bf16(af[i], bfr[j], acc[i][j], 0, 0, 0);
        }
    }

    float bsv[2];
    #pragma unroll
    for (int j = 0; j < 2; ++j) bsv[j] = bias[n0 + wn + j * 16 + l16];
    #pragma unroll
    for (int i = 0; i < 4; ++i)
        #pragma unroll
        for (int r = 0; r < 4; ++r) {
            const int m = m0 + i * 16 + l4 * 4 + r;
            #pragma unroll
            for (int j = 0; j < 2; ++j) {
                const int n = n0 + wn + j * 16 + l16;
                const float v = fmaxf(acc[i][j][r] + bsv[j], 0.0f);
                C[(size_t)m * N + n] = (short)f2bf(v);
            }
        }
}

// ---------------------------------------------------------------------------
// Fused dispatch: z-GEMM (M-tile 32) + permutation builder.
// blocks 0..63: z-norm; 64..191: queue-col perm; 192..199: row perm.
// ---------------------------------------------------------------------------
__global__ void __launch_bounds__(256) znorm_perm(const short* __restrict__ Ab,
                                                  const short* __restrict__ Bb,
                                                  const float* __restrict__ bias,
                                                  short* __restrict__ zb,
                                                  const int* __restrict__ qlab,
                                                  const int* __restrict__ labels,
                                                  const int* __restrict__ qpart,
                                                  const int* __restrict__ rcnt,
                                                  int* __restrict__ qcnt,
                                                  int* __restrict__ colidx,
                                                  int* __restrict__ qlabp,
                                                  int* __restrict__ rowmap,
                                                  int* __restrict__ rlabp,
                                                  int* __restrict__ pc) {
    __shared__ __align__(16) short As[32 * 128];    // 8 KB
    __shared__ __align__(16) short Bs[128 * 128];   // 32 KB
    __shared__ float ssq[32];
    __shared__ int wcnt[4][3];
    __shared__ int gbase[3];
    const int blk = blockIdx.x;
    const int t = threadIdx.x;
    const int lane = t & 63, wv = t >> 6;

    if (blk >= 64) {
        const unsigned long long below = (1ull << lane) - 1ull;
        int q0 = 0, q1 = 0, qv = 0;
        for (int i = 0; i < 32; ++i) {
            q0 += qpart[i * 4]; q1 += qpart[i * 4 + 1]; qv += qpart[i * 4 + 2];
        }
        if (blk < 192) {
            const int cb = blk - 64;
            if (cb == 0 && t == 0) { qcnt[0] = q0; qcnt[1] = q1; qcnt[2] = qv; }
            const int j = cb * 256 + t;
            const int q = qlab[j];
            const int cls = (q == 0) ? 0 : ((q == 1) ? 1 : 2);
            const unsigned long long b0 = __ballot(cls == 0);
            const unsigned long long b1 = __ballot(cls == 1);
            const unsigned long long b2 = __ballot(cls == 2);
            const int rank = (cls == 0) ? __popcll(b0 & below)
                           : ((cls == 1) ? __popcll(b1 & below) : __popcll(b2 & below));
            if (lane == 0) {
                wcnt[wv][0] = __popcll(b0); wcnt[wv][1] = __popcll(b1); wcnt[wv][2] = __popcll(b2);
            }
            __syncthreads();
            if (t < 3) {
                const int tot = wcnt[0][t] + wcnt[1][t] + wcnt[2][t] + wcnt[3][t];
                gbase[t] = atomicAdd(&pc[t], tot);
            }
            __syncthreads();
            int wb = 0;
            #pragma unroll
            for (int w = 0; w < 4; ++w) if (w < wv) wb += wcnt[w][cls];
            const int cbase = (cls == 0) ? 0 : ((cls == 1) ? q0 : q0 + q1);
            const int pos = cbase + gbase[cls] + wb + rank;
            colidx[pos] = j; qlabp[pos] = q;
        } else {
            const int r = (blk - 192) * 256 + t;
            const int l = labels[r];
            const int cls = (l == 0) ? 0 : 1;
            const unsigned long long b0 = __ballot(cls == 0);
            const unsigned long long b1 = __ballot(cls == 1);
            const int rank = (cls == 0) ? __popcll(b0 & below) : __popcll(b1 & below);
            if (lane == 0) { wcnt[wv][0] = __popcll(b0); wcnt[wv][1] = __popcll(b1); }
            __syncthreads();
            if (t < 2) {
                const int tot = wcnt[0][t] + wcnt[1][t] + wcnt[2][t] + wcnt[3][t];
                gbase[t] = atomicAdd(&pc[3 + t], tot);
            }
            __syncthreads();
            int wb = 0;
            #pragma unroll
            for (int w = 0; w < 4; ++w) if (w < wv) wb += wcnt[w][cls];
            const int cbase = (cls == 0) ? 0 : rcnt[0];
            const int pos = cbase + gbase[cls] + wb + rank;
            rowmap[pos] = r; rlabp[pos] = l;
        }
        return;
    }

    // ---- z GEMM path: 32-row M-tile, fused bias + L2-normalize ----
    const int l16 = lane & 15, l4 = lane >> 4;
    const int m0 = blk * 32;
    const int wn = wv * 32;
    const int K = EMB_D_;

    if (t < 32) ssq[t] = 0.0f;

    f32x4 acc[2][2];
    #pragma unroll
    for (int i = 0; i < 2; ++i)
        #pragma unroll
        for (int j = 0; j < 2; ++j) acc[i][j] = f32x4{0.f, 0.f, 0.f, 0.f};

    for (int kb = 0; kb < K; kb += 128) {
        __syncthreads();
        #pragma unroll
        for (int it = 0; it < 2; ++it) {
            const int r = it * 4 + wv, row = r * 4 + l4, cg = l16 ^ (row & 15);
            __builtin_amdgcn_global_load_lds(
                (const __attribute__((address_space(1))) void*)(Ab + (size_t)(m0 + row) * K + kb + cg * 8),
                (__attribute__((address_space(3))) void*)(As + r * 512), 16, 0, 0);
        }
        #pragma unroll
        for (int it = 0; it < 8; ++it) {
            const int r = it * 4 + wv, row = r * 4 + l4, cg = l16 ^ (row & 15);
            __builtin_amdgcn_global_load_lds(
                (const __attribute__((address_space(1))) void*)(Bb + (size_t)(row) * K + kb + cg * 8),
                (__attribute__((address_space(3))) void*)(Bs + r * 512), 16, 0, 0);
        }
        __syncthreads();
        #pragma unroll
        for (int ks = 0; ks < 4; ++ks) {
            short8 af[2], bfr[2];
            const int ch = (ks * 4 + l4) ^ l16;
            #pragma unroll
            for (int i = 0; i < 2; ++i)
                af[i] = *(const short8*)(As + (i * 16 + l16) * 128 + ch * 8);
            #pragma unroll
            for (int j = 0; j < 2; ++j)
                bfr[j] = *(const short8*)(Bs + (wn + j * 16 + l16) * 128 + ch * 8);
            #pragma unroll
            for (int i = 0; i < 2; ++i)
                #pragma unroll
                for (int j = 0; j < 2; ++j)
                    acc[i][j] = __builtin_amdgcn_mfma_f32_16x16x32_bf16(af[i], bfr[j], acc[i][j], 0, 0, 0);
        }
    }

    float bsv[2];
    #pragma unroll
    for (int j = 0; j < 2; ++j) bsv[j] = bias[wn + j * 16 + l16];
    #pragma unroll
    for (int i = 0; i < 2; ++i)
        #pragma unroll
        for (int r = 0; r < 4; ++r) {
            float p = 0.0f;
            #pragma unroll
            for (int j = 0; j < 2; ++j) {
                acc[i][j][r] += bsv[j];
                p += acc[i][j][r] * acc[i][j][r];
            }
            #pragma unroll
            for (int o = 8; o > 0; o >>= 1) p += __shfl_xor(p, o);
            if (l16 == 0) atomicAdd(&ssq[i * 16 + l4 * 4 + r], p);
        }
    __syncthreads();
    #pragma unroll
    for (int i = 0; i < 2; ++i)
        #pragma unroll
        for (int r = 0; r < 4; ++r) {
            const int lrow = i * 16 + l4 * 4 + r;
            const float inv = rsqrtf(ssq[lrow]);
            #pragma unroll
            for (int j = 0; j < 2; ++j)
                zb[(size_t)(m0 + lrow) * PROJ_D_ + wn + j * 16 + l16] =
                    (short)f2bf(acc[i][j][r] * inv);
        }
}

// ---------------------------------------------------------------------------
// Combined dispatch, 48 KB LDS -> 3 blocks/CU (was 64 KB / 2):
//  blocks 0..2047:   masked queue GEMM -> u8 codes, 64-row M-tile,
//                    label-partitioned (half exit), register-prefetched
//                    gather indices (single vmcnt drain at block start).
//  blocks 2048..2559: S = z z^T 64x128 tile, packed bf16 out (backfills
//                    the CUs freed by exited mask8 blocks).
// ---------------------------------------------------------------------------
__global__ void __launch_bounds__(256) mask8_spack(const short* __restrict__ zb,
                                                   const short* __restrict__ qb,
                                                   unsigned char* __restrict__ codes,
                                                   const int* __restrict__ rlabp,
                                                   const int* __restrict__ qlabp,
                                                   const int* __restrict__ colidx,
                                                   const int* __restrict__ rowmap,
                                                   const int* __restrict__ qcnt,
                                                   const int* __restrict__ rcnt,
                                                   short* __restrict__ Sbuf) {
    __shared__ __align__(16) short As[64 * 128];    // 16 KB
    __shared__ __align__(16) short Bs[128 * 128];   // 32 KB
    const int bid = blockIdx.x, t = threadIdx.x;
    const int lane = t & 63, wv = t >> 6;
    const int l16 = lane & 15, l4 = lane >> 4;
    const int wm = (wv & 1) * 32, wn = (wv >> 1) * 64;

    if (bid >= 2048) {
        // ---- S GEMM tile (64x128) ----
        const int q = bid - 2048;
        const int m0 = (q >> 4) * 64, n0 = (q & 15) * 128;
        #pragma unroll
        for (int it = 0; it < 4; ++it) {
            const int r = it * 4 + wv, row = r * 4 + l4, cg = l16 ^ (row & 15);
            __builtin_amdgcn_global_load_lds(
                (const __attribute__((address_space(1))) void*)(zb + (size_t)(m0 + row) * 128 + cg * 8),
                (__attribute__((address_space(3))) void*)(As + r * 512), 16, 0, 0);
        }
        #pragma unroll
        for (int it = 0; it < 8; ++it) {
            const int r = it * 4 + wv, row = r * 4 + l4, cg = l16 ^ (row & 15);
            __builtin_amdgcn_global_load_lds(
                (const __attribute__((address_space(1))) void*)(zb + (size_t)(n0 + row) * 128 + cg * 8),
                (__attribute__((address_space(3))) void*)(Bs + r * 512), 16, 0, 0);
        }
        __syncthreads();

        f32x4 acc[2][4];
        #pragma unroll
        for (int i = 0; i < 2; ++i)
            #pragma unroll
            for (int j = 0; j < 4; ++j) acc[i][j] = f32x4{0.f, 0.f, 0.f, 0.f};

        #pragma unroll
        for (int ks = 0; ks < 4; ++ks) {
            short8 af[2], bfr[4];
            const int ch = (ks * 4 + l4) ^ l16;
            #pragma unroll
            for (int i = 0; i < 2; ++i)
                af[i]  = *(const short8*)(As + (wm + i * 16 + l16) * 128 + ch * 8);
            #pragma unroll
            for (int j = 0; j < 4; ++j)
                bfr[j] = *(const short8*)(Bs + (wn + j * 16 + l16) * 128 + ch * 8);
            #pragma unroll
            for (int i = 0; i < 2; ++i)
                #pragma unroll
                for (int j = 0; j < 4; ++j)
                    acc[i][j] = __builtin_amdgcn_mfma_f32_16x16x32_bf16(af[i], bfr[j], acc[i][j], 0, 0, 0);
        }
        #pragma unroll
        for (int i = 0; i < 2; ++i)
            #pragma unroll
            for (int r = 0; r < 4; ++r) {
                const int m = m0 + wm + i * 16 + l4 * 4 + r;
                union { unsigned short u[4]; uint2 d; } pk;
                #pragma unroll
                for (int j = 0; j < 4; ++j) pk.u[j] = f2bf(acc[i][j][r]);
                *(uint2*)(Sbuf + (size_t)m * BATCH_N + n0 + wn + l16 * 4) = pk.d;
            }
        return;
    }

    // ---- mask8 path (64-row M-tile) ----
    const int bx = bid & 63, by = bid >> 6;
    const int m0 = by * 64;
    const int c0 = qcnt[0], c1v = qcnt[1], r0 = rcnt[0];
    int lo, hi;
    if (m0 + 64 <= r0)  { lo = c0; hi = c0 + c1v; }   // label-0 rows -> label-1 cols
    else if (m0 >= r0)  { lo = 0;  hi = c0; }         // label-1 rows -> label-0 cols
    else                { lo = 0;  hi = c0 + c1v; }   // mixed boundary tile
    const int bs = bx * 512;
    if (bs + 512 <= lo || bs >= hi) return;           // uniform block exit

    // prefetch all indirection into registers (one wait, then pure ALU)
    int ra[4], ca[32], la[8], qa[16];
    #pragma unroll
    for (int it = 0; it < 4; ++it)
        ra[it] = rowmap[m0 + (it * 4 + wv) * 4 + l4];
    #pragma unroll
    for (int tt = 0; tt < 4; ++tt)
        #pragma unroll
        for (int it = 0; it < 8; ++it)
            ca[tt * 8 + it] = colidx[bs + tt * 128 + (it * 4 + wv) * 4 + l4];
    #pragma unroll
    for (int i = 0; i < 2; ++i)
        #pragma unroll
        for (int r = 0; r < 4; ++r)
            la[i * 4 + r] = rlabp[m0 + wm + i * 16 + l4 * 4 + r];
    #pragma unroll
    for (int tt = 0; tt < 4; ++tt)
        #pragma unroll
        for (int j = 0; j < 4; ++j)
            qa[tt * 4 + j] = qlabp[bs + tt * 128 + wn + j * 16 + l16];

    #pragma unroll
    for (int it = 0; it < 4; ++it) {
        const int r = it * 4 + wv, row = r * 4 + l4, cg = l16 ^ (row & 15);
        __builtin_amdgcn_global_load_lds(
            (const __attribute__((address_space(1))) void*)(zb + (size_t)ra[it] * 128 + cg * 8),
            (__attribute__((address_space(3))) void*)(As + r * 512), 16, 0, 0);
    }
    #pragma unroll
    for (int it = 0; it < 8; ++it) {
        const int r = it * 4 + wv, row = r * 4 + l4, cg = l16 ^ (row & 15);
        __builtin_amdgcn_global_load_lds(
            (const __attribute__((address_space(1))) void*)(qb + (size_t)ca[it] * 128 + cg * 8),
            (__attribute__((address_space(3))) void*)(Bs + r * 512), 16, 0, 0);
    }
    const float C0 = 1.0f - WLO * S8ENC;
    __syncthreads();

    #pragma unroll
    for (int tt = 0; tt < 4; ++tt) {
        const int n0 = bs + tt * 128;

        f32x4 acc[2][4];
        #pragma unroll
        for (int i = 0; i < 2; ++i)
            #pragma unroll
            for (int j = 0; j < 4; ++j) acc[i][j] = f32x4{0.f, 0.f, 0.f, 0.f};

        #pragma unroll
        for (int ks = 0; ks < 4; ++ks) {
            short8 af[2], bfr[4];
            const int ch = (ks * 4 + l4) ^ l16;
            #pragma unroll
            for (int i = 0; i < 2; ++i)
                af[i]  = *(const short8*)(As + (wm + i * 16 + l16) * 128 + ch * 8);
            #pragma unroll
            for (int j = 0; j < 4; ++j)
                bfr[j] = *(const short8*)(Bs + (wn + j * 16 + l16) * 128 + ch * 8);
            #pragma unroll
            for (int i = 0; i < 2; ++i)
                #pragma unroll
                for (int j = 0; j < 4; ++j)
                    acc[i][j] = __builtin_amdgcn_mfma_f32_16x16x32_bf16(af[i], bfr[j], acc[i][j], 0, 0, 0);
        }

        if (tt < 3) {
            __syncthreads();          // all waves done reading Bs tile tt
            #pragma unroll
            for (int it = 0; it < 8; ++it) {
                const int r = it * 4 + wv, row = r * 4 + l4, cg = l16 ^ (row & 15);
                __builtin_amdgcn_global_load_lds(
                    (const __attribute__((address_space(1))) void*)(qb + (size_t)ca[(tt + 1) * 8 + it] * 128 + cg * 8),
                    (__attribute__((address_space(3))) void*)(Bs + r * 512), 16, 0, 0);
            }
        }

        // epilogue for this tile (overlaps next tile's B staging)
        float a0[4], a1[4];
        #pragma unroll
        for (int j = 0; j < 4; ++j) {
            const int q = qa[tt * 4 + j];
            a0[j] = (q >= 0 && q != 0) ? C0 : -1e9f;
            a1[j] = (q >= 0 && q != 1) ? C0 : -1e9f;
        }
        #pragma unroll
        for (int i = 0; i < 2; ++i) {
            #pragma unroll
            for (int r = 0; r < 4; ++r) {
                const int m  = m0 + wm + i * 16 + l4 * 4 + r;
                const bool z = (la[i * 4 + r] == 0);
                unsigned pk = 0;
                #pragma unroll
                for (int j = 0; j < 4; ++j) {
                    const float add = z ? a0[j] : a1[j];
                    const float f = fmaf(acc[i][j][r], S8ENC, add);
#if __has_builtin(__builtin_amdgcn_cvt_pk_u8_f32)
                    pk = __builtin_amdgcn_cvt_pk_u8_f32(f, j, pk);
#else
                    const unsigned c = (unsigned)fminf(fmaxf(f, 0.0f), 255.0f);
                    pk |= c << (8 * j);
#endif
                }
                *(unsigned*)(codes + (size_t)m * QUEUE_N + n0 + wn + l16 * 4) = pk;
            }
        }
        if (tt < 3) __syncthreads();  // next tile's B staged (barrier drains vmcnt)
    }
}

// ---------------------------------------------------------------------------
// Histogram crossing search (used by inline fallback)
// ---------------------------------------------------------------------------
__device__ __forceinline__ void find_crossing(int* hist, int* grp, int target,
                                              int* s_bin, int* s_chi) {
    const int t = threadIdx.x;
    const int b0 = hist[4*t], b1 = hist[4*t+1], b2 = hist[4*t+2], b3 = hist[4*t+3];
    grp[t] = b0 + b1 + b2 + b3;
    __syncthreads();
    for (int off = 1; off < 256; off <<= 1) {
        int add = (t + off < 256) ? grp[t + off] : 0;
        __syncthreads();
        grp[t] += add;
        __syncthreads();
    }
    int cab = (t < 255) ? grp[t + 1] : 0;
    const int hb[4] = {b0, b1, b2, b3};
    #pragma unroll
    for (int i = 3; i >= 0; i--) {
        const int h = hb[i];
        if (cab < target && cab + h >= target) { *s_bin = 4*t + i; *s_chi = cab; }
        cab += h;
    }
    __syncthreads();
}

// iterate all 128 packed-half2 values
#define FOR_ALL_VALS(BODY)                                                   \
    _Pragma("unroll")                                                        \
    for (int _k = 0; _k < 64; _k++) {                                        \
        const float2 _f = __half22float2(*(const __half2*)&dv[_k]);          \
        { const float v = _f.x; BODY }                                       \
        { const float v = _f.y; BODY }                                       \
    }

// ---------------------------------------------------------------------------
// topk lse from codes (partitioned row p, opposite-label span only) with the
// exact fallback INLINE on failure. SMALL LDS (~7 KB) -> high occupancy.
// Per-wave split histograms (4x256) cut same-address LDS conflicts 4x.
// ---------------------------------------------------------------------------
__global__ void __launch_bounds__(256) topk_fb(const unsigned char* __restrict__ codes,
                                               const int* __restrict__ qcnt,
                                               const int* __restrict__ rlabp,
                                               const int* __restrict__ rowmap,
                                               const short* __restrict__ zb,
                                               const short* __restrict__ qb,
                                               const int* __restrict__ qlab,
                                               float* __restrict__ lseq) {
    __shared__ int hist4[1024];          // 4 per-wave hists; reused as fh by fallback
    __shared__ int grp[256];             // suffix-scan buffer; reused by fallback
    __shared__ float zrow[128];
    __shared__ int s_bin, s_chi, s_bin2, s_chi2;
    __shared__ float scf[4];
    __shared__ int sci[4];
    const int p = blockIdx.x, t = threadIdx.x;
    const int orig  = rowmap[p];
    const int myLab = rlabp[p];
    const int opp   = opp_of(myLab, qcnt);

    if (opp >= HARD_K_) {
        for (int k = t; k < 1024; k += 256) hist4[k] = 0;
        __syncthreads();

        const int c0 = qcnt[0];
        const int lo = (myLab == 0) ? c0 : 0;
        const int hi = (myLab == 0) ? c0 + qcnt[1] : c0;
        const int klo = (lo & ~511) >> 4;            // uint4 index (16 cols each)
        const int khi = ((hi + 511) & ~511) >> 4;

        int* myh = hist4 + (t >> 6) * 256;
        const uint4* rowp = (const uint4*)(codes + (size_t)p * QUEUE_N);
        for (int k = klo + t; k < khi; k += 256) {
            const uint4 u = rowp[k];
            const unsigned w[4] = {u.x, u.y, u.z, u.w};
            #pragma unroll
            for (int q = 0; q < 4; q++)
                #pragma unroll
                for (int s = 0; s < 4; s++) {
                    const int c = (w[q] >> (8 * s)) & 0xFF;
                    if (c) atomicAdd(&myh[c], 1);
                }
        }
        __syncthreads();
        const int h = hist4[t] + hist4[256 + t] + hist4[512 + t] + hist4[768 + t];
        grp[t] = h;
        __syncthreads();
        for (int off = 1; off < 256; off <<= 1) {
            int add = (t + off < 256) ? grp[t + off] : 0;
            __syncthreads();
            grp[t] += add;
            __syncthreads();
        }
        const int total = grp[1];
        if (total >= HARD_K_) {
            {
                const int above = (t < 255) ? grp[t + 1] : 0;
                if (grp[t] >= HARD_K_ && above < HARD_K_) s_bin = t;
            }
            __syncthreads();
            const int b = s_bin;

            float e = 0.0f;
            if (t > b && h) e = (float)h * __expf((WLO + ((float)t - 0.5f) * BINW - 1.0f) * INV_T);
            #pragma unroll
            for (int o = 32; o > 0; o >>= 1) e += __shfl_xor(e, o);
            if ((t & 63) == 0) scf[t >> 6] = e;
            __syncthreads();
            if (t == 0) {
                const float Eab  = scf[0] + scf[1] + scf[2] + scf[3];
                const int   cab  = (b < 255) ? grp[b + 1] : 0;
                const float ebin = __expf((WLO + ((float)b - 0.5f) * BINW - 1.0f) * INV_T);
                const float sadj = Eab + (float)(HARD_K_ - cab) * ebin;
                lseq[orig] = INV_T + __logf(sadj);
            }
            return;
        }
        __syncthreads();   // hist path failed; safe to reuse LDS below
    }

    // ---- exact fallback, inline (rare) ----
    int* fh = hist4;
    if (t < 128) zrow[t] = bf2f(zb[(size_t)orig * 128 + t]);
    __syncthreads();

    const int mylab = myLab;
    unsigned dv[64];
    float rm = -1e30f, rs = 0.0f;
    for (int k = 0; k < 128; k++) {
        const int j = t + 256 * k;
        float d = 0.0f;
        #pragma unroll
        for (int c = 0; c < 16; ++c) {
            const short8 qv = *(const short8*)(qb + (size_t)j * 128 + c * 8);
            #pragma unroll
            for (int e = 0; e < 8; ++e) d += zrow[c * 8 + e] * bf2f(qv[e]);
        }
        if (j < HARD_K_) {
            const float sv = d * INV_T;
            if (sv > rm) { rs = rs * __expf(rm - sv) + 1.0f; rm = sv; }
            else         { rs += __expf(sv - rm); }
        }
        const int q = qlab[j];
        const float mv = (q != mylab && q >= 0) ? d : -65504.0f;
        const __half h = __float2half(mv);
        unsigned short* pp = (unsigned short*)&dv[k >> 1];
        pp[k & 1] = *(const unsigned short*)&h;
    }

    if (opp == 0) {
        #pragma unroll
        for (int o = 32; o > 0; o >>= 1) {
            const float om = __shfl_xor(rm, o), os = __shfl_xor(rs, o);
            const float nm = fmaxf(rm, om);
            rs = rs * __expf(rm - nm) + os * __expf(om - nm);
            rm = nm;
        }
        if ((t & 63) == 0) { scf[t >> 6] = rm; ((float*)sci)[t >> 6] = rs; }
        __syncthreads();
        if (t == 0) {
            float M = -1e30f, Sx = 0.0f;
            for (int w = 0; w < 4; w++) {
                const float nm = fmaxf(M, scf[w]);
                Sx = Sx * __expf(M - nm) + ((float*)sci)[w] * __expf(scf[w] - nm);
                M = nm;
            }
            lseq[orig] = M + __logf(Sx);
        }
        return;
    }
    if (opp < HARD_K_) {
        float mm = -1e30f, ss = 0.0f;
        FOR_ALL_VALS(
            if (v > -60000.0f) {
                const float sv = v * INV_T;
                if (sv > mm) { ss = ss * __expf(mm - sv) + 1.0f; mm = sv; }
                else         { ss += __expf(sv - mm); }
            } )
        #pragma unroll
        for (int o = 32; o > 0; o >>= 1) {
            const float om = __shfl_xor(mm, o), os = __shfl_xor(ss, o);
            const float nm = fmaxf(mm, om);
            ss = ss * __expf(mm - nm) + os * __expf(om - nm);
            mm = nm;
        }
        if ((t & 63) == 0) { scf[t >> 6] = mm; ((float*)sci)[t >> 6] = ss; }
        __syncthreads();
        if (t == 0) {
            float M = -1e30f, Sx = 0.0f;
            for (int w = 0; w < 4; w++) {
                const float nm = fmaxf(M, scf[w]);
                Sx = Sx * __expf(M - nm) + ((float*)sci)[w] * __expf(scf[w] - nm);
                M = nm;
            }
            lseq[orig] = M + __logf(Sx);
        }
        return;
    }

    float mloc = -1e30f;
    FOR_ALL_VALS( mloc = fmaxf(mloc, v); )
    #pragma unroll
    for (int o = 32; o > 0; o >>= 1) mloc = fmaxf(mloc, __shfl_xor(mloc, o));
    if ((t & 63) == 0) scf[t >> 6] = mloc;
    __syncthreads();
    const float m = fmaxf(fmaxf(scf[0], scf[1]), fmaxf(scf[2], scf[3]));

    int c1 = 0, c2 = 0;
    const float w1 = m - 0.25f, w2 = m - 1.0f;
    FOR_ALL_VALS( c1 += (v >= w1); c2 += (v >= w2); )
    #pragma unroll
    for (int o = 32; o > 0; o >>= 1) { c1 += __shfl_xor(c1, o); c2 += __shfl_xor(c2, o); }
    if ((t & 63) == 0) { sci[t >> 6] = c1; }
    __syncthreads();
    const int C1 = sci[0] + sci[1] + sci[2] + sci[3];
    __syncthreads();
    if ((t & 63) == 0) { sci[t >> 6] = c2; }
    __syncthreads();
    const int C2 = sci[0] + sci[1] + sci[2] + sci[3];

    float lo;
    if      (C1 >= HARD_K_) lo = w1;
    else if (C2 >= HARD_K_) lo = w2;
    else                    lo = -1.01f;
    const float range = m - lo;
    const float scale = 1024.0f / range;

    for (int k = t; k < 1024; k += 256) fh[k] = 0;
    __syncthreads();
    FOR_ALL_VALS(
        if (v >= lo) {
            const float bf = fminf((v - lo) * scale, 1023.0f);
            atomicAdd(&fh[(int)bf], 1);
        } )
    __syncthreads();
    find_crossing(fh, grp, HARD_K_, &s_bin, &s_chi);
    const int   bin1 = s_bin, chi1 = s_chi;
    const float binw = range * (1.0f / 1024.0f);
    const float lo1  = lo + bin1 * binw;
    const float ssc  = 1024.0f / binw;

    for (int k = t; k < 1024; k += 256) fh[k] = 0;
    __syncthreads();
    FOR_ALL_VALS(
        if (v >= lo) {
            const float bf = fminf((v - lo) * scale, 1023.0f);
            if ((int)bf == bin1) {
                const float sf = fminf(fmaxf((v - lo1) * ssc, 0.0f), 1023.0f);
                atomicAdd(&fh[(int)sf], 1);
            }
        } )
    __syncthreads();
    find_crossing(fh, grp, HARD_K_ - chi1, &s_bin2, &s_chi2);
    const float thr = lo1 + s_bin2 * (binw * (1.0f / 1024.0f));

    float sl = 0.0f; int cg = 0;
    FOR_ALL_VALS( if (v > thr) { cg++; sl += __expf((v - m) * INV_T); } )
    #pragma unroll
    for (int o = 32; o > 0; o >>= 1) { sl += __shfl_xor(sl, o); cg += __shfl_xor(cg, o); }
    if ((t & 63) == 0) { scf[t >> 6] = sl; sci[t >> 6] = cg; }
    __syncthreads();
    if (t == 0) {
        const float slt = scf[0] + scf[1] + scf[2] + scf[3];
        const int   cgt = sci[0] + sci[1] + sci[2] + sci[3];
        const float sadj = slt + ((float)HARD_K_ - (float)cgt) * __expf((thr - m) * INV_T);
        lseq[orig] = m * INV_T + __logf(sadj);
    }
}

// ---------------------------------------------------------------------------
// Batch lse + positive-pair loss over packed bf16 S, with fused final reduce:
// last block (device-scope atomic counter) sums all partials -> out[0].
// All cross-block traffic via device-scope atomics (XCD-safe).
// ---------------------------------------------------------------------------
__global__ void __launch_bounds__(256) brl_final(const short* __restrict__ S,
                                                 const int* __restrict__ labels,
                                                 const float* __restrict__ lse_queue,
                                                 float* __restrict__ part_out,
                                                 int* __restrict__ cnt_out,
                                                 int* __restrict__ done,
                                                 float* __restrict__ out) {
    const int t = threadIdx.x;
    const int wv = t >> 6, lane = t & 63;
    const int row = blockIdx.x * 4 + wv;
    __shared__ int plab[BATCH_N];      // labels in packed order
    __shared__ int s_last;
    for (int idx = t; idx < BATCH_N; idx += 256) {
        const int col = (idx & ~63) + ((idx & 3) << 4) + ((idx >> 2) & 15);
        plab[idx] = labels[col];
    }
    __syncthreads();
    const int myLab = labels[row];
    const uint4* rp = (const uint4*)(S + (size_t)row * BATCH_N);  // 8 bf16 per uint4

    float v[32]; int lb[32];
    #pragma unroll
    for (int kk = 0; kk < 4; kk++) {
        const uint4 u = rp[lane + 64 * kk];
        const unsigned w[4] = {u.x, u.y, u.z, u.w};
        const int base = (lane + 64 * kk) * 8;
        #pragma unroll
        for (int q = 0; q < 4; q++) {
            v[kk * 8 + 2 * q]     = __uint_as_float(w[q] << 16);
            v[kk * 8 + 2 * q + 1] = __uint_as_float(w[q] & 0xFFFF0000u);
            lb[kk * 8 + 2 * q]     = plab[base + 2 * q];
            lb[kk * 8 + 2 * q + 1] = plab[base + 2 * q + 1];
        }
    }

    const float REF = INV_T;
    float sneg = 0.0f;
    #pragma unroll
    for (int k = 0; k < 32; k++) {
        const float ev = __expf(v[k] * INV_T - REF);
        sneg += (lb[k] != myLab) ? ev : 0.0f;
    }
    #pragma unroll
    for (int o = 32; o > 0; o >>= 1) sneg += __shfl_xor(sneg, o);
    const float lseb = (sneg > 0.0f) ? REF + __logf(sneg) : -1e30f;
    const float Lq = lse_queue[row];
    const float mx0 = fmaxf(lseb, Lq), mn0 = fminf(lseb, Lq);
    const float L = mx0 + __logf(1.0f + __expf(mn0 - mx0));

    float part = 0.0f; int cnt = 0;
    #pragma unroll
    for (int k = 0; k < 32; k++) {
        const int idx = ((lane + 64 * (k >> 3)) * 8) + (k & 7);
        const int col = (idx & ~63) + ((idx & 3) << 4) + ((idx >> 2) & 15);
        if (lb[k] == myLab && col != row) {
            const float sv = v[k] * INV_T;
            const float mx = fmaxf(sv, L), mn = fminf(sv, L);
            part += (mx - sv) + __logf(1.0f + __expf(mn - mx));
            cnt++;
        }
    }
    #pragma unroll
    for (int o = 32; o > 0; o >>= 1) { part += __shfl_xor(part, o); cnt += __shfl_xor(cnt, o); }
    if (lane == 0) {
        atomicExch(&part_out[row], part);       // device-scope visible
        atomicExch(&cnt_out[row], cnt);
        __threadfence();
    }
    __syncthreads();
    if (t == 0) s_last = (atomicAdd(done, 1) == (int)gridDim.x - 1);
    __syncthreads();
    if (!s_last) return;

    // ---- final reduce (last block; reads via device-scope atomics) ----
    __threadfence();
    float s = 0.0f; int c = 0;
    #pragma unroll
    for (int k = 0; k < 8; k++) {
        const int idx = t + 256 * k;
        s += atomicAdd(&part_out[idx], 0.0f);
        c += atomicAdd(&cnt_out[idx], 0);
    }
    #pragma unroll
    for (int o = 32; o > 0; o >>= 1) { s += __shfl_xor(s, o); c += __shfl_xor(c, o); }
    __shared__ float sf[4]; __shared__ int sc[4];
    if ((t & 63) == 0) { sf[t >> 6] = s; sc[t >> 6] = c; }
    __syncthreads();
    if (t == 0) {
        const float st = sf[0] + sf[1] + sf[2] + sf[3];
        const int   ct = sc[0] + sc[1] + sc[2] + sc[3];
        out[0] = (ct > 0) ? (st / (float)ct) : 0.0f;
    }
}

// ---------------------------------------------------------------------------
extern "C" void kernel_launch(void* const* d_in, const int* in_sizes, int n_in,
                              void* d_out, int out_size, void* d_ws, size_t ws_size,
                              hipStream_t stream) {
    const float* emb    = (const float*)d_in[0];
    const int*   labels = (const int*)  d_in[1];
    const float* W1     = (const float*)d_in[2];
    const float* b1     = (const float*)d_in[3];
    const float* W2     = (const float*)d_in[4];
    const float* b2     = (const float*)d_in[5];
    const float* queue  = (const float*)d_in[6];
    const int*   qlab   = (const int*)  d_in[7];

    char* ws = (char*)d_ws;
    short*         Sbuf  = (short*)        (ws);              // 8 MB used (16 MB region)
    unsigned char* codes = (unsigned char*)(ws + 16777216);   // 64 MB
    short*         embb  = (short*)        (ws + 83886080);   // 3145728
    short*         hbf   = (short*)        (ws + 87031808);   // 3145728
    short*         zb    = (short*)        (ws + 90177536);   // 524288
    short*         qb    = (short*)        (ws + 90701824);   // 8388608
    short*         w1t   = (short*)        (ws + 99090432);   // 1179648
    short*         w2t   = (short*)        (ws + 100270080);  // 196608
    float*         lseq  = (float*)        (ws + 100466688);  // 8192
    int*           qcnt  = (int*)          (ws + 100474880);  // 64
    int*           rcnt  = (int*)          (ws + 100474944);  // 64
    int*           pc    = (int*)          (ws + 100475008);  // 64 (pc[0..4]=perm, pc[6]=done)
    int*           qpart = (int*)          (ws + 100475072);  // 512
    float*         partb = (float*)        (ws + 100475584);  // 8192
    int*           cntb  = (int*)          (ws + 100483776);  // 8192
    int*           colidx= (int*)          (ws + 100491968);  // 131072
    int*           qlabp = (int*)          (ws + 100623040);  // 131072
    int*           rowmap= (int*)          (ws + 100754112);  // 8192
    int*           rlabp = (int*)          (ws + 100762304);  // 8192

    dim3 blk(256);
    prep<<<dim3(5833), blk, 0, stream>>>(emb, embb, queue, qb, qlab, qpart, W1, w1t, W2, w2t, labels, rcnt, pc);
    mfma_h64<<<dim3(EMB_D_ / 128, BATCH_N / 64), blk, 0, stream>>>(embb, w1t, b1, hbf, EMB_D_, EMB_D_);
    znorm_perm<<<dim3(200), blk, 0, stream>>>(hbf, w2t, b2, zb, qlab, labels, qpart, rcnt,
                                              qcnt, colidx, qlabp, rowmap, rlabp, pc);
    mask8_spack<<<dim3(2560), blk, 0, stream>>>(zb, qb, codes, rlabp, qlabp, colidx, rowmap, qcnt, rcnt, Sbuf);
    topk_fb<<<dim3(BATCH_N), blk, 0, stream>>>(codes, qcnt, rlabp, rowmap, zb, qb, qlab, lseq);
    brl_final<<<dim3(BATCH_N / 4), blk, 0, stream>>>(Sbuf, labels, lseq, partb, cntb, pc + 6, (float*)d_out);
}

// Round 5
// 158.096 us; speedup vs baseline: 1.2184x; 1.1750x over previous
//
#include <hip/hip_runtime.h>
#include <hip/hip_fp16.h>

#define BATCH_N   2048
#define EMB_D_    768
#define PROJ_D_   128
#define QUEUE_N   32768
#define HARD_K_   512
static constexpr float INV_T  = 1.0f / 0.07f;
static constexpr float WLO    = 0.12f;              // code-0 boundary (512th opp val ~0.164)
static constexpr float S8ENC  = 255.0f / 0.88f;     // encode scale
static constexpr float BINW   = 0.88f / 255.0f;     // code bin width

typedef __attribute__((ext_vector_type(8))) short short8;
typedef __attribute__((ext_vector_type(4))) short short4v;
typedef __attribute__((ext_vector_type(4))) float f32x4;

__device__ __forceinline__ unsigned short f2bf(float f) {
    unsigned u = __float_as_uint(f);
    unsigned r = u + 0x7fffu + ((u >> 16) & 1u);   // RNE
    return (unsigned short)(r >> 16);
}
__device__ __forceinline__ float bf2f(short s) {
    return __uint_as_float(((unsigned)(unsigned short)s) << 16);
}
__device__ __forceinline__ int opp_of(int mylab, const int* __restrict__ qcnt) {
    const int same = (mylab == 0) ? qcnt[0] : ((mylab == 1) ? qcnt[1] : 0);
    return qcnt[2] - same;
}

// ---------------------------------------------------------------------------
// Merged prep: emb cast + queue cast + qlab census (plain partial stores) +
// W1/W2 transpose + row census + pc zero. No memset dispatch needed.
// ---------------------------------------------------------------------------
__global__ void __launch_bounds__(256) prep(const float* __restrict__ emb, short* __restrict__ embb,
                                            const float* __restrict__ queue, short* __restrict__ qb,
                                            const int* __restrict__ qlab, int* __restrict__ qpart,
                                            const float* __restrict__ W1, short* __restrict__ w1t,
                                            const float* __restrict__ W2, short* __restrict__ w2t,
                                            const int* __restrict__ labels, int* __restrict__ rcnt,
                                            int* __restrict__ pc) {
    __shared__ float tile[64][65];
    const int b = blockIdx.x, t = threadIdx.x;
    if (b < 1536) {
        const int i = b * 256 + t;
        const float4 f = ((const float4*)emb)[i];
        short4v o = {(short)f2bf(f.x), (short)f2bf(f.y), (short)f2bf(f.z), (short)f2bf(f.w)};
        ((short4v*)embb)[i] = o;
    } else if (b < 5632) {
        const int i = (b - 1536) * 256 + t;
        const float4 f = ((const float4*)queue)[i];
        short4v o = {(short)f2bf(f.x), (short)f2bf(f.y), (short)f2bf(f.z), (short)f2bf(f.w)};
        ((short4v*)qb)[i] = o;
    } else if (b < 5664) {
        const int i = (b - 5632) * 256 + t;
        int c0 = 0, c1 = 0, cv = 0;
        for (int j = i; j < QUEUE_N; j += 8192) {
            const int q = qlab[j];
            c0 += (q == 0); c1 += (q == 1); cv += (q >= 0);
        }
        #pragma unroll
        for (int o = 32; o > 0; o >>= 1) {
            c0 += __shfl_xor(c0, o); c1 += __shfl_xor(c1, o); cv += __shfl_xor(cv, o);
        }
        int* red = (int*)tile;
        const int wv = t >> 6;
        if ((t & 63) == 0) { red[wv * 4 + 0] = c0; red[wv * 4 + 1] = c1; red[wv * 4 + 2] = cv; }
        __syncthreads();
        if (t == 0) {
            const int bb = (b - 5632) * 4;
            qpart[bb + 0] = red[0] + red[4] + red[8]  + red[12];
            qpart[bb + 1] = red[1] + red[5] + red[9]  + red[13];
            qpart[bb + 2] = red[2] + red[6] + red[10] + red[14];
        }
    } else if (b < 5832) {
        const int bid = b - 5664;
        const float* A; short* At; int R, C, bx, by;
        if (bid < 144) { A = W1; At = w1t; R = EMB_D_; C = EMB_D_;  bx = (bid % 12) * 64; by = (bid / 12) * 64; }
        else { const int b2 = bid - 144; A = W2; At = w2t; R = EMB_D_; C = PROJ_D_; bx = (b2 & 1) * 64; by = (b2 >> 1) * 64; }
        const int tc = t & 63, tg = t >> 6;
        #pragma unroll
        for (int i = 0; i < 16; i++) {
            const int r = tg * 16 + i;
            tile[r][tc] = A[(size_t)(by + r) * C + bx + tc];
        }
        __syncthreads();
        #pragma unroll
        for (int i = 0; i < 16; i++) {
            const int r = tg * 16 + i;
            At[(size_t)(bx + r) * R + by + tc] = (short)f2bf(tile[tc][r]);
        }
    } else {
        // row-label census (plain store) + pc zero
        int c = 0;
        for (int j = t; j < BATCH_N; j += 256) c += (labels[j] == 0);
        #pragma unroll
        for (int o = 32; o > 0; o >>= 1) c += __shfl_xor(c, o);
        int* red = (int*)tile;
        if ((t & 63) == 0) red[t >> 6] = c;
        __syncthreads();
        if (t == 0) rcnt[0] = red[0] + red[1] + red[2] + red[3];
        if (t < 8) pc[t] = 0;
    }
}

// ---------------------------------------------------------------------------
// GEMM1: bf16 MFMA NT, 64x128 (MxN) tile, K-loop, fused bias+ReLU, bf16 out.
// ---------------------------------------------------------------------------
__global__ void __launch_bounds__(256) mfma_h64(const short* __restrict__ Ab,
                                                const short* __restrict__ Bb,
                                                const float* __restrict__ bias,
                                                short* __restrict__ C,
                                                int N, int K) {
    __shared__ __align__(16) short As[64 * 128];    // 16 KB
    __shared__ __align__(16) short Bs[128 * 128];   // 32 KB
    const int t = threadIdx.x;
    const int lane = t & 63, wv = t >> 6;
    const int l16 = lane & 15, l4 = lane >> 4;
    const int m0 = blockIdx.y * 64, n0 = blockIdx.x * 128;
    const int wn = wv * 32;

    f32x4 acc[4][2];
    #pragma unroll
    for (int i = 0; i < 4; ++i)
        #pragma unroll
        for (int j = 0; j < 2; ++j) acc[i][j] = f32x4{0.f, 0.f, 0.f, 0.f};

    for (int kb = 0; kb < K; kb += 128) {
        __syncthreads();
        #pragma unroll
        for (int it = 0; it < 4; ++it) {            // A: 16 units of 512 shorts
            const int r = it * 4 + wv, row = r * 4 + l4, cg = l16 ^ (row & 15);
            __builtin_amdgcn_global_load_lds(
                (const __attribute__((address_space(1))) void*)(Ab + (size_t)(m0 + row) * K + kb + cg * 8),
                (__attribute__((address_space(3))) void*)(As + r * 512), 16, 0, 0);
        }
        #pragma unroll
        for (int it = 0; it < 8; ++it) {            // B: 32 units
            const int r = it * 4 + wv, row = r * 4 + l4, cg = l16 ^ (row & 15);
            __builtin_amdgcn_global_load_lds(
                (const __attribute__((address_space(1))) void*)(Bb + (size_t)(n0 + row) * K + kb + cg * 8),
                (__attribute__((address_space(3))) void*)(Bs + r * 512), 16, 0, 0);
        }
        __syncthreads();
        #pragma unroll
        for (int ks = 0; ks < 4; ++ks) {
            short8 af[4], bfr[2];
            const int ch = (ks * 4 + l4) ^ l16;
            #pragma unroll
            for (int i = 0; i < 4; ++i)
                af[i] = *(const short8*)(As + (i * 16 + l16) * 128 + ch * 8);
            #pragma unroll
            for (int j = 0; j < 2; ++j)
                bfr[j] = *(const short8*)(Bs + (wn + j * 16 + l16) * 128 + ch * 8);
            #pragma unroll
            for (int i = 0; i < 4; ++i)
                #pragma unroll
                for (int j = 0; j < 2; ++j)
                    acc[i][j] = __builtin_amdgcn_mfma_f32_16x16x32_bf16(af[i], bfr[j], acc[i][j], 0, 0, 0);
        }
    }

    float bsv[2];
    #pragma unroll
    for (int j = 0; j < 2; ++j) bsv[j] = bias[n0 + wn + j * 16 + l16];
    #pragma unroll
    for (int i = 0; i < 4; ++i)
        #pragma unroll
        for (int r = 0; r < 4; ++r) {
            const int m = m0 + i * 16 + l4 * 4 + r;
            #pragma unroll
            for (int j = 0; j < 2; ++j) {
                const int n = n0 + wn + j * 16 + l16;
                const float v = fmaxf(acc[i][j][r] + bsv[j], 0.0f);
                C[(size_t)m * N + n] = (short)f2bf(v);
            }
        }
}

// ---------------------------------------------------------------------------
// Fused dispatch: z-GEMM (M-tile 32) + permutation builder.
// blocks 0..63: z-norm; 64..191: queue-col perm; 192..199: row perm.
// ---------------------------------------------------------------------------
__global__ void __launch_bounds__(256) znorm_perm(const short* __restrict__ Ab,
                                                  const short* __restrict__ Bb,
                                                  const float* __restrict__ bias,
                                                  short* __restrict__ zb,
                                                  const int* __restrict__ qlab,
                                                  const int* __restrict__ labels,
                                                  const int* __restrict__ qpart,
                                                  const int* __restrict__ rcnt,
                                                  int* __restrict__ qcnt,
                                                  int* __restrict__ colidx,
                                                  int* __restrict__ qlabp,
                                                  int* __restrict__ rowmap,
                                                  int* __restrict__ rlabp,
                                                  int* __restrict__ pc) {
    __shared__ __align__(16) short As[32 * 128];    // 8 KB
    __shared__ __align__(16) short Bs[128 * 128];   // 32 KB
    __shared__ float ssq[32];
    __shared__ int wcnt[4][3];
    __shared__ int gbase[3];
    const int blk = blockIdx.x;
    const int t = threadIdx.x;
    const int lane = t & 63, wv = t >> 6;

    if (blk >= 64) {
        const unsigned long long below = (1ull << lane) - 1ull;
        int q0 = 0, q1 = 0, qv = 0;
        for (int i = 0; i < 32; ++i) {
            q0 += qpart[i * 4]; q1 += qpart[i * 4 + 1]; qv += qpart[i * 4 + 2];
        }
        if (blk < 192) {
            const int cb = blk - 64;
            if (cb == 0 && t == 0) { qcnt[0] = q0; qcnt[1] = q1; qcnt[2] = qv; }
            const int j = cb * 256 + t;
            const int q = qlab[j];
            const int cls = (q == 0) ? 0 : ((q == 1) ? 1 : 2);
            const unsigned long long b0 = __ballot(cls == 0);
            const unsigned long long b1 = __ballot(cls == 1);
            const unsigned long long b2 = __ballot(cls == 2);
            const int rank = (cls == 0) ? __popcll(b0 & below)
                           : ((cls == 1) ? __popcll(b1 & below) : __popcll(b2 & below));
            if (lane == 0) {
                wcnt[wv][0] = __popcll(b0); wcnt[wv][1] = __popcll(b1); wcnt[wv][2] = __popcll(b2);
            }
            __syncthreads();
            if (t < 3) {
                const int tot = wcnt[0][t] + wcnt[1][t] + wcnt[2][t] + wcnt[3][t];
                gbase[t] = atomicAdd(&pc[t], tot);
            }
            __syncthreads();
            int wb = 0;
            #pragma unroll
            for (int w = 0; w < 4; ++w) if (w < wv) wb += wcnt[w][cls];
            const int cbase = (cls == 0) ? 0 : ((cls == 1) ? q0 : q0 + q1);
            const int pos = cbase + gbase[cls] + wb + rank;
            colidx[pos] = j; qlabp[pos] = q;
        } else {
            const int r = (blk - 192) * 256 + t;
            const int l = labels[r];
            const int cls = (l == 0) ? 0 : 1;
            const unsigned long long b0 = __ballot(cls == 0);
            const unsigned long long b1 = __ballot(cls == 1);
            const int rank = (cls == 0) ? __popcll(b0 & below) : __popcll(b1 & below);
            if (lane == 0) { wcnt[wv][0] = __popcll(b0); wcnt[wv][1] = __popcll(b1); }
            __syncthreads();
            if (t < 2) {
                const int tot = wcnt[0][t] + wcnt[1][t] + wcnt[2][t] + wcnt[3][t];
                gbase[t] = atomicAdd(&pc[3 + t], tot);
            }
            __syncthreads();
            int wb = 0;
            #pragma unroll
            for (int w = 0; w < 4; ++w) if (w < wv) wb += wcnt[w][cls];
            const int cbase = (cls == 0) ? 0 : rcnt[0];
            const int pos = cbase + gbase[cls] + wb + rank;
            rowmap[pos] = r; rlabp[pos] = l;
        }
        return;
    }

    // ---- z GEMM path: 32-row M-tile, fused bias + L2-normalize ----
    const int l16 = lane & 15, l4 = lane >> 4;
    const int m0 = blk * 32;
    const int wn = wv * 32;
    const int K = EMB_D_;

    if (t < 32) ssq[t] = 0.0f;

    f32x4 acc[2][2];
    #pragma unroll
    for (int i = 0; i < 2; ++i)
        #pragma unroll
        for (int j = 0; j < 2; ++j) acc[i][j] = f32x4{0.f, 0.f, 0.f, 0.f};

    for (int kb = 0; kb < K; kb += 128) {
        __syncthreads();
        #pragma unroll
        for (int it = 0; it < 2; ++it) {
            const int r = it * 4 + wv, row = r * 4 + l4, cg = l16 ^ (row & 15);
            __builtin_amdgcn_global_load_lds(
                (const __attribute__((address_space(1))) void*)(Ab + (size_t)(m0 + row) * K + kb + cg * 8),
                (__attribute__((address_space(3))) void*)(As + r * 512), 16, 0, 0);
        }
        #pragma unroll
        for (int it = 0; it < 8; ++it) {
            const int r = it * 4 + wv, row = r * 4 + l4, cg = l16 ^ (row & 15);
            __builtin_amdgcn_global_load_lds(
                (const __attribute__((address_space(1))) void*)(Bb + (size_t)(row) * K + kb + cg * 8),
                (__attribute__((address_space(3))) void*)(Bs + r * 512), 16, 0, 0);
        }
        __syncthreads();
        #pragma unroll
        for (int ks = 0; ks < 4; ++ks) {
            short8 af[2], bfr[2];
            const int ch = (ks * 4 + l4) ^ l16;
            #pragma unroll
            for (int i = 0; i < 2; ++i)
                af[i] = *(const short8*)(As + (i * 16 + l16) * 128 + ch * 8);
            #pragma unroll
            for (int j = 0; j < 2; ++j)
                bfr[j] = *(const short8*)(Bs + (wn + j * 16 + l16) * 128 + ch * 8);
            #pragma unroll
            for (int i = 0; i < 2; ++i)
                #pragma unroll
                for (int j = 0; j < 2; ++j)
                    acc[i][j] = __builtin_amdgcn_mfma_f32_16x16x32_bf16(af[i], bfr[j], acc[i][j], 0, 0, 0);
        }
    }

    float bsv[2];
    #pragma unroll
    for (int j = 0; j < 2; ++j) bsv[j] = bias[wn + j * 16 + l16];
    #pragma unroll
    for (int i = 0; i < 2; ++i)
        #pragma unroll
        for (int r = 0; r < 4; ++r) {
            float p = 0.0f;
            #pragma unroll
            for (int j = 0; j < 2; ++j) {
                acc[i][j][r] += bsv[j];
                p += acc[i][j][r] * acc[i][j][r];
            }
            #pragma unroll
            for (int o = 8; o > 0; o >>= 1) p += __shfl_xor(p, o);
            if (l16 == 0) atomicAdd(&ssq[i * 16 + l4 * 4 + r], p);
        }
    __syncthreads();
    #pragma unroll
    for (int i = 0; i < 2; ++i)
        #pragma unroll
        for (int r = 0; r < 4; ++r) {
            const int lrow = i * 16 + l4 * 4 + r;
            const float inv = rsqrtf(ssq[lrow]);
            #pragma unroll
            for (int j = 0; j < 2; ++j)
                zb[(size_t)(m0 + lrow) * PROJ_D_ + wn + j * 16 + l16] =
                    (short)f2bf(acc[i][j][r] * inv);
        }
}

// ---------------------------------------------------------------------------
// Combined dispatch, 48 KB LDS -> 3 blocks/CU:
//  blocks 0..2047:   masked queue GEMM -> u8 codes, 64-row M-tile,
//                    label-partitioned (half exit), register-prefetched
//                    gather indices (single vmcnt drain at block start).
//  blocks 2048..2559: S = z z^T 64x128 tile, packed bf16 out (backfills
//                    the CUs freed by exited mask8 blocks).
// ---------------------------------------------------------------------------
__global__ void __launch_bounds__(256) mask8_spack(const short* __restrict__ zb,
                                                   const short* __restrict__ qb,
                                                   unsigned char* __restrict__ codes,
                                                   const int* __restrict__ rlabp,
                                                   const int* __restrict__ qlabp,
                                                   const int* __restrict__ colidx,
                                                   const int* __restrict__ rowmap,
                                                   const int* __restrict__ qcnt,
                                                   const int* __restrict__ rcnt,
                                                   short* __restrict__ Sbuf) {
    __shared__ __align__(16) short As[64 * 128];    // 16 KB
    __shared__ __align__(16) short Bs[128 * 128];   // 32 KB
    const int bid = blockIdx.x, t = threadIdx.x;
    const int lane = t & 63, wv = t >> 6;
    const int l16 = lane & 15, l4 = lane >> 4;
    const int wm = (wv & 1) * 32, wn = (wv >> 1) * 64;

    if (bid >= 2048) {
        // ---- S GEMM tile (64x128) ----
        const int q = bid - 2048;
        const int m0 = (q >> 4) * 64, n0 = (q & 15) * 128;
        #pragma unroll
        for (int it = 0; it < 4; ++it) {
            const int r = it * 4 + wv, row = r * 4 + l4, cg = l16 ^ (row & 15);
            __builtin_amdgcn_global_load_lds(
                (const __attribute__((address_space(1))) void*)(zb + (size_t)(m0 + row) * 128 + cg * 8),
                (__attribute__((address_space(3))) void*)(As + r * 512), 16, 0, 0);
        }
        #pragma unroll
        for (int it = 0; it < 8; ++it) {
            const int r = it * 4 + wv, row = r * 4 + l4, cg = l16 ^ (row & 15);
            __builtin_amdgcn_global_load_lds(
                (const __attribute__((address_space(1))) void*)(zb + (size_t)(n0 + row) * 128 + cg * 8),
                (__attribute__((address_space(3))) void*)(Bs + r * 512), 16, 0, 0);
        }
        __syncthreads();

        f32x4 acc[2][4];
        #pragma unroll
        for (int i = 0; i < 2; ++i)
            #pragma unroll
            for (int j = 0; j < 4; ++j) acc[i][j] = f32x4{0.f, 0.f, 0.f, 0.f};

        #pragma unroll
        for (int ks = 0; ks < 4; ++ks) {
            short8 af[2], bfr[4];
            const int ch = (ks * 4 + l4) ^ l16;
            #pragma unroll
            for (int i = 0; i < 2; ++i)
                af[i]  = *(const short8*)(As + (wm + i * 16 + l16) * 128 + ch * 8);
            #pragma unroll
            for (int j = 0; j < 4; ++j)
                bfr[j] = *(const short8*)(Bs + (wn + j * 16 + l16) * 128 + ch * 8);
            #pragma unroll
            for (int i = 0; i < 2; ++i)
                #pragma unroll
                for (int j = 0; j < 4; ++j)
                    acc[i][j] = __builtin_amdgcn_mfma_f32_16x16x32_bf16(af[i], bfr[j], acc[i][j], 0, 0, 0);
        }
        #pragma unroll
        for (int i = 0; i < 2; ++i)
            #pragma unroll
            for (int r = 0; r < 4; ++r) {
                const int m = m0 + wm + i * 16 + l4 * 4 + r;
                union { unsigned short u[4]; uint2 d; } pk;
                #pragma unroll
                for (int j = 0; j < 4; ++j) pk.u[j] = f2bf(acc[i][j][r]);
                *(uint2*)(Sbuf + (size_t)m * BATCH_N + n0 + wn + l16 * 4) = pk.d;
            }
        return;
    }

    // ---- mask8 path (64-row M-tile) ----
    const int bx = bid & 63, by = bid >> 6;
    const int m0 = by * 64;
    const int c0 = qcnt[0], c1v = qcnt[1], r0 = rcnt[0];
    int lo, hi;
    if (m0 + 64 <= r0)  { lo = c0; hi = c0 + c1v; }   // label-0 rows -> label-1 cols
    else if (m0 >= r0)  { lo = 0;  hi = c0; }         // label-1 rows -> label-0 cols
    else                { lo = 0;  hi = c0 + c1v; }   // mixed boundary tile
    const int bs = bx * 512;
    if (bs + 512 <= lo || bs >= hi) return;           // uniform block exit

    // prefetch all indirection into registers (one wait, then pure ALU)
    int ra[4], ca[32], la[8], qa[16];
    #pragma unroll
    for (int it = 0; it < 4; ++it)
        ra[it] = rowmap[m0 + (it * 4 + wv) * 4 + l4];
    #pragma unroll
    for (int tt = 0; tt < 4; ++tt)
        #pragma unroll
        for (int it = 0; it < 8; ++it)
            ca[tt * 8 + it] = colidx[bs + tt * 128 + (it * 4 + wv) * 4 + l4];
    #pragma unroll
    for (int i = 0; i < 2; ++i)
        #pragma unroll
        for (int r = 0; r < 4; ++r)
            la[i * 4 + r] = rlabp[m0 + wm + i * 16 + l4 * 4 + r];
    #pragma unroll
    for (int tt = 0; tt < 4; ++tt)
        #pragma unroll
        for (int j = 0; j < 4; ++j)
            qa[tt * 4 + j] = qlabp[bs + tt * 128 + wn + j * 16 + l16];

    #pragma unroll
    for (int it = 0; it < 4; ++it) {
        const int r = it * 4 + wv, row = r * 4 + l4, cg = l16 ^ (row & 15);
        __builtin_amdgcn_global_load_lds(
            (const __attribute__((address_space(1))) void*)(zb + (size_t)ra[it] * 128 + cg * 8),
            (__attribute__((address_space(3))) void*)(As + r * 512), 16, 0, 0);
    }
    #pragma unroll
    for (int it = 0; it < 8; ++it) {
        const int r = it * 4 + wv, row = r * 4 + l4, cg = l16 ^ (row & 15);
        __builtin_amdgcn_global_load_lds(
            (const __attribute__((address_space(1))) void*)(qb + (size_t)ca[it] * 128 + cg * 8),
            (__attribute__((address_space(3))) void*)(Bs + r * 512), 16, 0, 0);
    }
    const float C0 = 1.0f - WLO * S8ENC;
    __syncthreads();

    #pragma unroll
    for (int tt = 0; tt < 4; ++tt) {
        const int n0 = bs + tt * 128;

        f32x4 acc[2][4];
        #pragma unroll
        for (int i = 0; i < 2; ++i)
            #pragma unroll
            for (int j = 0; j < 4; ++j) acc[i][j] = f32x4{0.f, 0.f, 0.f, 0.f};

        #pragma unroll
        for (int ks = 0; ks < 4; ++ks) {
            short8 af[2], bfr[4];
            const int ch = (ks * 4 + l4) ^ l16;
            #pragma unroll
            for (int i = 0; i < 2; ++i)
                af[i]  = *(const short8*)(As + (wm + i * 16 + l16) * 128 + ch * 8);
            #pragma unroll
            for (int j = 0; j < 4; ++j)
                bfr[j] = *(const short8*)(Bs + (wn + j * 16 + l16) * 128 + ch * 8);
            #pragma unroll
            for (int i = 0; i < 2; ++i)
                #pragma unroll
                for (int j = 0; j < 4; ++j)
                    acc[i][j] = __builtin_amdgcn_mfma_f32_16x16x32_bf16(af[i], bfr[j], acc[i][j], 0, 0, 0);
        }

        if (tt < 3) {
            __syncthreads();          // all waves done reading Bs tile tt
            #pragma unroll
            for (int it = 0; it < 8; ++it) {
                const int r = it * 4 + wv, row = r * 4 + l4, cg = l16 ^ (row & 15);
                __builtin_amdgcn_global_load_lds(
                    (const __attribute__((address_space(1))) void*)(qb + (size_t)ca[(tt + 1) * 8 + it] * 128 + cg * 8),
                    (__attribute__((address_space(3))) void*)(Bs + r * 512), 16, 0, 0);
            }
        }

        // epilogue for this tile (overlaps next tile's B staging)
        float a0[4], a1[4];
        #pragma unroll
        for (int j = 0; j < 4; ++j) {
            const int q = qa[tt * 4 + j];
            a0[j] = (q >= 0 && q != 0) ? C0 : -1e9f;
            a1[j] = (q >= 0 && q != 1) ? C0 : -1e9f;
        }
        #pragma unroll
        for (int i = 0; i < 2; ++i) {
            #pragma unroll
            for (int r = 0; r < 4; ++r) {
                const int m  = m0 + wm + i * 16 + l4 * 4 + r;
                const bool z = (la[i * 4 + r] == 0);
                unsigned pk = 0;
                #pragma unroll
                for (int j = 0; j < 4; ++j) {
                    const float add = z ? a0[j] : a1[j];
                    const float f = fmaf(acc[i][j][r], S8ENC, add);
#if __has_builtin(__builtin_amdgcn_cvt_pk_u8_f32)
                    pk = __builtin_amdgcn_cvt_pk_u8_f32(f, j, pk);
#else
                    const unsigned c = (unsigned)fminf(fmaxf(f, 0.0f), 255.0f);
                    pk |= c << (8 * j);
#endif
                }
                *(unsigned*)(codes + (size_t)m * QUEUE_N + n0 + wn + l16 * 4) = pk;
            }
        }
        if (tt < 3) __syncthreads();  // next tile's B staged (barrier drains vmcnt)
    }
}

// ---------------------------------------------------------------------------
// Histogram crossing search (used by inline fallback)
// ---------------------------------------------------------------------------
__device__ __forceinline__ void find_crossing(int* hist, int* grp, int target,
                                              int* s_bin, int* s_chi) {
    const int t = threadIdx.x;
    const int b0 = hist[4*t], b1 = hist[4*t+1], b2 = hist[4*t+2], b3 = hist[4*t+3];
    grp[t] = b0 + b1 + b2 + b3;
    __syncthreads();
    for (int off = 1; off < 256; off <<= 1) {
        int add = (t + off < 256) ? grp[t + off] : 0;
        __syncthreads();
        grp[t] += add;
        __syncthreads();
    }
    int cab = (t < 255) ? grp[t + 1] : 0;
    const int hb[4] = {b0, b1, b2, b3};
    #pragma unroll
    for (int i = 3; i >= 0; i--) {
        const int h = hb[i];
        if (cab < target && cab + h >= target) { *s_bin = 4*t + i; *s_chi = cab; }
        cab += h;
    }
    __syncthreads();
}

// iterate all 128 packed-half2 values
#define FOR_ALL_VALS(BODY)                                                   \
    _Pragma("unroll")                                                        \
    for (int _k = 0; _k < 64; _k++) {                                        \
        const float2 _f = __half22float2(*(const __half2*)&dv[_k]);          \
        { const float v = _f.x; BODY }                                       \
        { const float v = _f.y; BODY }                                       \
    }

// ---------------------------------------------------------------------------
// topk lse from codes (partitioned row p, opposite-label span only) with the
// exact fallback INLINE on failure. SMALL LDS (~7 KB) -> high occupancy.
// Per-wave split histograms (4x256) cut same-address LDS conflicts 4x.
// ---------------------------------------------------------------------------
__global__ void __launch_bounds__(256) topk_fb(const unsigned char* __restrict__ codes,
                                               const int* __restrict__ qcnt,
                                               const int* __restrict__ rlabp,
                                               const int* __restrict__ rowmap,
                                               const short* __restrict__ zb,
                                               const short* __restrict__ qb,
                                               const int* __restrict__ qlab,
                                               float* __restrict__ lseq) {
    __shared__ int hist4[1024];          // 4 per-wave hists; reused as fh by fallback
    __shared__ int grp[256];             // suffix-scan buffer; reused by fallback
    __shared__ float zrow[128];
    __shared__ int s_bin, s_chi, s_bin2, s_chi2;
    __shared__ float scf[4];
    __shared__ int sci[4];
    const int p = blockIdx.x, t = threadIdx.x;
    const int orig  = rowmap[p];
    const int myLab = rlabp[p];
    const int opp   = opp_of(myLab, qcnt);

    if (opp >= HARD_K_) {
        for (int k = t; k < 1024; k += 256) hist4[k] = 0;
        __syncthreads();

        const int c0 = qcnt[0];
        const int lo = (myLab == 0) ? c0 : 0;
        const int hi = (myLab == 0) ? c0 + qcnt[1] : c0;
        const int klo = (lo & ~511) >> 4;            // uint4 index (16 cols each)
        const int khi = ((hi + 511) & ~511) >> 4;

        int* myh = hist4 + (t >> 6) * 256;
        const uint4* rowp = (const uint4*)(codes + (size_t)p * QUEUE_N);
        for (int k = klo + t; k < khi; k += 256) {
            const uint4 u = rowp[k];
            const unsigned w[4] = {u.x, u.y, u.z, u.w};
            #pragma unroll
            for (int q = 0; q < 4; q++)
                #pragma unroll
                for (int s = 0; s < 4; s++) {
                    const int c = (w[q] >> (8 * s)) & 0xFF;
                    if (c) atomicAdd(&myh[c], 1);
                }
        }
        __syncthreads();
        const int h = hist4[t] + hist4[256 + t] + hist4[512 + t] + hist4[768 + t];
        grp[t] = h;
        __syncthreads();
        for (int off = 1; off < 256; off <<= 1) {
            int add = (t + off < 256) ? grp[t + off] : 0;
            __syncthreads();
            grp[t] += add;
            __syncthreads();
        }
        const int total = grp[1];
        if (total >= HARD_K_) {
            {
                const int above = (t < 255) ? grp[t + 1] : 0;
                if (grp[t] >= HARD_K_ && above < HARD_K_) s_bin = t;
            }
            __syncthreads();
            const int b = s_bin;

            float e = 0.0f;
            if (t > b && h) e = (float)h * __expf((WLO + ((float)t - 0.5f) * BINW - 1.0f) * INV_T);
            #pragma unroll
            for (int o = 32; o > 0; o >>= 1) e += __shfl_xor(e, o);
            if ((t & 63) == 0) scf[t >> 6] = e;
            __syncthreads();
            if (t == 0) {
                const float Eab  = scf[0] + scf[1] + scf[2] + scf[3];
                const int   cab  = (b < 255) ? grp[b + 1] : 0;
                const float ebin = __expf((WLO + ((float)b - 0.5f) * BINW - 1.0f) * INV_T);
                const float sadj = Eab + (float)(HARD_K_ - cab) * ebin;
                lseq[orig] = INV_T + __logf(sadj);
            }
            return;
        }
        __syncthreads();   // hist path failed; safe to reuse LDS below
    }

    // ---- exact fallback, inline (rare) ----
    int* fh = hist4;
    if (t < 128) zrow[t] = bf2f(zb[(size_t)orig * 128 + t]);
    __syncthreads();

    const int mylab = myLab;
    unsigned dv[64];
    float rm = -1e30f, rs = 0.0f;
    for (int k = 0; k < 128; k++) {
        const int j = t + 256 * k;
        float d = 0.0f;
        #pragma unroll
        for (int c = 0; c < 16; ++c) {
            const short8 qv = *(const short8*)(qb + (size_t)j * 128 + c * 8);
            #pragma unroll
            for (int e = 0; e < 8; ++e) d += zrow[c * 8 + e] * bf2f(qv[e]);
        }
        if (j < HARD_K_) {
            const float sv = d * INV_T;
            if (sv > rm) { rs = rs * __expf(rm - sv) + 1.0f; rm = sv; }
            else         { rs += __expf(sv - rm); }
        }
        const int q = qlab[j];
        const float mv = (q != mylab && q >= 0) ? d : -65504.0f;
        const __half h = __float2half(mv);
        unsigned short* pp = (unsigned short*)&dv[k >> 1];
        pp[k & 1] = *(const unsigned short*)&h;
    }

    if (opp == 0) {
        #pragma unroll
        for (int o = 32; o > 0; o >>= 1) {
            const float om = __shfl_xor(rm, o), os = __shfl_xor(rs, o);
            const float nm = fmaxf(rm, om);
            rs = rs * __expf(rm - nm) + os * __expf(om - nm);
            rm = nm;
        }
        if ((t & 63) == 0) { scf[t >> 6] = rm; ((float*)sci)[t >> 6] = rs; }
        __syncthreads();
        if (t == 0) {
            float M = -1e30f, Sx = 0.0f;
            for (int w = 0; w < 4; w++) {
                const float nm = fmaxf(M, scf[w]);
                Sx = Sx * __expf(M - nm) + ((float*)sci)[w] * __expf(scf[w] - nm);
                M = nm;
            }
            lseq[orig] = M + __logf(Sx);
        }
        return;
    }
    if (opp < HARD_K_) {
        float mm = -1e30f, ss = 0.0f;
        FOR_ALL_VALS(
            if (v > -60000.0f) {
                const float sv = v * INV_T;
                if (sv > mm) { ss = ss * __expf(mm - sv) + 1.0f; mm = sv; }
                else         { ss += __expf(sv - mm); }
            } )
        #pragma unroll
        for (int o = 32; o > 0; o >>= 1) {
            const float om = __shfl_xor(mm, o), os = __shfl_xor(ss, o);
            const float nm = fmaxf(mm, om);
            ss = ss * __expf(mm - nm) + os * __expf(om - nm);
            mm = nm;
        }
        if ((t & 63) == 0) { scf[t >> 6] = mm; ((float*)sci)[t >> 6] = ss; }
        __syncthreads();
        if (t == 0) {
            float M = -1e30f, Sx = 0.0f;
            for (int w = 0; w < 4; w++) {
                const float nm = fmaxf(M, scf[w]);
                Sx = Sx * __expf(M - nm) + ((float*)sci)[w] * __expf(scf[w] - nm);
                M = nm;
            }
            lseq[orig] = M + __logf(Sx);
        }
        return;
    }

    float mloc = -1e30f;
    FOR_ALL_VALS( mloc = fmaxf(mloc, v); )
    #pragma unroll
    for (int o = 32; o > 0; o >>= 1) mloc = fmaxf(mloc, __shfl_xor(mloc, o));
    if ((t & 63) == 0) scf[t >> 6] = mloc;
    __syncthreads();
    const float m = fmaxf(fmaxf(scf[0], scf[1]), fmaxf(scf[2], scf[3]));

    int c1 = 0, c2 = 0;
    const float w1 = m - 0.25f, w2 = m - 1.0f;
    FOR_ALL_VALS( c1 += (v >= w1); c2 += (v >= w2); )
    #pragma unroll
    for (int o = 32; o > 0; o >>= 1) { c1 += __shfl_xor(c1, o); c2 += __shfl_xor(c2, o); }
    if ((t & 63) == 0) { sci[t >> 6] = c1; }
    __syncthreads();
    const int C1 = sci[0] + sci[1] + sci[2] + sci[3];
    __syncthreads();
    if ((t & 63) == 0) { sci[t >> 6] = c2; }
    __syncthreads();
    const int C2 = sci[0] + sci[1] + sci[2] + sci[3];

    float lo;
    if      (C1 >= HARD_K_) lo = w1;
    else if (C2 >= HARD_K_) lo = w2;
    else                    lo = -1.01f;
    const float range = m - lo;
    const float scale = 1024.0f / range;

    for (int k = t; k < 1024; k += 256) fh[k] = 0;
    __syncthreads();
    FOR_ALL_VALS(
        if (v >= lo) {
            const float bf = fminf((v - lo) * scale, 1023.0f);
            atomicAdd(&fh[(int)bf], 1);
        } )
    __syncthreads();
    find_crossing(fh, grp, HARD_K_, &s_bin, &s_chi);
    const int   bin1 = s_bin, chi1 = s_chi;
    const float binw = range * (1.0f / 1024.0f);
    const float lo1  = lo + bin1 * binw;
    const float ssc  = 1024.0f / binw;

    for (int k = t; k < 1024; k += 256) fh[k] = 0;
    __syncthreads();
    FOR_ALL_VALS(
        if (v >= lo) {
            const float bf = fminf((v - lo) * scale, 1023.0f);
            if ((int)bf == bin1) {
                const float sf = fminf(fmaxf((v - lo1) * ssc, 0.0f), 1023.0f);
                atomicAdd(&fh[(int)sf], 1);
            }
        } )
    __syncthreads();
    find_crossing(fh, grp, HARD_K_ - chi1, &s_bin2, &s_chi2);
    const float thr = lo1 + s_bin2 * (binw * (1.0f / 1024.0f));

    float sl = 0.0f; int cg = 0;
    FOR_ALL_VALS( if (v > thr) { cg++; sl += __expf((v - m) * INV_T); } )
    #pragma unroll
    for (int o = 32; o > 0; o >>= 1) { sl += __shfl_xor(sl, o); cg += __shfl_xor(cg, o); }
    if ((t & 63) == 0) { scf[t >> 6] = sl; sci[t >> 6] = cg; }
    __syncthreads();
    if (t == 0) {
        const float slt = scf[0] + scf[1] + scf[2] + scf[3];
        const int   cgt = sci[0] + sci[1] + sci[2] + sci[3];
        const float sadj = slt + ((float)HARD_K_ - (float)cgt) * __expf((thr - m) * INV_T);
        lseq[orig] = m * INV_T + __logf(sadj);
    }
}

// ---------------------------------------------------------------------------
// Batch lse + positive-pair loss over packed bf16 S (r2-verified, plain
// stores, no fences -- the brl_final atomic-tail fusion measured +20us).
// ---------------------------------------------------------------------------
__global__ void __launch_bounds__(256) batch_row_loss(const short* __restrict__ S,
                                                      const int* __restrict__ labels,
                                                      const float* __restrict__ lse_queue,
                                                      float* __restrict__ part_out,
                                                      int* __restrict__ cnt_out) {
    const int t = threadIdx.x;
    const int wv = t >> 6, lane = t & 63;
    const int row = blockIdx.x * 4 + wv;
    __shared__ int plab[BATCH_N];      // labels in packed order
    for (int idx = t; idx < BATCH_N; idx += 256) {
        const int col = (idx & ~63) + ((idx & 3) << 4) + ((idx >> 2) & 15);
        plab[idx] = labels[col];
    }
    __syncthreads();
    const int myLab = labels[row];
    const uint4* rp = (const uint4*)(S + (size_t)row * BATCH_N);  // 8 bf16 per uint4

    float v[32]; int lb[32];
    #pragma unroll
    for (int kk = 0; kk < 4; kk++) {
        const uint4 u = rp[lane + 64 * kk];
        const unsigned w[4] = {u.x, u.y, u.z, u.w};
        const int base = (lane + 64 * kk) * 8;
        #pragma unroll
        for (int q = 0; q < 4; q++) {
            v[kk * 8 + 2 * q]     = __uint_as_float(w[q] << 16);
            v[kk * 8 + 2 * q + 1] = __uint_as_float(w[q] & 0xFFFF0000u);
            lb[kk * 8 + 2 * q]     = plab[base + 2 * q];
            lb[kk * 8 + 2 * q + 1] = plab[base + 2 * q + 1];
        }
    }

    const float REF = INV_T;
    float sneg = 0.0f;
    #pragma unroll
    for (int k = 0; k < 32; k++) {
        const float ev = __expf(v[k] * INV_T - REF);
        sneg += (lb[k] != myLab) ? ev : 0.0f;
    }
    #pragma unroll
    for (int o = 32; o > 0; o >>= 1) sneg += __shfl_xor(sneg, o);
    const float lseb = (sneg > 0.0f) ? REF + __logf(sneg) : -1e30f;
    const float Lq = lse_queue[row];
    const float mx0 = fmaxf(lseb, Lq), mn0 = fminf(lseb, Lq);
    const float L = mx0 + __logf(1.0f + __expf(mn0 - mx0));

    float part = 0.0f; int cnt = 0;
    #pragma unroll
    for (int k = 0; k < 32; k++) {
        const int idx = ((lane + 64 * (k >> 3)) * 8) + (k & 7);
        const int col = (idx & ~63) + ((idx & 3) << 4) + ((idx >> 2) & 15);
        if (lb[k] == myLab && col != row) {
            const float sv = v[k] * INV_T;
            const float mx = fmaxf(sv, L), mn = fminf(sv, L);
            part += (mx - sv) + __logf(1.0f + __expf(mn - mx));
            cnt++;
        }
    }
    #pragma unroll
    for (int o = 32; o > 0; o >>= 1) { part += __shfl_xor(part, o); cnt += __shfl_xor(cnt, o); }
    if (lane == 0) { part_out[row] = part; cnt_out[row] = cnt; }
}

// reduce 2048 per-row partials -> scalar loss. One block.
__global__ void __launch_bounds__(256) finalize_loss(const float* __restrict__ part,
                                                     const int* __restrict__ cnt,
                                                     float* __restrict__ out) {
    const int t = threadIdx.x;
    float s = 0.0f; int c = 0;
    #pragma unroll
    for (int k = 0; k < 8; k++) { s += part[t + 256 * k]; c += cnt[t + 256 * k]; }
    #pragma unroll
    for (int o = 32; o > 0; o >>= 1) { s += __shfl_xor(s, o); c += __shfl_xor(c, o); }
    __shared__ float sf[4]; __shared__ int sc[4];
    if ((t & 63) == 0) { sf[t >> 6] = s; sc[t >> 6] = c; }
    __syncthreads();
    if (t == 0) {
        const float st = sf[0] + sf[1] + sf[2] + sf[3];
        const int   ct = sc[0] + sc[1] + sc[2] + sc[3];
        out[0] = (ct > 0) ? (st / (float)ct) : 0.0f;
    }
}

// ---------------------------------------------------------------------------
extern "C" void kernel_launch(void* const* d_in, const int* in_sizes, int n_in,
                              void* d_out, int out_size, void* d_ws, size_t ws_size,
                              hipStream_t stream) {
    const float* emb    = (const float*)d_in[0];
    const int*   labels = (const int*)  d_in[1];
    const float* W1     = (const float*)d_in[2];
    const float* b1     = (const float*)d_in[3];
    const float* W2     = (const float*)d_in[4];
    const float* b2     = (const float*)d_in[5];
    const float* queue  = (const float*)d_in[6];
    const int*   qlab   = (const int*)  d_in[7];

    char* ws = (char*)d_ws;
    short*         Sbuf  = (short*)        (ws);              // 8 MB used (16 MB region)
    unsigned char* codes = (unsigned char*)(ws + 16777216);   // 64 MB
    short*         embb  = (short*)        (ws + 83886080);   // 3145728
    short*         hbf   = (short*)        (ws + 87031808);   // 3145728
    short*         zb    = (short*)        (ws + 90177536);   // 524288
    short*         qb    = (short*)        (ws + 90701824);   // 8388608
    short*         w1t   = (short*)        (ws + 99090432);   // 1179648
    short*         w2t   = (short*)        (ws + 100270080);  // 196608
    float*         lseq  = (float*)        (ws + 100466688);  // 8192
    int*           qcnt  = (int*)          (ws + 100474880);  // 64
    int*           rcnt  = (int*)          (ws + 100474944);  // 64
    int*           pc    = (int*)          (ws + 100475008);  // 64
    int*           qpart = (int*)          (ws + 100475072);  // 512
    float*         partb = (float*)        (ws + 100475584);  // 8192
    int*           cntb  = (int*)          (ws + 100483776);  // 8192
    int*           colidx= (int*)          (ws + 100491968);  // 131072
    int*           qlabp = (int*)          (ws + 100623040);  // 131072
    int*           rowmap= (int*)          (ws + 100754112);  // 8192
    int*           rlabp = (int*)          (ws + 100762304);  // 8192

    dim3 blk(256);
    prep<<<dim3(5833), blk, 0, stream>>>(emb, embb, queue, qb, qlab, qpart, W1, w1t, W2, w2t, labels, rcnt, pc);
    mfma_h64<<<dim3(EMB_D_ / 128, BATCH_N / 64), blk, 0, stream>>>(embb, w1t, b1, hbf, EMB_D_, EMB_D_);
    znorm_perm<<<dim3(200), blk, 0, stream>>>(hbf, w2t, b2, zb, qlab, labels, qpart, rcnt,
                                              qcnt, colidx, qlabp, rowmap, rlabp, pc);
    mask8_spack<<<dim3(2560), blk, 0, stream>>>(zb, qb, codes, rlabp, qlabp, colidx, rowmap, qcnt, rcnt, Sbuf);
    topk_fb<<<dim3(BATCH_N), blk, 0, stream>>>(codes, qcnt, rlabp, rowmap, zb, qb, qlab, lseq);
    batch_row_loss<<<dim3(BATCH_N / 4), blk, 0, stream>>>(Sbuf, labels, lseq, partb, cntb);
    finalize_loss<<<1, blk, 0, stream>>>(partb, cntb, (float*)d_out);
}

// Round 6
// 154.961 us; speedup vs baseline: 1.2430x; 1.0202x over previous
//
#include <hip/hip_runtime.h>
#include <hip/hip_fp16.h>

#define BATCH_N   2048
#define EMB_D_    768
#define PROJ_D_   128
#define QUEUE_N   32768
#define HARD_K_   512
static constexpr float INV_T  = 1.0f / 0.07f;
static constexpr float WLO    = 0.12f;              // code-0 boundary (512th opp val ~0.164)
static constexpr float S8ENC  = 255.0f / 0.88f;     // encode scale
static constexpr float BINW   = 0.88f / 255.0f;     // code bin width

typedef __attribute__((ext_vector_type(8))) short short8;
typedef __attribute__((ext_vector_type(4))) short short4v;
typedef __attribute__((ext_vector_type(4))) float f32x4;

__device__ __forceinline__ unsigned short f2bf(float f) {
    unsigned u = __float_as_uint(f);
    unsigned r = u + 0x7fffu + ((u >> 16) & 1u);   // RNE
    return (unsigned short)(r >> 16);
}
__device__ __forceinline__ float bf2f(short s) {
    return __uint_as_float(((unsigned)(unsigned short)s) << 16);
}
__device__ __forceinline__ int opp_of(int mylab, const int* __restrict__ qcnt) {
    const int same = (mylab == 0) ? qcnt[0] : ((mylab == 1) ? qcnt[1] : 0);
    return qcnt[2] - same;
}

// ---------------------------------------------------------------------------
// Merged prep: emb cast + queue cast + qlab census (plain partial stores) +
// W1/W2 transpose + row census + pc zero. No memset dispatch needed.
// ---------------------------------------------------------------------------
__global__ void __launch_bounds__(256) prep(const float* __restrict__ emb, short* __restrict__ embb,
                                            const float* __restrict__ queue, short* __restrict__ qb,
                                            const int* __restrict__ qlab, int* __restrict__ qpart,
                                            const float* __restrict__ W1, short* __restrict__ w1t,
                                            const float* __restrict__ W2, short* __restrict__ w2t,
                                            const int* __restrict__ labels, int* __restrict__ rcnt,
                                            int* __restrict__ pc) {
    __shared__ float tile[64][65];
    const int b = blockIdx.x, t = threadIdx.x;
    if (b < 1536) {
        const int i = b * 256 + t;
        const float4 f = ((const float4*)emb)[i];
        short4v o = {(short)f2bf(f.x), (short)f2bf(f.y), (short)f2bf(f.z), (short)f2bf(f.w)};
        ((short4v*)embb)[i] = o;
    } else if (b < 5632) {
        const int i = (b - 1536) * 256 + t;
        const float4 f = ((const float4*)queue)[i];
        short4v o = {(short)f2bf(f.x), (short)f2bf(f.y), (short)f2bf(f.z), (short)f2bf(f.w)};
        ((short4v*)qb)[i] = o;
    } else if (b < 5664) {
        const int i = (b - 5632) * 256 + t;
        int c0 = 0, c1 = 0, cv = 0;
        for (int j = i; j < QUEUE_N; j += 8192) {
            const int q = qlab[j];
            c0 += (q == 0); c1 += (q == 1); cv += (q >= 0);
        }
        #pragma unroll
        for (int o = 32; o > 0; o >>= 1) {
            c0 += __shfl_xor(c0, o); c1 += __shfl_xor(c1, o); cv += __shfl_xor(cv, o);
        }
        int* red = (int*)tile;
        const int wv = t >> 6;
        if ((t & 63) == 0) { red[wv * 4 + 0] = c0; red[wv * 4 + 1] = c1; red[wv * 4 + 2] = cv; }
        __syncthreads();
        if (t == 0) {
            const int bb = (b - 5632) * 4;
            qpart[bb + 0] = red[0] + red[4] + red[8]  + red[12];
            qpart[bb + 1] = red[1] + red[5] + red[9]  + red[13];
            qpart[bb + 2] = red[2] + red[6] + red[10] + red[14];
        }
    } else if (b < 5832) {
        const int bid = b - 5664;
        const float* A; short* At; int R, C, bx, by;
        if (bid < 144) { A = W1; At = w1t; R = EMB_D_; C = EMB_D_;  bx = (bid % 12) * 64; by = (bid / 12) * 64; }
        else { const int b2 = bid - 144; A = W2; At = w2t; R = EMB_D_; C = PROJ_D_; bx = (b2 & 1) * 64; by = (b2 >> 1) * 64; }
        const int tc = t & 63, tg = t >> 6;
        #pragma unroll
        for (int i = 0; i < 16; i++) {
            const int r = tg * 16 + i;
            tile[r][tc] = A[(size_t)(by + r) * C + bx + tc];
        }
        __syncthreads();
        #pragma unroll
        for (int i = 0; i < 16; i++) {
            const int r = tg * 16 + i;
            At[(size_t)(bx + r) * R + by + tc] = (short)f2bf(tile[tc][r]);
        }
    } else {
        // row-label census (plain store) + pc zero
        int c = 0;
        for (int j = t; j < BATCH_N; j += 256) c += (labels[j] == 0);
        #pragma unroll
        for (int o = 32; o > 0; o >>= 1) c += __shfl_xor(c, o);
        int* red = (int*)tile;
        if ((t & 63) == 0) red[t >> 6] = c;
        __syncthreads();
        if (t == 0) rcnt[0] = red[0] + red[1] + red[2] + red[3];
        if (t < 8) pc[t] = 0;
    }
}

// ---------------------------------------------------------------------------
// GEMM1: bf16 MFMA NT, 64x128 (MxN) tile, K-loop, fused bias+ReLU, bf16 out.
// ---------------------------------------------------------------------------
__global__ void __launch_bounds__(256) mfma_h64(const short* __restrict__ Ab,
                                                const short* __restrict__ Bb,
                                                const float* __restrict__ bias,
                                                short* __restrict__ C,
                                                int N, int K) {
    __shared__ __align__(16) short As[64 * 128];    // 16 KB
    __shared__ __align__(16) short Bs[128 * 128];   // 32 KB
    const int t = threadIdx.x;
    const int lane = t & 63, wv = t >> 6;
    const int l16 = lane & 15, l4 = lane >> 4;
    const int m0 = blockIdx.y * 64, n0 = blockIdx.x * 128;
    const int wn = wv * 32;

    f32x4 acc[4][2];
    #pragma unroll
    for (int i = 0; i < 4; ++i)
        #pragma unroll
        for (int j = 0; j < 2; ++j) acc[i][j] = f32x4{0.f, 0.f, 0.f, 0.f};

    for (int kb = 0; kb < K; kb += 128) {
        __syncthreads();
        #pragma unroll
        for (int it = 0; it < 4; ++it) {            // A: 16 units of 512 shorts
            const int r = it * 4 + wv, row = r * 4 + l4, cg = l16 ^ (row & 15);
            __builtin_amdgcn_global_load_lds(
                (const __attribute__((address_space(1))) void*)(Ab + (size_t)(m0 + row) * K + kb + cg * 8),
                (__attribute__((address_space(3))) void*)(As + r * 512), 16, 0, 0);
        }
        #pragma unroll
        for (int it = 0; it < 8; ++it) {            // B: 32 units
            const int r = it * 4 + wv, row = r * 4 + l4, cg = l16 ^ (row & 15);
            __builtin_amdgcn_global_load_lds(
                (const __attribute__((address_space(1))) void*)(Bb + (size_t)(n0 + row) * K + kb + cg * 8),
                (__attribute__((address_space(3))) void*)(Bs + r * 512), 16, 0, 0);
        }
        __syncthreads();
        #pragma unroll
        for (int ks = 0; ks < 4; ++ks) {
            short8 af[4], bfr[2];
            const int ch = (ks * 4 + l4) ^ l16;
            #pragma unroll
            for (int i = 0; i < 4; ++i)
                af[i] = *(const short8*)(As + (i * 16 + l16) * 128 + ch * 8);
            #pragma unroll
            for (int j = 0; j < 2; ++j)
                bfr[j] = *(const short8*)(Bs + (wn + j * 16 + l16) * 128 + ch * 8);
            #pragma unroll
            for (int i = 0; i < 4; ++i)
                #pragma unroll
                for (int j = 0; j < 2; ++j)
                    acc[i][j] = __builtin_amdgcn_mfma_f32_16x16x32_bf16(af[i], bfr[j], acc[i][j], 0, 0, 0);
        }
    }

    float bsv[2];
    #pragma unroll
    for (int j = 0; j < 2; ++j) bsv[j] = bias[n0 + wn + j * 16 + l16];
    #pragma unroll
    for (int i = 0; i < 4; ++i)
        #pragma unroll
        for (int r = 0; r < 4; ++r) {
            const int m = m0 + i * 16 + l4 * 4 + r;
            #pragma unroll
            for (int j = 0; j < 2; ++j) {
                const int n = n0 + wn + j * 16 + l16;
                const float v = fmaxf(acc[i][j][r] + bsv[j], 0.0f);
                C[(size_t)m * N + n] = (short)f2bf(v);
            }
        }
}

// ---------------------------------------------------------------------------
// Fused dispatch: z-GEMM (M-tile 32) + permutation builder.
// blocks 0..63: z-norm; 64..191: queue-col perm; 192..199: row perm.
// ---------------------------------------------------------------------------
__global__ void __launch_bounds__(256) znorm_perm(const short* __restrict__ Ab,
                                                  const short* __restrict__ Bb,
                                                  const float* __restrict__ bias,
                                                  short* __restrict__ zb,
                                                  const int* __restrict__ qlab,
                                                  const int* __restrict__ labels,
                                                  const int* __restrict__ qpart,
                                                  const int* __restrict__ rcnt,
                                                  int* __restrict__ qcnt,
                                                  int* __restrict__ colidx,
                                                  int* __restrict__ qlabp,
                                                  int* __restrict__ rowmap,
                                                  int* __restrict__ rlabp,
                                                  int* __restrict__ pc) {
    __shared__ __align__(16) short As[32 * 128];    // 8 KB
    __shared__ __align__(16) short Bs[128 * 128];   // 32 KB
    __shared__ float ssq[32];
    __shared__ int wcnt[4][3];
    __shared__ int gbase[3];
    const int blk = blockIdx.x;
    const int t = threadIdx.x;
    const int lane = t & 63, wv = t >> 6;

    if (blk >= 64) {
        const unsigned long long below = (1ull << lane) - 1ull;
        int q0 = 0, q1 = 0, qv = 0;
        for (int i = 0; i < 32; ++i) {
            q0 += qpart[i * 4]; q1 += qpart[i * 4 + 1]; qv += qpart[i * 4 + 2];
        }
        if (blk < 192) {
            const int cb = blk - 64;
            if (cb == 0 && t == 0) { qcnt[0] = q0; qcnt[1] = q1; qcnt[2] = qv; }
            const int j = cb * 256 + t;
            const int q = qlab[j];
            const int cls = (q == 0) ? 0 : ((q == 1) ? 1 : 2);
            const unsigned long long b0 = __ballot(cls == 0);
            const unsigned long long b1 = __ballot(cls == 1);
            const unsigned long long b2 = __ballot(cls == 2);
            const int rank = (cls == 0) ? __popcll(b0 & below)
                           : ((cls == 1) ? __popcll(b1 & below) : __popcll(b2 & below));
            if (lane == 0) {
                wcnt[wv][0] = __popcll(b0); wcnt[wv][1] = __popcll(b1); wcnt[wv][2] = __popcll(b2);
            }
            __syncthreads();
            if (t < 3) {
                const int tot = wcnt[0][t] + wcnt[1][t] + wcnt[2][t] + wcnt[3][t];
                gbase[t] = atomicAdd(&pc[t], tot);
            }
            __syncthreads();
            int wb = 0;
            #pragma unroll
            for (int w = 0; w < 4; ++w) if (w < wv) wb += wcnt[w][cls];
            const int cbase = (cls == 0) ? 0 : ((cls == 1) ? q0 : q0 + q1);
            const int pos = cbase + gbase[cls] + wb + rank;
            colidx[pos] = j; qlabp[pos] = q;
        } else {
            const int r = (blk - 192) * 256 + t;
            const int l = labels[r];
            const int cls = (l == 0) ? 0 : 1;
            const unsigned long long b0 = __ballot(cls == 0);
            const unsigned long long b1 = __ballot(cls == 1);
            const int rank = (cls == 0) ? __popcll(b0 & below) : __popcll(b1 & below);
            if (lane == 0) { wcnt[wv][0] = __popcll(b0); wcnt[wv][1] = __popcll(b1); }
            __syncthreads();
            if (t < 2) {
                const int tot = wcnt[0][t] + wcnt[1][t] + wcnt[2][t] + wcnt[3][t];
                gbase[t] = atomicAdd(&pc[3 + t], tot);
            }
            __syncthreads();
            int wb = 0;
            #pragma unroll
            for (int w = 0; w < 4; ++w) if (w < wv) wb += wcnt[w][cls];
            const int cbase = (cls == 0) ? 0 : rcnt[0];
            const int pos = cbase + gbase[cls] + wb + rank;
            rowmap[pos] = r; rlabp[pos] = l;
        }
        return;
    }

    // ---- z GEMM path: 32-row M-tile, fused bias + L2-normalize ----
    const int l16 = lane & 15, l4 = lane >> 4;
    const int m0 = blk * 32;
    const int wn = wv * 32;
    const int K = EMB_D_;

    if (t < 32) ssq[t] = 0.0f;

    f32x4 acc[2][2];
    #pragma unroll
    for (int i = 0; i < 2; ++i)
        #pragma unroll
        for (int j = 0; j < 2; ++j) acc[i][j] = f32x4{0.f, 0.f, 0.f, 0.f};

    for (int kb = 0; kb < K; kb += 128) {
        __syncthreads();
        #pragma unroll
        for (int it = 0; it < 2; ++it) {
            const int r = it * 4 + wv, row = r * 4 + l4, cg = l16 ^ (row & 15);
            __builtin_amdgcn_global_load_lds(
                (const __attribute__((address_space(1))) void*)(Ab + (size_t)(m0 + row) * K + kb + cg * 8),
                (__attribute__((address_space(3))) void*)(As + r * 512), 16, 0, 0);
        }
        #pragma unroll
        for (int it = 0; it < 8; ++it) {
            const int r = it * 4 + wv, row = r * 4 + l4, cg = l16 ^ (row & 15);
            __builtin_amdgcn_global_load_lds(
                (const __attribute__((address_space(1))) void*)(Bb + (size_t)(row) * K + kb + cg * 8),
                (__attribute__((address_space(3))) void*)(Bs + r * 512), 16, 0, 0);
        }
        __syncthreads();
        #pragma unroll
        for (int ks = 0; ks < 4; ++ks) {
            short8 af[2], bfr[2];
            const int ch = (ks * 4 + l4) ^ l16;
            #pragma unroll
            for (int i = 0; i < 2; ++i)
                af[i] = *(const short8*)(As + (i * 16 + l16) * 128 + ch * 8);
            #pragma unroll
            for (int j = 0; j < 2; ++j)
                bfr[j] = *(const short8*)(Bs + (wn + j * 16 + l16) * 128 + ch * 8);
            #pragma unroll
            for (int i = 0; i < 2; ++i)
                #pragma unroll
                for (int j = 0; j < 2; ++j)
                    acc[i][j] = __builtin_amdgcn_mfma_f32_16x16x32_bf16(af[i], bfr[j], acc[i][j], 0, 0, 0);
        }
    }

    float bsv[2];
    #pragma unroll
    for (int j = 0; j < 2; ++j) bsv[j] = bias[wn + j * 16 + l16];
    #pragma unroll
    for (int i = 0; i < 2; ++i)
        #pragma unroll
        for (int r = 0; r < 4; ++r) {
            float p = 0.0f;
            #pragma unroll
            for (int j = 0; j < 2; ++j) {
                acc[i][j][r] += bsv[j];
                p += acc[i][j][r] * acc[i][j][r];
            }
            #pragma unroll
            for (int o = 8; o > 0; o >>= 1) p += __shfl_xor(p, o);
            if (l16 == 0) atomicAdd(&ssq[i * 16 + l4 * 4 + r], p);
        }
    __syncthreads();
    #pragma unroll
    for (int i = 0; i < 2; ++i)
        #pragma unroll
        for (int r = 0; r < 4; ++r) {
            const int lrow = i * 16 + l4 * 4 + r;
            const float inv = rsqrtf(ssq[lrow]);
            #pragma unroll
            for (int j = 0; j < 2; ++j)
                zb[(size_t)(m0 + lrow) * PROJ_D_ + wn + j * 16 + l16] =
                    (short)f2bf(acc[i][j][r] * inv);
        }
}

// ---------------------------------------------------------------------------
// Combined dispatch, 48 KB LDS -> 3 blocks/CU:
//  blocks 0..2047:   masked queue GEMM -> u8 codes, 64-row M-tile,
//                    label-partitioned (half exit), register-prefetched
//                    gather indices (single vmcnt drain at block start).
//  blocks 2048..2559: S = z z^T 64x128 tile, packed bf16 out (backfills
//                    the CUs freed by exited mask8 blocks).
// ---------------------------------------------------------------------------
__global__ void __launch_bounds__(256) mask8_spack(const short* __restrict__ zb,
                                                   const short* __restrict__ qb,
                                                   unsigned char* __restrict__ codes,
                                                   const int* __restrict__ rlabp,
                                                   const int* __restrict__ qlabp,
                                                   const int* __restrict__ colidx,
                                                   const int* __restrict__ rowmap,
                                                   const int* __restrict__ qcnt,
                                                   const int* __restrict__ rcnt,
                                                   short* __restrict__ Sbuf) {
    __shared__ __align__(16) short As[64 * 128];    // 16 KB
    __shared__ __align__(16) short Bs[128 * 128];   // 32 KB
    const int bid = blockIdx.x, t = threadIdx.x;
    const int lane = t & 63, wv = t >> 6;
    const int l16 = lane & 15, l4 = lane >> 4;
    const int wm = (wv & 1) * 32, wn = (wv >> 1) * 64;

    if (bid >= 2048) {
        // ---- S GEMM tile (64x128) ----
        const int q = bid - 2048;
        const int m0 = (q >> 4) * 64, n0 = (q & 15) * 128;
        #pragma unroll
        for (int it = 0; it < 4; ++it) {
            const int r = it * 4 + wv, row = r * 4 + l4, cg = l16 ^ (row & 15);
            __builtin_amdgcn_global_load_lds(
                (const __attribute__((address_space(1))) void*)(zb + (size_t)(m0 + row) * 128 + cg * 8),
                (__attribute__((address_space(3))) void*)(As + r * 512), 16, 0, 0);
        }
        #pragma unroll
        for (int it = 0; it < 8; ++it) {
            const int r = it * 4 + wv, row = r * 4 + l4, cg = l16 ^ (row & 15);
            __builtin_amdgcn_global_load_lds(
                (const __attribute__((address_space(1))) void*)(zb + (size_t)(n0 + row) * 128 + cg * 8),
                (__attribute__((address_space(3))) void*)(Bs + r * 512), 16, 0, 0);
        }
        __syncthreads();

        f32x4 acc[2][4];
        #pragma unroll
        for (int i = 0; i < 2; ++i)
            #pragma unroll
            for (int j = 0; j < 4; ++j) acc[i][j] = f32x4{0.f, 0.f, 0.f, 0.f};

        #pragma unroll
        for (int ks = 0; ks < 4; ++ks) {
            short8 af[2], bfr[4];
            const int ch = (ks * 4 + l4) ^ l16;
            #pragma unroll
            for (int i = 0; i < 2; ++i)
                af[i]  = *(const short8*)(As + (wm + i * 16 + l16) * 128 + ch * 8);
            #pragma unroll
            for (int j = 0; j < 4; ++j)
                bfr[j] = *(const short8*)(Bs + (wn + j * 16 + l16) * 128 + ch * 8);
            #pragma unroll
            for (int i = 0; i < 2; ++i)
                #pragma unroll
                for (int j = 0; j < 4; ++j)
                    acc[i][j] = __builtin_amdgcn_mfma_f32_16x16x32_bf16(af[i], bfr[j], acc[i][j], 0, 0, 0);
        }
        #pragma unroll
        for (int i = 0; i < 2; ++i)
            #pragma unroll
            for (int r = 0; r < 4; ++r) {
                const int m = m0 + wm + i * 16 + l4 * 4 + r;
                union { unsigned short u[4]; uint2 d; } pk;
                #pragma unroll
                for (int j = 0; j < 4; ++j) pk.u[j] = f2bf(acc[i][j][r]);
                *(uint2*)(Sbuf + (size_t)m * BATCH_N + n0 + wn + l16 * 4) = pk.d;
            }
        return;
    }

    // ---- mask8 path (64-row M-tile) ----
    const int bx = bid & 63, by = bid >> 6;
    const int m0 = by * 64;
    const int c0 = qcnt[0], c1v = qcnt[1], r0 = rcnt[0];
    int lo, hi;
    if (m0 + 64 <= r0)  { lo = c0; hi = c0 + c1v; }   // label-0 rows -> label-1 cols
    else if (m0 >= r0)  { lo = 0;  hi = c0; }         // label-1 rows -> label-0 cols
    else                { lo = 0;  hi = c0 + c1v; }   // mixed boundary tile
    const int bs = bx * 512;
    if (bs + 512 <= lo || bs >= hi) return;           // uniform block exit

    // prefetch all indirection into registers (one wait, then pure ALU)
    int ra[4], ca[32], la[8], qa[16];
    #pragma unroll
    for (int it = 0; it < 4; ++it)
        ra[it] = rowmap[m0 + (it * 4 + wv) * 4 + l4];
    #pragma unroll
    for (int tt = 0; tt < 4; ++tt)
        #pragma unroll
        for (int it = 0; it < 8; ++it)
            ca[tt * 8 + it] = colidx[bs + tt * 128 + (it * 4 + wv) * 4 + l4];
    #pragma unroll
    for (int i = 0; i < 2; ++i)
        #pragma unroll
        for (int r = 0; r < 4; ++r)
            la[i * 4 + r] = rlabp[m0 + wm + i * 16 + l4 * 4 + r];
    #pragma unroll
    for (int tt = 0; tt < 4; ++tt)
        #pragma unroll
        for (int j = 0; j < 4; ++j)
            qa[tt * 4 + j] = qlabp[bs + tt * 128 + wn + j * 16 + l16];

    #pragma unroll
    for (int it = 0; it < 4; ++it) {
        const int r = it * 4 + wv, row = r * 4 + l4, cg = l16 ^ (row & 15);
        __builtin_amdgcn_global_load_lds(
            (const __attribute__((address_space(1))) void*)(zb + (size_t)ra[it] * 128 + cg * 8),
            (__attribute__((address_space(3))) void*)(As + r * 512), 16, 0, 0);
    }
    #pragma unroll
    for (int it = 0; it < 8; ++it) {
        const int r = it * 4 + wv, row = r * 4 + l4, cg = l16 ^ (row & 15);
        __builtin_amdgcn_global_load_lds(
            (const __attribute__((address_space(1))) void*)(qb + (size_t)ca[it] * 128 + cg * 8),
            (__attribute__((address_space(3))) void*)(Bs + r * 512), 16, 0, 0);
    }
    const float C0 = 1.0f - WLO * S8ENC;
    __syncthreads();

    #pragma unroll
    for (int tt = 0; tt < 4; ++tt) {
        const int n0 = bs + tt * 128;

        f32x4 acc[2][4];
        #pragma unroll
        for (int i = 0; i < 2; ++i)
            #pragma unroll
            for (int j = 0; j < 4; ++j) acc[i][j] = f32x4{0.f, 0.f, 0.f, 0.f};

        #pragma unroll
        for (int ks = 0; ks < 4; ++ks) {
            short8 af[2], bfr[4];
            const int ch = (ks * 4 + l4) ^ l16;
            #pragma unroll
            for (int i = 0; i < 2; ++i)
                af[i]  = *(const short8*)(As + (wm + i * 16 + l16) * 128 + ch * 8);
            #pragma unroll
            for (int j = 0; j < 4; ++j)
                bfr[j] = *(const short8*)(Bs + (wn + j * 16 + l16) * 128 + ch * 8);
            #pragma unroll
            for (int i = 0; i < 2; ++i)
                #pragma unroll
                for (int j = 0; j < 4; ++j)
                    acc[i][j] = __builtin_amdgcn_mfma_f32_16x16x32_bf16(af[i], bfr[j], acc[i][j], 0, 0, 0);
        }

        if (tt < 3) {
            __syncthreads();          // all waves done reading Bs tile tt
            #pragma unroll
            for (int it = 0; it < 8; ++it) {
                const int r = it * 4 + wv, row = r * 4 + l4, cg = l16 ^ (row & 15);
                __builtin_amdgcn_global_load_lds(
                    (const __attribute__((address_space(1))) void*)(qb + (size_t)ca[(tt + 1) * 8 + it] * 128 + cg * 8),
                    (__attribute__((address_space(3))) void*)(Bs + r * 512), 16, 0, 0);
            }
        }

        // epilogue for this tile (overlaps next tile's B staging)
        float a0[4], a1[4];
        #pragma unroll
        for (int j = 0; j < 4; ++j) {
            const int q = qa[tt * 4 + j];
            a0[j] = (q >= 0 && q != 0) ? C0 : -1e9f;
            a1[j] = (q >= 0 && q != 1) ? C0 : -1e9f;
        }
        #pragma unroll
        for (int i = 0; i < 2; ++i) {
            #pragma unroll
            for (int r = 0; r < 4; ++r) {
                const int m  = m0 + wm + i * 16 + l4 * 4 + r;
                const bool z = (la[i * 4 + r] == 0);
                unsigned pk = 0;
                #pragma unroll
                for (int j = 0; j < 4; ++j) {
                    const float add = z ? a0[j] : a1[j];
                    const float f = fmaf(acc[i][j][r], S8ENC, add);
#if __has_builtin(__builtin_amdgcn_cvt_pk_u8_f32)
                    pk = __builtin_amdgcn_cvt_pk_u8_f32(f, j, pk);
#else
                    const unsigned c = (unsigned)fminf(fmaxf(f, 0.0f), 255.0f);
                    pk |= c << (8 * j);
#endif
                }
                *(unsigned*)(codes + (size_t)m * QUEUE_N + n0 + wn + l16 * 4) = pk;
            }
        }
        if (tt < 3) __syncthreads();  // next tile's B staged (barrier drains vmcnt)
    }
}

// ---------------------------------------------------------------------------
// Histogram crossing search (used by inline fallback)
// ---------------------------------------------------------------------------
__device__ __forceinline__ void find_crossing(int* hist, int* grp, int target,
                                              int* s_bin, int* s_chi) {
    const int t = threadIdx.x;
    const int b0 = hist[4*t], b1 = hist[4*t+1], b2 = hist[4*t+2], b3 = hist[4*t+3];
    grp[t] = b0 + b1 + b2 + b3;
    __syncthreads();
    for (int off = 1; off < 256; off <<= 1) {
        int add = (t + off < 256) ? grp[t + off] : 0;
        __syncthreads();
        grp[t] += add;
        __syncthreads();
    }
    int cab = (t < 255) ? grp[t + 1] : 0;
    const int hb[4] = {b0, b1, b2, b3};
    #pragma unroll
    for (int i = 3; i >= 0; i--) {
        const int h = hb[i];
        if (cab < target && cab + h >= target) { *s_bin = 4*t + i; *s_chi = cab; }
        cab += h;
    }
    __syncthreads();
}

// iterate all 128 packed-half2 values
#define FOR_ALL_VALS(BODY)                                                   \
    _Pragma("unroll")                                                        \
    for (int _k = 0; _k < 64; _k++) {                                        \
        const float2 _f = __half22float2(*(const __half2*)&dv[_k]);          \
        { const float v = _f.x; BODY }                                       \
        { const float v = _f.y; BODY }                                       \
    }

// ---------------------------------------------------------------------------
// Fused tail: one block per partitioned row p.
//  Phase A: topk lse from codes (hist path; exact fallback inline).
//           ALL control flow is block-uniform; L_q lands in s_Lq.
//  Phase B: wave 0 replicates batch_row_loss's single-wave reduction for
//           row orig (bit-identical order) -> part/cnt.
// Removes one dispatch + the lseq HBM round-trip.
// ---------------------------------------------------------------------------
__global__ void __launch_bounds__(256) tail_row(const unsigned char* __restrict__ codes,
                                                const int* __restrict__ qcnt,
                                                const int* __restrict__ rlabp,
                                                const int* __restrict__ rowmap,
                                                const short* __restrict__ zb,
                                                const short* __restrict__ qb,
                                                const int* __restrict__ qlab,
                                                const short* __restrict__ S,
                                                const int* __restrict__ labels,
                                                float* __restrict__ part_out,
                                                int* __restrict__ cnt_out) {
    __shared__ int hist4[1024];          // 4 per-wave hists; reused as fh by fallback
    __shared__ int grp[256];             // suffix-scan buffer; reused by fallback
    __shared__ float zrow[128];
    __shared__ int s_bin, s_chi, s_bin2, s_chi2;
    __shared__ float scf[4];
    __shared__ int sci[4];
    __shared__ float s_Lq;
    const int p = blockIdx.x, t = threadIdx.x;
    const int orig  = rowmap[p];
    const int myLab = rlabp[p];
    const int opp   = opp_of(myLab, qcnt);

    bool have = false;                   // block-uniform
    if (opp >= HARD_K_) {
        for (int k = t; k < 1024; k += 256) hist4[k] = 0;
        __syncthreads();

        const int c0 = qcnt[0];
        const int lo = (myLab == 0) ? c0 : 0;
        const int hi = (myLab == 0) ? c0 + qcnt[1] : c0;
        const int klo = (lo & ~511) >> 4;            // uint4 index (16 cols each)
        const int khi = ((hi + 511) & ~511) >> 4;

        int* myh = hist4 + (t >> 6) * 256;
        const uint4* rowp = (const uint4*)(codes + (size_t)p * QUEUE_N);
        for (int k = klo + t; k < khi; k += 256) {
            const uint4 u = rowp[k];
            const unsigned w[4] = {u.x, u.y, u.z, u.w};
            #pragma unroll
            for (int q = 0; q < 4; q++)
                #pragma unroll
                for (int s = 0; s < 4; s++) {
                    const int c = (w[q] >> (8 * s)) & 0xFF;
                    if (c) atomicAdd(&myh[c], 1);
                }
        }
        __syncthreads();
        const int h = hist4[t] + hist4[256 + t] + hist4[512 + t] + hist4[768 + t];
        grp[t] = h;
        __syncthreads();
        for (int off = 1; off < 256; off <<= 1) {
            int add = (t + off < 256) ? grp[t + off] : 0;
            __syncthreads();
            grp[t] += add;
            __syncthreads();
        }
        const int total = grp[1];
        have = (total >= HARD_K_);
        if (have) {
            {
                const int above = (t < 255) ? grp[t + 1] : 0;
                if (grp[t] >= HARD_K_ && above < HARD_K_) s_bin = t;
            }
            __syncthreads();
            const int b = s_bin;

            float e = 0.0f;
            if (t > b && h) e = (float)h * __expf((WLO + ((float)t - 0.5f) * BINW - 1.0f) * INV_T);
            #pragma unroll
            for (int o = 32; o > 0; o >>= 1) e += __shfl_xor(e, o);
            if ((t & 63) == 0) scf[t >> 6] = e;
            __syncthreads();
            if (t == 0) {
                const float Eab  = scf[0] + scf[1] + scf[2] + scf[3];
                const int   cab  = (b < 255) ? grp[b + 1] : 0;
                const float ebin = __expf((WLO + ((float)b - 0.5f) * BINW - 1.0f) * INV_T);
                const float sadj = Eab + (float)(HARD_K_ - cab) * ebin;
                s_Lq = INV_T + __logf(sadj);
            }
        } else {
            __syncthreads();   // hist path failed; safe to reuse LDS below
        }
    }

    if (!have) {
        // ---- exact fallback, inline (rare) ----
        int* fh = hist4;
        if (t < 128) zrow[t] = bf2f(zb[(size_t)orig * 128 + t]);
        __syncthreads();

        const int mylab = myLab;
        unsigned dv[64];
        float rm = -1e30f, rs = 0.0f;
        for (int k = 0; k < 128; k++) {
            const int j = t + 256 * k;
            float d = 0.0f;
            #pragma unroll
            for (int c = 0; c < 16; ++c) {
                const short8 qv = *(const short8*)(qb + (size_t)j * 128 + c * 8);
                #pragma unroll
                for (int e = 0; e < 8; ++e) d += zrow[c * 8 + e] * bf2f(qv[e]);
            }
            if (j < HARD_K_) {
                const float sv = d * INV_T;
                if (sv > rm) { rs = rs * __expf(rm - sv) + 1.0f; rm = sv; }
                else         { rs += __expf(sv - rm); }
            }
            const int q = qlab[j];
            const float mv = (q != mylab && q >= 0) ? d : -65504.0f;
            const __half h = __float2half(mv);
            unsigned short* pp = (unsigned short*)&dv[k >> 1];
            pp[k & 1] = *(const unsigned short*)&h;
        }

        if (opp == 0) {
            float rm2 = rm, rs2 = rs;
            #pragma unroll
            for (int o = 32; o > 0; o >>= 1) {
                const float om = __shfl_xor(rm2, o), os = __shfl_xor(rs2, o);
                const float nm = fmaxf(rm2, om);
                rs2 = rs2 * __expf(rm2 - nm) + os * __expf(om - nm);
                rm2 = nm;
            }
            if ((t & 63) == 0) { scf[t >> 6] = rm2; ((float*)sci)[t >> 6] = rs2; }
            __syncthreads();
            if (t == 0) {
                float M = -1e30f, Sx = 0.0f;
                for (int w = 0; w < 4; w++) {
                    const float nm = fmaxf(M, scf[w]);
                    Sx = Sx * __expf(M - nm) + ((float*)sci)[w] * __expf(scf[w] - nm);
                    M = nm;
                }
                s_Lq = M + __logf(Sx);
            }
        } else if (opp < HARD_K_) {
            float mm = -1e30f, ss = 0.0f;
            FOR_ALL_VALS(
                if (v > -60000.0f) {
                    const float sv = v * INV_T;
                    if (sv > mm) { ss = ss * __expf(mm - sv) + 1.0f; mm = sv; }
                    else         { ss += __expf(sv - mm); }
                } )
            #pragma unroll
            for (int o = 32; o > 0; o >>= 1) {
                const float om = __shfl_xor(mm, o), os = __shfl_xor(ss, o);
                const float nm = fmaxf(mm, om);
                ss = ss * __expf(mm - nm) + os * __expf(om - nm);
                mm = nm;
            }
            if ((t & 63) == 0) { scf[t >> 6] = mm; ((float*)sci)[t >> 6] = ss; }
            __syncthreads();
            if (t == 0) {
                float M = -1e30f, Sx = 0.0f;
                for (int w = 0; w < 4; w++) {
                    const float nm = fmaxf(M, scf[w]);
                    Sx = Sx * __expf(M - nm) + ((float*)sci)[w] * __expf(scf[w] - nm);
                    M = nm;
                }
                s_Lq = M + __logf(Sx);
            }
        } else {
            float mloc = -1e30f;
            FOR_ALL_VALS( mloc = fmaxf(mloc, v); )
            #pragma unroll
            for (int o = 32; o > 0; o >>= 1) mloc = fmaxf(mloc, __shfl_xor(mloc, o));
            if ((t & 63) == 0) scf[t >> 6] = mloc;
            __syncthreads();
            const float m = fmaxf(fmaxf(scf[0], scf[1]), fmaxf(scf[2], scf[3]));

            int c1 = 0, c2 = 0;
            const float w1 = m - 0.25f, w2 = m - 1.0f;
            FOR_ALL_VALS( c1 += (v >= w1); c2 += (v >= w2); )
            #pragma unroll
            for (int o = 32; o > 0; o >>= 1) { c1 += __shfl_xor(c1, o); c2 += __shfl_xor(c2, o); }
            if ((t & 63) == 0) { sci[t >> 6] = c1; }
            __syncthreads();
            const int C1 = sci[0] + sci[1] + sci[2] + sci[3];
            __syncthreads();
            if ((t & 63) == 0) { sci[t >> 6] = c2; }
            __syncthreads();
            const int C2 = sci[0] + sci[1] + sci[2] + sci[3];

            float lo;
            if      (C1 >= HARD_K_) lo = w1;
            else if (C2 >= HARD_K_) lo = w2;
            else                    lo = -1.01f;
            const float range = m - lo;
            const float scale = 1024.0f / range;

            for (int k = t; k < 1024; k += 256) fh[k] = 0;
            __syncthreads();
            FOR_ALL_VALS(
                if (v >= lo) {
                    const float bf = fminf((v - lo) * scale, 1023.0f);
                    atomicAdd(&fh[(int)bf], 1);
                } )
            __syncthreads();
            find_crossing(fh, grp, HARD_K_, &s_bin, &s_chi);
            const int   bin1 = s_bin, chi1 = s_chi;
            const float binw = range * (1.0f / 1024.0f);
            const float lo1  = lo + bin1 * binw;
            const float ssc  = 1024.0f / binw;

            for (int k = t; k < 1024; k += 256) fh[k] = 0;
            __syncthreads();
            FOR_ALL_VALS(
                if (v >= lo) {
                    const float bf = fminf((v - lo) * scale, 1023.0f);
                    if ((int)bf == bin1) {
                        const float sf = fminf(fmaxf((v - lo1) * ssc, 0.0f), 1023.0f);
                        atomicAdd(&fh[(int)sf], 1);
                    }
                } )
            __syncthreads();
            find_crossing(fh, grp, HARD_K_ - chi1, &s_bin2, &s_chi2);
            const float thr = lo1 + s_bin2 * (binw * (1.0f / 1024.0f));

            float sl = 0.0f; int cg = 0;
            FOR_ALL_VALS( if (v > thr) { cg++; sl += __expf((v - m) * INV_T); } )
            #pragma unroll
            for (int o = 32; o > 0; o >>= 1) { sl += __shfl_xor(sl, o); cg += __shfl_xor(cg, o); }
            if ((t & 63) == 0) { scf[t >> 6] = sl; sci[t >> 6] = cg; }
            __syncthreads();
            if (t == 0) {
                const float slt = scf[0] + scf[1] + scf[2] + scf[3];
                const int   cgt = sci[0] + sci[1] + sci[2] + sci[3];
                const float sadj = slt + ((float)HARD_K_ - (float)cgt) * __expf((thr - m) * INV_T);
                s_Lq = m * INV_T + __logf(sadj);
            }
        }
    }
    __syncthreads();                      // s_Lq visible to all

    // ---- phase B: batch lse + positive-pair loss for row orig (wave 0;
    //      identical element->lane mapping and shuffle order as the old
    //      batch_row_loss single-wave reduction -> bit-identical) ----
    if (t >= 64) return;
    const int lane = t;
    const uint4* rp = (const uint4*)(S + (size_t)orig * BATCH_N);  // 8 bf16 per uint4

    float v[32]; int lb[32];
    #pragma unroll
    for (int kk = 0; kk < 4; kk++) {
        const uint4 u = rp[lane + 64 * kk];
        const unsigned w[4] = {u.x, u.y, u.z, u.w};
        const int base = (lane + 64 * kk) * 8;
        #pragma unroll
        for (int q = 0; q < 4; q++) {
            v[kk * 8 + 2 * q]     = __uint_as_float(w[q] << 16);
            v[kk * 8 + 2 * q + 1] = __uint_as_float(w[q] & 0xFFFF0000u);
            const int i0 = base + 2 * q, i1 = base + 2 * q + 1;
            lb[kk * 8 + 2 * q]     = labels[(i0 & ~63) + ((i0 & 3) << 4) + ((i0 >> 2) & 15)];
            lb[kk * 8 + 2 * q + 1] = labels[(i1 & ~63) + ((i1 & 3) << 4) + ((i1 >> 2) & 15)];
        }
    }

    const float REF = INV_T;
    float sneg = 0.0f;
    #pragma unroll
    for (int k = 0; k < 32; k++) {
        const float ev = __expf(v[k] * INV_T - REF);
        sneg += (lb[k] != myLab) ? ev : 0.0f;
    }
    #pragma unroll
    for (int o = 32; o > 0; o >>= 1) sneg += __shfl_xor(sneg, o);
    const float lseb = (sneg > 0.0f) ? REF + __logf(sneg) : -1e30f;
    const float Lq = s_Lq;
    const float mx0 = fmaxf(lseb, Lq), mn0 = fminf(lseb, Lq);
    const float L = mx0 + __logf(1.0f + __expf(mn0 - mx0));

    float part = 0.0f; int cnt = 0;
    #pragma unroll
    for (int k = 0; k < 32; k++) {
        const int idx = ((lane + 64 * (k >> 3)) * 8) + (k & 7);
        const int col = (idx & ~63) + ((idx & 3) << 4) + ((idx >> 2) & 15);
        if (lb[k] == myLab && col != orig) {
            const float sv = v[k] * INV_T;
            const float mx = fmaxf(sv, L), mn = fminf(sv, L);
            part += (mx - sv) + __logf(1.0f + __expf(mn - mx));
            cnt++;
        }
    }
    #pragma unroll
    for (int o = 32; o > 0; o >>= 1) { part += __shfl_xor(part, o); cnt += __shfl_xor(cnt, o); }
    if (lane == 0) { part_out[orig] = part; cnt_out[orig] = cnt; }
}

// reduce 2048 per-row partials -> scalar loss. One block.
__global__ void __launch_bounds__(256) finalize_loss(const float* __restrict__ part,
                                                     const int* __restrict__ cnt,
                                                     float* __restrict__ out) {
    const int t = threadIdx.x;
    float s = 0.0f; int c = 0;
    #pragma unroll
    for (int k = 0; k < 8; k++) { s += part[t + 256 * k]; c += cnt[t + 256 * k]; }
    #pragma unroll
    for (int o = 32; o > 0; o >>= 1) { s += __shfl_xor(s, o); c += __shfl_xor(c, o); }
    __shared__ float sf[4]; __shared__ int sc[4];
    if ((t & 63) == 0) { sf[t >> 6] = s; sc[t >> 6] = c; }
    __syncthreads();
    if (t == 0) {
        const float st = sf[0] + sf[1] + sf[2] + sf[3];
        const int   ct = sc[0] + sc[1] + sc[2] + sc[3];
        out[0] = (ct > 0) ? (st / (float)ct) : 0.0f;
    }
}

// ---------------------------------------------------------------------------
extern "C" void kernel_launch(void* const* d_in, const int* in_sizes, int n_in,
                              void* d_out, int out_size, void* d_ws, size_t ws_size,
                              hipStream_t stream) {
    const float* emb    = (const float*)d_in[0];
    const int*   labels = (const int*)  d_in[1];
    const float* W1     = (const float*)d_in[2];
    const float* b1     = (const float*)d_in[3];
    const float* W2     = (const float*)d_in[4];
    const float* b2     = (const float*)d_in[5];
    const float* queue  = (const float*)d_in[6];
    const int*   qlab   = (const int*)  d_in[7];

    char* ws = (char*)d_ws;
    short*         Sbuf  = (short*)        (ws);              // 8 MB used (16 MB region)
    unsigned char* codes = (unsigned char*)(ws + 16777216);   // 64 MB
    short*         embb  = (short*)        (ws + 83886080);   // 3145728
    short*         hbf   = (short*)        (ws + 87031808);   // 3145728
    short*         zb    = (short*)        (ws + 90177536);   // 524288
    short*         qb    = (short*)        (ws + 90701824);   // 8388608
    short*         w1t   = (short*)        (ws + 99090432);   // 1179648
    short*         w2t   = (short*)        (ws + 100270080);  // 196608
    int*           qcnt  = (int*)          (ws + 100474880);  // 64
    int*           rcnt  = (int*)          (ws + 100474944);  // 64
    int*           pc    = (int*)          (ws + 100475008);  // 64
    int*           qpart = (int*)          (ws + 100475072);  // 512
    float*         partb = (float*)        (ws + 100475584);  // 8192
    int*           cntb  = (int*)          (ws + 100483776);  // 8192
    int*           colidx= (int*)          (ws + 100491968);  // 131072
    int*           qlabp = (int*)          (ws + 100623040);  // 131072
    int*           rowmap= (int*)          (ws + 100754112);  // 8192
    int*           rlabp = (int*)          (ws + 100762304);  // 8192

    dim3 blk(256);
    prep<<<dim3(5833), blk, 0, stream>>>(emb, embb, queue, qb, qlab, qpart, W1, w1t, W2, w2t, labels, rcnt, pc);
    mfma_h64<<<dim3(EMB_D_ / 128, BATCH_N / 64), blk, 0, stream>>>(embb, w1t, b1, hbf, EMB_D_, EMB_D_);
    znorm_perm<<<dim3(200), blk, 0, stream>>>(hbf, w2t, b2, zb, qlab, labels, qpart, rcnt,
                                              qcnt, colidx, qlabp, rowmap, rlabp, pc);
    mask8_spack<<<dim3(2560), blk, 0, stream>>>(zb, qb, codes, rlabp, qlabp, colidx, rowmap, qcnt, rcnt, Sbuf);
    tail_row<<<dim3(BATCH_N), blk, 0, stream>>>(codes, qcnt, rlabp, rowmap, zb, qb, qlab,
                                                Sbuf, labels, partb, cntb);
    finalize_loss<<<1, blk, 0, stream>>>(partb, cntb, (float*)d_out);
}

// Round 7
// 154.795 us; speedup vs baseline: 1.2443x; 1.0011x over previous
//
#include <hip/hip_runtime.h>
#include <hip/hip_fp16.h>

#define BATCH_N   2048
#define EMB_D_    768
#define PROJ_D_   128
#define QUEUE_N   32768
#define HARD_K_   512
static constexpr float INV_T  = 1.0f / 0.07f;
static constexpr float WLO    = 0.12f;              // code-0 boundary (512th opp val ~0.164)
static constexpr float S8ENC  = 255.0f / 0.88f;     // encode scale
static constexpr float BINW   = 0.88f / 255.0f;     // code bin width

typedef __attribute__((ext_vector_type(8))) short short8;
typedef __attribute__((ext_vector_type(4))) short short4v;
typedef __attribute__((ext_vector_type(4))) float f32x4;

__device__ __forceinline__ unsigned short f2bf(float f) {
    unsigned u = __float_as_uint(f);
    unsigned r = u + 0x7fffu + ((u >> 16) & 1u);   // RNE
    return (unsigned short)(r >> 16);
}
__device__ __forceinline__ float bf2f(short s) {
    return __uint_as_float(((unsigned)(unsigned short)s) << 16);
}
__device__ __forceinline__ int opp_of(int mylab, const int* __restrict__ qcnt) {
    const int same = (mylab == 0) ? qcnt[0] : ((mylab == 1) ? qcnt[1] : 0);
    return qcnt[2] - same;
}

// ---------------------------------------------------------------------------
// Merged prep: emb cast + qlab census (plain partial stores) + W1/W2
// transpose + row census + pc zero. Queue cast MOVED to the h64 dispatch
// (it idles at 192 blocks; cast blocks backfill its unused CUs).
// ---------------------------------------------------------------------------
__global__ void __launch_bounds__(256) prep(const float* __restrict__ emb, short* __restrict__ embb,
                                            const int* __restrict__ qlab, int* __restrict__ qpart,
                                            const float* __restrict__ W1, short* __restrict__ w1t,
                                            const float* __restrict__ W2, short* __restrict__ w2t,
                                            const int* __restrict__ labels, int* __restrict__ rcnt,
                                            int* __restrict__ pc) {
    __shared__ float tile[64][65];
    const int b = blockIdx.x, t = threadIdx.x;
    if (b < 1536) {
        const int i = b * 256 + t;
        const float4 f = ((const float4*)emb)[i];
        short4v o = {(short)f2bf(f.x), (short)f2bf(f.y), (short)f2bf(f.z), (short)f2bf(f.w)};
        ((short4v*)embb)[i] = o;
    } else if (b < 1568) {
        const int i = (b - 1536) * 256 + t;
        int c0 = 0, c1 = 0, cv = 0;
        for (int j = i; j < QUEUE_N; j += 8192) {
            const int q = qlab[j];
            c0 += (q == 0); c1 += (q == 1); cv += (q >= 0);
        }
        #pragma unroll
        for (int o = 32; o > 0; o >>= 1) {
            c0 += __shfl_xor(c0, o); c1 += __shfl_xor(c1, o); cv += __shfl_xor(cv, o);
        }
        int* red = (int*)tile;
        const int wv = t >> 6;
        if ((t & 63) == 0) { red[wv * 4 + 0] = c0; red[wv * 4 + 1] = c1; red[wv * 4 + 2] = cv; }
        __syncthreads();
        if (t == 0) {
            const int bb = (b - 1536) * 4;
            qpart[bb + 0] = red[0] + red[4] + red[8]  + red[12];
            qpart[bb + 1] = red[1] + red[5] + red[9]  + red[13];
            qpart[bb + 2] = red[2] + red[6] + red[10] + red[14];
        }
    } else if (b < 1736) {
        const int bid = b - 1568;
        const float* A; short* At; int R, C, bx, by;
        if (bid < 144) { A = W1; At = w1t; R = EMB_D_; C = EMB_D_;  bx = (bid % 12) * 64; by = (bid / 12) * 64; }
        else { const int b2 = bid - 144; A = W2; At = w2t; R = EMB_D_; C = PROJ_D_; bx = (b2 & 1) * 64; by = (b2 >> 1) * 64; }
        const int tc = t & 63, tg = t >> 6;
        #pragma unroll
        for (int i = 0; i < 16; i++) {
            const int r = tg * 16 + i;
            tile[r][tc] = A[(size_t)(by + r) * C + bx + tc];
        }
        __syncthreads();
        #pragma unroll
        for (int i = 0; i < 16; i++) {
            const int r = tg * 16 + i;
            At[(size_t)(bx + r) * R + by + tc] = (short)f2bf(tile[tc][r]);
        }
    } else {
        // row-label census (plain store) + pc zero
        int c = 0;
        for (int j = t; j < BATCH_N; j += 256) c += (labels[j] == 0);
        #pragma unroll
        for (int o = 32; o > 0; o >>= 1) c += __shfl_xor(c, o);
        int* red = (int*)tile;
        if ((t & 63) == 0) red[t >> 6] = c;
        __syncthreads();
        if (t == 0) rcnt[0] = red[0] + red[1] + red[2] + red[3];
        if (t < 8) pc[t] = 0;
    }
}

// ---------------------------------------------------------------------------
// GEMM1 + queue cast in ONE dispatch:
//  blocks 0..191:    bf16 MFMA NT 64x128 tile, fused bias+ReLU (critical path,
//                    scheduled first).
//  blocks 192..4287: queue f32 -> bf16 cast (backfills the ~75% of CUs the
//                    192-block GEMM leaves idle; qb not needed until mask8).
// ---------------------------------------------------------------------------
__global__ void __launch_bounds__(256) h64_qcast(const short* __restrict__ Ab,
                                                 const short* __restrict__ Bb,
                                                 const float* __restrict__ bias,
                                                 short* __restrict__ C,
                                                 int N, int K,
                                                 const float* __restrict__ queue,
                                                 short* __restrict__ qb) {
    const int t = threadIdx.x;
    if (blockIdx.x >= 192) {
        const int i = (blockIdx.x - 192) * 256 + t;
        const float4 f = ((const float4*)queue)[i];
        short4v o = {(short)f2bf(f.x), (short)f2bf(f.y), (short)f2bf(f.z), (short)f2bf(f.w)};
        ((short4v*)qb)[i] = o;
        return;
    }
    __shared__ __align__(16) short As[64 * 128];    // 16 KB
    __shared__ __align__(16) short Bs[128 * 128];   // 32 KB
    const int lane = t & 63, wv = t >> 6;
    const int l16 = lane & 15, l4 = lane >> 4;
    const int m0 = (blockIdx.x / 6) * 64, n0 = (blockIdx.x % 6) * 128;
    const int wn = wv * 32;

    f32x4 acc[4][2];
    #pragma unroll
    for (int i = 0; i < 4; ++i)
        #pragma unroll
        for (int j = 0; j < 2; ++j) acc[i][j] = f32x4{0.f, 0.f, 0.f, 0.f};

    for (int kb = 0; kb < K; kb += 128) {
        __syncthreads();
        #pragma unroll
        for (int it = 0; it < 4; ++it) {            // A: 16 units of 512 shorts
            const int r = it * 4 + wv, row = r * 4 + l4, cg = l16 ^ (row & 15);
            __builtin_amdgcn_global_load_lds(
                (const __attribute__((address_space(1))) void*)(Ab + (size_t)(m0 + row) * K + kb + cg * 8),
                (__attribute__((address_space(3))) void*)(As + r * 512), 16, 0, 0);
        }
        #pragma unroll
        for (int it = 0; it < 8; ++it) {            // B: 32 units
            const int r = it * 4 + wv, row = r * 4 + l4, cg = l16 ^ (row & 15);
            __builtin_amdgcn_global_load_lds(
                (const __attribute__((address_space(1))) void*)(Bb + (size_t)(n0 + row) * K + kb + cg * 8),
                (__attribute__((address_space(3))) void*)(Bs + r * 512), 16, 0, 0);
        }
        __syncthreads();
        #pragma unroll
        for (int ks = 0; ks < 4; ++ks) {
            short8 af[4], bfr[2];
            const int ch = (ks * 4 + l4) ^ l16;
            #pragma unroll
            for (int i = 0; i < 4; ++i)
                af[i] = *(const short8*)(As + (i * 16 + l16) * 128 + ch * 8);
            #pragma unroll
            for (int j = 0; j < 2; ++j)
                bfr[j] = *(const short8*)(Bs + (wn + j * 16 + l16) * 128 + ch * 8);
            #pragma unroll
            for (int i = 0; i < 4; ++i)
                #pragma unroll
                for (int j = 0; j < 2; ++j)
                    acc[i][j] = __builtin_amdgcn_mfma_f32_16x16x32_bf16(af[i], bfr[j], acc[i][j], 0, 0, 0);
        }
    }

    float bsv[2];
    #pragma unroll
    for (int j = 0; j < 2; ++j) bsv[j] = bias[n0 + wn + j * 16 + l16];
    #pragma unroll
    for (int i = 0; i < 4; ++i)
        #pragma unroll
        for (int r = 0; r < 4; ++r) {
            const int m = m0 + i * 16 + l4 * 4 + r;
            #pragma unroll
            for (int j = 0; j < 2; ++j) {
                const int n = n0 + wn + j * 16 + l16;
                const float v = fmaxf(acc[i][j][r] + bsv[j], 0.0f);
                C[(size_t)m * N + n] = (short)f2bf(v);
            }
        }
}

// ---------------------------------------------------------------------------
// Fused dispatch: z-GEMM (M-tile 32) + permutation builder.
// blocks 0..63: z-norm; 64..191: queue-col perm; 192..199: row perm.
// ---------------------------------------------------------------------------
__global__ void __launch_bounds__(256) znorm_perm(const short* __restrict__ Ab,
                                                  const short* __restrict__ Bb,
                                                  const float* __restrict__ bias,
                                                  short* __restrict__ zb,
                                                  const int* __restrict__ qlab,
                                                  const int* __restrict__ labels,
                                                  const int* __restrict__ qpart,
                                                  const int* __restrict__ rcnt,
                                                  int* __restrict__ qcnt,
                                                  int* __restrict__ colidx,
                                                  int* __restrict__ qlabp,
                                                  int* __restrict__ rowmap,
                                                  int* __restrict__ rlabp,
                                                  int* __restrict__ pc) {
    __shared__ __align__(16) short As[32 * 128];    // 8 KB
    __shared__ __align__(16) short Bs[128 * 128];   // 32 KB
    __shared__ float ssq[32];
    __shared__ int wcnt[4][3];
    __shared__ int gbase[3];
    const int blk = blockIdx.x;
    const int t = threadIdx.x;
    const int lane = t & 63, wv = t >> 6;

    if (blk >= 64) {
        const unsigned long long below = (1ull << lane) - 1ull;
        int q0 = 0, q1 = 0, qv = 0;
        for (int i = 0; i < 32; ++i) {
            q0 += qpart[i * 4]; q1 += qpart[i * 4 + 1]; qv += qpart[i * 4 + 2];
        }
        if (blk < 192) {
            const int cb = blk - 64;
            if (cb == 0 && t == 0) { qcnt[0] = q0; qcnt[1] = q1; qcnt[2] = qv; }
            const int j = cb * 256 + t;
            const int q = qlab[j];
            const int cls = (q == 0) ? 0 : ((q == 1) ? 1 : 2);
            const unsigned long long b0 = __ballot(cls == 0);
            const unsigned long long b1 = __ballot(cls == 1);
            const unsigned long long b2 = __ballot(cls == 2);
            const int rank = (cls == 0) ? __popcll(b0 & below)
                           : ((cls == 1) ? __popcll(b1 & below) : __popcll(b2 & below));
            if (lane == 0) {
                wcnt[wv][0] = __popcll(b0); wcnt[wv][1] = __popcll(b1); wcnt[wv][2] = __popcll(b2);
            }
            __syncthreads();
            if (t < 3) {
                const int tot = wcnt[0][t] + wcnt[1][t] + wcnt[2][t] + wcnt[3][t];
                gbase[t] = atomicAdd(&pc[t], tot);
            }
            __syncthreads();
            int wb = 0;
            #pragma unroll
            for (int w = 0; w < 4; ++w) if (w < wv) wb += wcnt[w][cls];
            const int cbase = (cls == 0) ? 0 : ((cls == 1) ? q0 : q0 + q1);
            const int pos = cbase + gbase[cls] + wb + rank;
            colidx[pos] = j; qlabp[pos] = q;
        } else {
            const int r = (blk - 192) * 256 + t;
            const int l = labels[r];
            const int cls = (l == 0) ? 0 : 1;
            const unsigned long long b0 = __ballot(cls == 0);
            const unsigned long long b1 = __ballot(cls == 1);
            const int rank = (cls == 0) ? __popcll(b0 & below) : __popcll(b1 & below);
            if (lane == 0) { wcnt[wv][0] = __popcll(b0); wcnt[wv][1] = __popcll(b1); }
            __syncthreads();
            if (t < 2) {
                const int tot = wcnt[0][t] + wcnt[1][t] + wcnt[2][t] + wcnt[3][t];
                gbase[t] = atomicAdd(&pc[3 + t], tot);
            }
            __syncthreads();
            int wb = 0;
            #pragma unroll
            for (int w = 0; w < 4; ++w) if (w < wv) wb += wcnt[w][cls];
            const int cbase = (cls == 0) ? 0 : rcnt[0];
            const int pos = cbase + gbase[cls] + wb + rank;
            rowmap[pos] = r; rlabp[pos] = l;
        }
        return;
    }

    // ---- z GEMM path: 32-row M-tile, fused bias + L2-normalize ----
    const int l16 = lane & 15, l4 = lane >> 4;
    const int m0 = blk * 32;
    const int wn = wv * 32;
    const int K = EMB_D_;

    if (t < 32) ssq[t] = 0.0f;

    f32x4 acc[2][2];
    #pragma unroll
    for (int i = 0; i < 2; ++i)
        #pragma unroll
        for (int j = 0; j < 2; ++j) acc[i][j] = f32x4{0.f, 0.f, 0.f, 0.f};

    for (int kb = 0; kb < K; kb += 128) {
        __syncthreads();
        #pragma unroll
        for (int it = 0; it < 2; ++it) {
            const int r = it * 4 + wv, row = r * 4 + l4, cg = l16 ^ (row & 15);
            __builtin_amdgcn_global_load_lds(
                (const __attribute__((address_space(1))) void*)(Ab + (size_t)(m0 + row) * K + kb + cg * 8),
                (__attribute__((address_space(3))) void*)(As + r * 512), 16, 0, 0);
        }
        #pragma unroll
        for (int it = 0; it < 8; ++it) {
            const int r = it * 4 + wv, row = r * 4 + l4, cg = l16 ^ (row & 15);
            __builtin_amdgcn_global_load_lds(
                (const __attribute__((address_space(1))) void*)(Bb + (size_t)(row) * K + kb + cg * 8),
                (__attribute__((address_space(3))) void*)(Bs + r * 512), 16, 0, 0);
        }
        __syncthreads();
        #pragma unroll
        for (int ks = 0; ks < 4; ++ks) {
            short8 af[2], bfr[2];
            const int ch = (ks * 4 + l4) ^ l16;
            #pragma unroll
            for (int i = 0; i < 2; ++i)
                af[i] = *(const short8*)(As + (i * 16 + l16) * 128 + ch * 8);
            #pragma unroll
            for (int j = 0; j < 2; ++j)
                bfr[j] = *(const short8*)(Bs + (wn + j * 16 + l16) * 128 + ch * 8);
            #pragma unroll
            for (int i = 0; i < 2; ++i)
                #pragma unroll
                for (int j = 0; j < 2; ++j)
                    acc[i][j] = __builtin_amdgcn_mfma_f32_16x16x32_bf16(af[i], bfr[j], acc[i][j], 0, 0, 0);
        }
    }

    float bsv[2];
    #pragma unroll
    for (int j = 0; j < 2; ++j) bsv[j] = bias[wn + j * 16 + l16];
    #pragma unroll
    for (int i = 0; i < 2; ++i)
        #pragma unroll
        for (int r = 0; r < 4; ++r) {
            float p = 0.0f;
            #pragma unroll
            for (int j = 0; j < 2; ++j) {
                acc[i][j][r] += bsv[j];
                p += acc[i][j][r] * acc[i][j][r];
            }
            #pragma unroll
            for (int o = 8; o > 0; o >>= 1) p += __shfl_xor(p, o);
            if (l16 == 0) atomicAdd(&ssq[i * 16 + l4 * 4 + r], p);
        }
    __syncthreads();
    #pragma unroll
    for (int i = 0; i < 2; ++i)
        #pragma unroll
        for (int r = 0; r < 4; ++r) {
            const int lrow = i * 16 + l4 * 4 + r;
            const float inv = rsqrtf(ssq[lrow]);
            #pragma unroll
            for (int j = 0; j < 2; ++j)
                zb[(size_t)(m0 + lrow) * PROJ_D_ + wn + j * 16 + l16] =
                    (short)f2bf(acc[i][j][r] * inv);
        }
}

// ---------------------------------------------------------------------------
// Combined dispatch, 48 KB LDS -> 3 blocks/CU:
//  blocks 0..2047:   masked queue GEMM -> u8 codes, 64-row M-tile,
//                    label-partitioned (half exit), register-prefetched
//                    gather indices (single vmcnt drain at block start).
//  blocks 2048..2559: S = z z^T 64x128 tile, packed bf16 out (backfills
//                    the CUs freed by exited mask8 blocks).
// ---------------------------------------------------------------------------
__global__ void __launch_bounds__(256) mask8_spack(const short* __restrict__ zb,
                                                   const short* __restrict__ qb,
                                                   unsigned char* __restrict__ codes,
                                                   const int* __restrict__ rlabp,
                                                   const int* __restrict__ qlabp,
                                                   const int* __restrict__ colidx,
                                                   const int* __restrict__ rowmap,
                                                   const int* __restrict__ qcnt,
                                                   const int* __restrict__ rcnt,
                                                   short* __restrict__ Sbuf) {
    __shared__ __align__(16) short As[64 * 128];    // 16 KB
    __shared__ __align__(16) short Bs[128 * 128];   // 32 KB
    const int bid = blockIdx.x, t = threadIdx.x;
    const int lane = t & 63, wv = t >> 6;
    const int l16 = lane & 15, l4 = lane >> 4;
    const int wm = (wv & 1) * 32, wn = (wv >> 1) * 64;

    if (bid >= 2048) {
        // ---- S GEMM tile (64x128) ----
        const int q = bid - 2048;
        const int m0 = (q >> 4) * 64, n0 = (q & 15) * 128;
        #pragma unroll
        for (int it = 0; it < 4; ++it) {
            const int r = it * 4 + wv, row = r * 4 + l4, cg = l16 ^ (row & 15);
            __builtin_amdgcn_global_load_lds(
                (const __attribute__((address_space(1))) void*)(zb + (size_t)(m0 + row) * 128 + cg * 8),
                (__attribute__((address_space(3))) void*)(As + r * 512), 16, 0, 0);
        }
        #pragma unroll
        for (int it = 0; it < 8; ++it) {
            const int r = it * 4 + wv, row = r * 4 + l4, cg = l16 ^ (row & 15);
            __builtin_amdgcn_global_load_lds(
                (const __attribute__((address_space(1))) void*)(zb + (size_t)(n0 + row) * 128 + cg * 8),
                (__attribute__((address_space(3))) void*)(Bs + r * 512), 16, 0, 0);
        }
        __syncthreads();

        f32x4 acc[2][4];
        #pragma unroll
        for (int i = 0; i < 2; ++i)
            #pragma unroll
            for (int j = 0; j < 4; ++j) acc[i][j] = f32x4{0.f, 0.f, 0.f, 0.f};

        #pragma unroll
        for (int ks = 0; ks < 4; ++ks) {
            short8 af[2], bfr[4];
            const int ch = (ks * 4 + l4) ^ l16;
            #pragma unroll
            for (int i = 0; i < 2; ++i)
                af[i]  = *(const short8*)(As + (wm + i * 16 + l16) * 128 + ch * 8);
            #pragma unroll
            for (int j = 0; j < 4; ++j)
                bfr[j] = *(const short8*)(Bs + (wn + j * 16 + l16) * 128 + ch * 8);
            #pragma unroll
            for (int i = 0; i < 2; ++i)
                #pragma unroll
                for (int j = 0; j < 4; ++j)
                    acc[i][j] = __builtin_amdgcn_mfma_f32_16x16x32_bf16(af[i], bfr[j], acc[i][j], 0, 0, 0);
        }
        #pragma unroll
        for (int i = 0; i < 2; ++i)
            #pragma unroll
            for (int r = 0; r < 4; ++r) {
                const int m = m0 + wm + i * 16 + l4 * 4 + r;
                union { unsigned short u[4]; uint2 d; } pk;
                #pragma unroll
                for (int j = 0; j < 4; ++j) pk.u[j] = f2bf(acc[i][j][r]);
                *(uint2*)(Sbuf + (size_t)m * BATCH_N + n0 + wn + l16 * 4) = pk.d;
            }
        return;
    }

    // ---- mask8 path (64-row M-tile) ----
    const int bx = bid & 63, by = bid >> 6;
    const int m0 = by * 64;
    const int c0 = qcnt[0], c1v = qcnt[1], r0 = rcnt[0];
    int lo, hi;
    if (m0 + 64 <= r0)  { lo = c0; hi = c0 + c1v; }   // label-0 rows -> label-1 cols
    else if (m0 >= r0)  { lo = 0;  hi = c0; }         // label-1 rows -> label-0 cols
    else                { lo = 0;  hi = c0 + c1v; }   // mixed boundary tile
    const int bs = bx * 512;
    if (bs + 512 <= lo || bs >= hi) return;           // uniform block exit

    // prefetch all indirection into registers (one wait, then pure ALU)
    int ra[4], ca[32], la[8], qa[16];
    #pragma unroll
    for (int it = 0; it < 4; ++it)
        ra[it] = rowmap[m0 + (it * 4 + wv) * 4 + l4];
    #pragma unroll
    for (int tt = 0; tt < 4; ++tt)
        #pragma unroll
        for (int it = 0; it < 8; ++it)
            ca[tt * 8 + it] = colidx[bs + tt * 128 + (it * 4 + wv) * 4 + l4];
    #pragma unroll
    for (int i = 0; i < 2; ++i)
        #pragma unroll
        for (int r = 0; r < 4; ++r)
            la[i * 4 + r] = rlabp[m0 + wm + i * 16 + l4 * 4 + r];
    #pragma unroll
    for (int tt = 0; tt < 4; ++tt)
        #pragma unroll
        for (int j = 0; j < 4; ++j)
            qa[tt * 4 + j] = qlabp[bs + tt * 128 + wn + j * 16 + l16];

    #pragma unroll
    for (int it = 0; it < 4; ++it) {
        const int r = it * 4 + wv, row = r * 4 + l4, cg = l16 ^ (row & 15);
        __builtin_amdgcn_global_load_lds(
            (const __attribute__((address_space(1))) void*)(zb + (size_t)ra[it] * 128 + cg * 8),
            (__attribute__((address_space(3))) void*)(As + r * 512), 16, 0, 0);
    }
    #pragma unroll
    for (int it = 0; it < 8; ++it) {
        const int r = it * 4 + wv, row = r * 4 + l4, cg = l16 ^ (row & 15);
        __builtin_amdgcn_global_load_lds(
            (const __attribute__((address_space(1))) void*)(qb + (size_t)ca[it] * 128 + cg * 8),
            (__attribute__((address_space(3))) void*)(Bs + r * 512), 16, 0, 0);
    }
    const float C0 = 1.0f - WLO * S8ENC;
    __syncthreads();

    #pragma unroll
    for (int tt = 0; tt < 4; ++tt) {
        const int n0 = bs + tt * 128;

        f32x4 acc[2][4];
        #pragma unroll
        for (int i = 0; i < 2; ++i)
            #pragma unroll
            for (int j = 0; j < 4; ++j) acc[i][j] = f32x4{0.f, 0.f, 0.f, 0.f};

        #pragma unroll
        for (int ks = 0; ks < 4; ++ks) {
            short8 af[2], bfr[4];
            const int ch = (ks * 4 + l4) ^ l16;
            #pragma unroll
            for (int i = 0; i < 2; ++i)
                af[i]  = *(const short8*)(As + (wm + i * 16 + l16) * 128 + ch * 8);
            #pragma unroll
            for (int j = 0; j < 4; ++j)
                bfr[j] = *(const short8*)(Bs + (wn + j * 16 + l16) * 128 + ch * 8);
            #pragma unroll
            for (int i = 0; i < 2; ++i)
                #pragma unroll
                for (int j = 0; j < 4; ++j)
                    acc[i][j] = __builtin_amdgcn_mfma_f32_16x16x32_bf16(af[i], bfr[j], acc[i][j], 0, 0, 0);
        }

        if (tt < 3) {
            __syncthreads();          // all waves done reading Bs tile tt
            #pragma unroll
            for (int it = 0; it < 8; ++it) {
                const int r = it * 4 + wv, row = r * 4 + l4, cg = l16 ^ (row & 15);
                __builtin_amdgcn_global_load_lds(
                    (const __attribute__((address_space(1))) void*)(qb + (size_t)ca[(tt + 1) * 8 + it] * 128 + cg * 8),
                    (__attribute__((address_space(3))) void*)(Bs + r * 512), 16, 0, 0);
            }
        }

        // epilogue for this tile (overlaps next tile's B staging)
        float a0[4], a1[4];
        #pragma unroll
        for (int j = 0; j < 4; ++j) {
            const int q = qa[tt * 4 + j];
            a0[j] = (q >= 0 && q != 0) ? C0 : -1e9f;
            a1[j] = (q >= 0 && q != 1) ? C0 : -1e9f;
        }
        #pragma unroll
        for (int i = 0; i < 2; ++i) {
            #pragma unroll
            for (int r = 0; r < 4; ++r) {
                const int m  = m0 + wm + i * 16 + l4 * 4 + r;
                const bool z = (la[i * 4 + r] == 0);
                unsigned pk = 0;
                #pragma unroll
                for (int j = 0; j < 4; ++j) {
                    const float add = z ? a0[j] : a1[j];
                    const float f = fmaf(acc[i][j][r], S8ENC, add);
#if __has_builtin(__builtin_amdgcn_cvt_pk_u8_f32)
                    pk = __builtin_amdgcn_cvt_pk_u8_f32(f, j, pk);
#else
                    const unsigned c = (unsigned)fminf(fmaxf(f, 0.0f), 255.0f);
                    pk |= c << (8 * j);
#endif
                }
                *(unsigned*)(codes + (size_t)m * QUEUE_N + n0 + wn + l16 * 4) = pk;
            }
        }
        if (tt < 3) __syncthreads();  // next tile's B staged (barrier drains vmcnt)
    }
}

// ---------------------------------------------------------------------------
// Histogram crossing search (used by inline fallback)
// ---------------------------------------------------------------------------
__device__ __forceinline__ void find_crossing(int* hist, int* grp, int target,
                                              int* s_bin, int* s_chi) {
    const int t = threadIdx.x;
    const int b0 = hist[4*t], b1 = hist[4*t+1], b2 = hist[4*t+2], b3 = hist[4*t+3];
    grp[t] = b0 + b1 + b2 + b3;
    __syncthreads();
    for (int off = 1; off < 256; off <<= 1) {
        int add = (t + off < 256) ? grp[t + off] : 0;
        __syncthreads();
        grp[t] += add;
        __syncthreads();
    }
    int cab = (t < 255) ? grp[t + 1] : 0;
    const int hb[4] = {b0, b1, b2, b3};
    #pragma unroll
    for (int i = 3; i >= 0; i--) {
        const int h = hb[i];
        if (cab < target && cab + h >= target) { *s_bin = 4*t + i; *s_chi = cab; }
        cab += h;
    }
    __syncthreads();
}

// iterate all 128 packed-half2 values
#define FOR_ALL_VALS(BODY)                                                   \
    _Pragma("unroll")                                                        \
    for (int _k = 0; _k < 64; _k++) {                                        \
        const float2 _f = __half22float2(*(const __half2*)&dv[_k]);          \
        { const float v = _f.x; BODY }                                       \
        { const float v = _f.y; BODY }                                       \
    }

// ---------------------------------------------------------------------------
// Fused tail: one block per partitioned row p.
//  Phase A: topk lse from codes (hist path; exact fallback inline).
//           ALL control flow is block-uniform; L_q lands in s_Lq.
//  Phase B: wave 0 replicates batch_row_loss's single-wave reduction for
//           row orig (bit-identical order) -> part/cnt.
// ---------------------------------------------------------------------------
__global__ void __launch_bounds__(256) tail_row(const unsigned char* __restrict__ codes,
                                                const int* __restrict__ qcnt,
                                                const int* __restrict__ rlabp,
                                                const int* __restrict__ rowmap,
                                                const short* __restrict__ zb,
                                                const short* __restrict__ qb,
                                                const int* __restrict__ qlab,
                                                const short* __restrict__ S,
                                                const int* __restrict__ labels,
                                                float* __restrict__ part_out,
                                                int* __restrict__ cnt_out) {
    __shared__ int hist4[1024];          // 4 per-wave hists; reused as fh by fallback
    __shared__ int grp[256];             // suffix-scan buffer; reused by fallback
    __shared__ float zrow[128];
    __shared__ int s_bin, s_chi, s_bin2, s_chi2;
    __shared__ float scf[4];
    __shared__ int sci[4];
    __shared__ float s_Lq;
    const int p = blockIdx.x, t = threadIdx.x;
    const int orig  = rowmap[p];
    const int myLab = rlabp[p];
    const int opp   = opp_of(myLab, qcnt);

    bool have = false;                   // block-uniform
    if (opp >= HARD_K_) {
        for (int k = t; k < 1024; k += 256) hist4[k] = 0;
        __syncthreads();

        const int c0 = qcnt[0];
        const int lo = (myLab == 0) ? c0 : 0;
        const int hi = (myLab == 0) ? c0 + qcnt[1] : c0;
        const int klo = (lo & ~511) >> 4;            // uint4 index (16 cols each)
        const int khi = ((hi + 511) & ~511) >> 4;

        int* myh = hist4 + (t >> 6) * 256;
        const uint4* rowp = (const uint4*)(codes + (size_t)p * QUEUE_N);
        for (int k = klo + t; k < khi; k += 256) {
            const uint4 u = rowp[k];
            const unsigned w[4] = {u.x, u.y, u.z, u.w};
            #pragma unroll
            for (int q = 0; q < 4; q++)
                #pragma unroll
                for (int s = 0; s < 4; s++) {
                    const int c = (w[q] >> (8 * s)) & 0xFF;
                    if (c) atomicAdd(&myh[c], 1);
                }
        }
        __syncthreads();
        const int h = hist4[t] + hist4[256 + t] + hist4[512 + t] + hist4[768 + t];
        grp[t] = h;
        __syncthreads();
        for (int off = 1; off < 256; off <<= 1) {
            int add = (t + off < 256) ? grp[t + off] : 0;
            __syncthreads();
            grp[t] += add;
            __syncthreads();
        }
        const int total = grp[1];
        have = (total >= HARD_K_);
        if (have) {
            {
                const int above = (t < 255) ? grp[t + 1] : 0;
                if (grp[t] >= HARD_K_ && above < HARD_K_) s_bin = t;
            }
            __syncthreads();
            const int b = s_bin;

            float e = 0.0f;
            if (t > b && h) e = (float)h * __expf((WLO + ((float)t - 0.5f) * BINW - 1.0f) * INV_T);
            #pragma unroll
            for (int o = 32; o > 0; o >>= 1) e += __shfl_xor(e, o);
            if ((t & 63) == 0) scf[t >> 6] = e;
            __syncthreads();
            if (t == 0) {
                const float Eab  = scf[0] + scf[1] + scf[2] + scf[3];
                const int   cab  = (b < 255) ? grp[b + 1] : 0;
                const float ebin = __expf((WLO + ((float)b - 0.5f) * BINW - 1.0f) * INV_T);
                const float sadj = Eab + (float)(HARD_K_ - cab) * ebin;
                s_Lq = INV_T + __logf(sadj);
            }
        } else {
            __syncthreads();   // hist path failed; safe to reuse LDS below
        }
    }

    if (!have) {
        // ---- exact fallback, inline (rare) ----
        int* fh = hist4;
        if (t < 128) zrow[t] = bf2f(zb[(size_t)orig * 128 + t]);
        __syncthreads();

        const int mylab = myLab;
        unsigned dv[64];
        float rm = -1e30f, rs = 0.0f;
        for (int k = 0; k < 128; k++) {
            const int j = t + 256 * k;
            float d = 0.0f;
            #pragma unroll
            for (int c = 0; c < 16; ++c) {
                const short8 qv = *(const short8*)(qb + (size_t)j * 128 + c * 8);
                #pragma unroll
                for (int e = 0; e < 8; ++e) d += zrow[c * 8 + e] * bf2f(qv[e]);
            }
            if (j < HARD_K_) {
                const float sv = d * INV_T;
                if (sv > rm) { rs = rs * __expf(rm - sv) + 1.0f; rm = sv; }
                else         { rs += __expf(sv - rm); }
            }
            const int q = qlab[j];
            const float mv = (q != mylab && q >= 0) ? d : -65504.0f;
            const __half h = __float2half(mv);
            unsigned short* pp = (unsigned short*)&dv[k >> 1];
            pp[k & 1] = *(const unsigned short*)&h;
        }

        if (opp == 0) {
            float rm2 = rm, rs2 = rs;
            #pragma unroll
            for (int o = 32; o > 0; o >>= 1) {
                const float om = __shfl_xor(rm2, o), os = __shfl_xor(rs2, o);
                const float nm = fmaxf(rm2, om);
                rs2 = rs2 * __expf(rm2 - nm) + os * __expf(om - nm);
                rm2 = nm;
            }
            if ((t & 63) == 0) { scf[t >> 6] = rm2; ((float*)sci)[t >> 6] = rs2; }
            __syncthreads();
            if (t == 0) {
                float M = -1e30f, Sx = 0.0f;
                for (int w = 0; w < 4; w++) {
                    const float nm = fmaxf(M, scf[w]);
                    Sx = Sx * __expf(M - nm) + ((float*)sci)[w] * __expf(scf[w] - nm);
                    M = nm;
                }
                s_Lq = M + __logf(Sx);
            }
        } else if (opp < HARD_K_) {
            float mm = -1e30f, ss = 0.0f;
            FOR_ALL_VALS(
                if (v > -60000.0f) {
                    const float sv = v * INV_T;
                    if (sv > mm) { ss = ss * __expf(mm - sv) + 1.0f; mm = sv; }
                    else         { ss += __expf(sv - mm); }
                } )
            #pragma unroll
            for (int o = 32; o > 0; o >>= 1) {
                const float om = __shfl_xor(mm, o), os = __shfl_xor(ss, o);
                const float nm = fmaxf(mm, om);
                ss = ss * __expf(mm - nm) + os * __expf(om - nm);
                mm = nm;
            }
            if ((t & 63) == 0) { scf[t >> 6] = mm; ((float*)sci)[t >> 6] = ss; }
            __syncthreads();
            if (t == 0) {
                float M = -1e30f, Sx = 0.0f;
                for (int w = 0; w < 4; w++) {
                    const float nm = fmaxf(M, scf[w]);
                    Sx = Sx * __expf(M - nm) + ((float*)sci)[w] * __expf(scf[w] - nm);
                    M = nm;
                }
                s_Lq = M + __logf(Sx);
            }
        } else {
            float mloc = -1e30f;
            FOR_ALL_VALS( mloc = fmaxf(mloc, v); )
            #pragma unroll
            for (int o = 32; o > 0; o >>= 1) mloc = fmaxf(mloc, __shfl_xor(mloc, o));
            if ((t & 63) == 0) scf[t >> 6] = mloc;
            __syncthreads();
            const float m = fmaxf(fmaxf(scf[0], scf[1]), fmaxf(scf[2], scf[3]));

            int c1 = 0, c2 = 0;
            const float w1 = m - 0.25f, w2 = m - 1.0f;
            FOR_ALL_VALS( c1 += (v >= w1); c2 += (v >= w2); )
            #pragma unroll
            for (int o = 32; o > 0; o >>= 1) { c1 += __shfl_xor(c1, o); c2 += __shfl_xor(c2, o); }
            if ((t & 63) == 0) { sci[t >> 6] = c1; }
            __syncthreads();
            const int C1 = sci[0] + sci[1] + sci[2] + sci[3];
            __syncthreads();
            if ((t & 63) == 0) { sci[t >> 6] = c2; }
            __syncthreads();
            const int C2 = sci[0] + sci[1] + sci[2] + sci[3];

            float lo;
            if      (C1 >= HARD_K_) lo = w1;
            else if (C2 >= HARD_K_) lo = w2;
            else                    lo = -1.01f;
            const float range = m - lo;
            const float scale = 1024.0f / range;

            for (int k = t; k < 1024; k += 256) fh[k] = 0;
            __syncthreads();
            FOR_ALL_VALS(
                if (v >= lo) {
                    const float bf = fminf((v - lo) * scale, 1023.0f);
                    atomicAdd(&fh[(int)bf], 1);
                } )
            __syncthreads();
            find_crossing(fh, grp, HARD_K_, &s_bin, &s_chi);
            const int   bin1 = s_bin, chi1 = s_chi;
            const float binw = range * (1.0f / 1024.0f);
            const float lo1  = lo + bin1 * binw;
            const float ssc  = 1024.0f / binw;

            for (int k = t; k < 1024; k += 256) fh[k] = 0;
            __syncthreads();
            FOR_ALL_VALS(
                if (v >= lo) {
                    const float bf = fminf((v - lo) * scale, 1023.0f);
                    if ((int)bf == bin1) {
                        const float sf = fminf(fmaxf((v - lo1) * ssc, 0.0f), 1023.0f);
                        atomicAdd(&fh[(int)sf], 1);
                    }
                } )
            __syncthreads();
            find_crossing(fh, grp, HARD_K_ - chi1, &s_bin2, &s_chi2);
            const float thr = lo1 + s_bin2 * (binw * (1.0f / 1024.0f));

            float sl = 0.0f; int cg = 0;
            FOR_ALL_VALS( if (v > thr) { cg++; sl += __expf((v - m) * INV_T); } )
            #pragma unroll
            for (int o = 32; o > 0; o >>= 1) { sl += __shfl_xor(sl, o); cg += __shfl_xor(cg, o); }
            if ((t & 63) == 0) { scf[t >> 6] = sl; sci[t >> 6] = cg; }
            __syncthreads();
            if (t == 0) {
                const float slt = scf[0] + scf[1] + scf[2] + scf[3];
                const int   cgt = sci[0] + sci[1] + sci[2] + sci[3];
                const float sadj = slt + ((float)HARD_K_ - (float)cgt) * __expf((thr - m) * INV_T);
                s_Lq = m * INV_T + __logf(sadj);
            }
        }
    }
    __syncthreads();                      // s_Lq visible to all

    // ---- phase B: batch lse + positive-pair loss for row orig (wave 0;
    //      identical element->lane mapping and shuffle order as the old
    //      batch_row_loss single-wave reduction -> bit-identical) ----
    if (t >= 64) return;
    const int lane = t;
    const uint4* rp = (const uint4*)(S + (size_t)orig * BATCH_N);  // 8 bf16 per uint4

    float v[32]; int lb[32];
    #pragma unroll
    for (int kk = 0; kk < 4; kk++) {
        const uint4 u = rp[lane + 64 * kk];
        const unsigned w[4] = {u.x, u.y, u.z, u.w};
        const int base = (lane + 64 * kk) * 8;
        #pragma unroll
        for (int q = 0; q < 4; q++) {
            v[kk * 8 + 2 * q]     = __uint_as_float(w[q] << 16);
            v[kk * 8 + 2 * q + 1] = __uint_as_float(w[q] & 0xFFFF0000u);
            const int i0 = base + 2 * q, i1 = base + 2 * q + 1;
            lb[kk * 8 + 2 * q]     = labels[(i0 & ~63) + ((i0 & 3) << 4) + ((i0 >> 2) & 15)];
            lb[kk * 8 + 2 * q + 1] = labels[(i1 & ~63) + ((i1 & 3) << 4) + ((i1 >> 2) & 15)];
        }
    }

    const float REF = INV_T;
    float sneg = 0.0f;
    #pragma unroll
    for (int k = 0; k < 32; k++) {
        const float ev = __expf(v[k] * INV_T - REF);
        sneg += (lb[k] != myLab) ? ev : 0.0f;
    }
    #pragma unroll
    for (int o = 32; o > 0; o >>= 1) sneg += __shfl_xor(sneg, o);
    const float lseb = (sneg > 0.0f) ? REF + __logf(sneg) : -1e30f;
    const float Lq = s_Lq;
    const float mx0 = fmaxf(lseb, Lq), mn0 = fminf(lseb, Lq);
    const float L = mx0 + __logf(1.0f + __expf(mn0 - mx0));

    float part = 0.0f; int cnt = 0;
    #pragma unroll
    for (int k = 0; k < 32; k++) {
        const int idx = ((lane + 64 * (k >> 3)) * 8) + (k & 7);
        const int col = (idx & ~63) + ((idx & 3) << 4) + ((idx >> 2) & 15);
        if (lb[k] == myLab && col != orig) {
            const float sv = v[k] * INV_T;
            const float mx = fmaxf(sv, L), mn = fminf(sv, L);
            part += (mx - sv) + __logf(1.0f + __expf(mn - mx));
            cnt++;
        }
    }
    #pragma unroll
    for (int o = 32; o > 0; o >>= 1) { part += __shfl_xor(part, o); cnt += __shfl_xor(cnt, o); }
    if (lane == 0) { part_out[orig] = part; cnt_out[orig] = cnt; }
}

// reduce 2048 per-row partials -> scalar loss. One block.
__global__ void __launch_bounds__(256) finalize_loss(const float* __restrict__ part,
                                                     const int* __restrict__ cnt,
                                                     float* __restrict__ out) {
    const int t = threadIdx.x;
    float s = 0.0f; int c = 0;
    #pragma unroll
    for (int k = 0; k < 8; k++) { s += part[t + 256 * k]; c += cnt[t + 256 * k]; }
    #pragma unroll
    for (int o = 32; o > 0; o >>= 1) { s += __shfl_xor(s, o); c += __shfl_xor(c, o); }
    __shared__ float sf[4]; __shared__ int sc[4];
    if ((t & 63) == 0) { sf[t >> 6] = s; sc[t >> 6] = c; }
    __syncthreads();
    if (t == 0) {
        const float st = sf[0] + sf[1] + sf[2] + sf[3];
        const int   ct = sc[0] + sc[1] + sc[2] + sc[3];
        out[0] = (ct > 0) ? (st / (float)ct) : 0.0f;
    }
}

// ---------------------------------------------------------------------------
extern "C" void kernel_launch(void* const* d_in, const int* in_sizes, int n_in,
                              void* d_out, int out_size, void* d_ws, size_t ws_size,
                              hipStream_t stream) {
    const float* emb    = (const float*)d_in[0];
    const int*   labels = (const int*)  d_in[1];
    const float* W1     = (const float*)d_in[2];
    const float* b1     = (const float*)d_in[3];
    const float* W2     = (const float*)d_in[4];
    const float* b2     = (const float*)d_in[5];
    const float* queue  = (const float*)d_in[6];
    const int*   qlab   = (const int*)  d_in[7];

    char* ws = (char*)d_ws;
    short*         Sbuf  = (short*)        (ws);              // 8 MB used (16 MB region)
    unsigned char* codes = (unsigned char*)(ws + 16777216);   // 64 MB
    short*         embb  = (short*)        (ws + 83886080);   // 3145728
    short*         hbf   = (short*)        (ws + 87031808);   // 3145728
    short*         zb    = (short*)        (ws + 90177536);   // 524288
    short*         qb    = (short*)        (ws + 90701824);   // 8388608
    short*         w1t   = (short*)        (ws + 99090432);   // 1179648
    short*         w2t   = (short*)        (ws + 100270080);  // 196608
    int*           qcnt  = (int*)          (ws + 100474880);  // 64
    int*           rcnt  = (int*)          (ws + 100474944);  // 64
    int*           pc    = (int*)          (ws + 100475008);  // 64
    int*           qpart = (int*)          (ws + 100475072);  // 512
    float*         partb = (float*)        (ws + 100475584);  // 8192
    int*           cntb  = (int*)          (ws + 100483776);  // 8192
    int*           colidx= (int*)          (ws + 100491968);  // 131072
    int*           qlabp = (int*)          (ws + 100623040);  // 131072
    int*           rowmap= (int*)          (ws + 100754112);  // 8192
    int*           rlabp = (int*)          (ws + 100762304);  // 8192

    dim3 blk(256);
    prep<<<dim3(1737), blk, 0, stream>>>(emb, embb, qlab, qpart, W1, w1t, W2, w2t, labels, rcnt, pc);
    h64_qcast<<<dim3(4288), blk, 0, stream>>>(embb, w1t, b1, hbf, EMB_D_, EMB_D_, queue, qb);
    znorm_perm<<<dim3(200), blk, 0, stream>>>(hbf, w2t, b2, zb, qlab, labels, qpart, rcnt,
                                              qcnt, colidx, qlabp, rowmap, rlabp, pc);
    mask8_spack<<<dim3(2560), blk, 0, stream>>>(zb, qb, codes, rlabp, qlabp, colidx, rowmap, qcnt, rcnt, Sbuf);
    tail_row<<<dim3(BATCH_N), blk, 0, stream>>>(codes, qcnt, rlabp, rowmap, zb, qb, qlab,
                                                Sbuf, labels, partb, cntb);
    finalize_loss<<<1, blk, 0, stream>>>(partb, cntb, (float*)d_out);
}